// Round 2
// baseline (1855.848 us; speedup 1.0000x reference)
//
#include <hip/hip_runtime.h>
#include <hip/hip_bf16.h>

typedef __hip_bfloat16 bf16;

#define B_    8
#define LP    12
#define NC    4096
#define NO    128
#define NAPO  8
#define NN    4224
#define E_    64
#define A_    64
#define H_    256
#define QC    80      // 1 + 64 thoughtIn + 12 proj + 3 pad
#define PROJ0 65
#define NCHUNK 17     // ceil(NN/256)

#define TOT_IN 688896

struct Ptr16 { const void* p[16]; };

__device__ __forceinline__ float b2f(bf16 x){ return __bfloat162float(x); }

// ---------------- k_detect: is the float data fp32 (flag=1) or bf16 (flag=0)? ----------------
// Probe concept_embIn (262144 elements -> >=512KB either way; we read 8KB).
// If fp32: even bf16-halves are mantissa garbage, ~46% have exponent >= 137 (|x|>=1024).
// If bf16: values ~N(0,0.05), exponent < 127 always.
__global__ void k_detect(const void* probe, int* flag){
  __shared__ int cnt;
  if (threadIdx.x == 0) cnt = 0;
  __syncthreads();
  const unsigned short* u = (const unsigned short*)probe;
  int c = 0;
  for (int i = threadIdx.x; i < 4096; i += 256){
    int e = (u[i] >> 7) & 0xFF;
    if (e >= 137) c++;
  }
  atomicAdd(&cnt, c);
  __syncthreads();
  if (threadIdx.x == 0) *flag = (cnt >= 8) ? 1 : 0;
}

// ---------------- k_convert: canonicalize all 16 float tensors to fp32 in ws ----------------
__global__ void k_convert(Ptr16 ps, const int* flag, float* dst){
  int idx = blockIdx.x*256 + threadIdx.x;
  if (idx >= TOT_IN) return;
  constexpr int cum[17] = {0,16384,32768,49152,65536,327680,589824,589888,589952,
                           622720,622976,639360,639424,672192,672448,688832,688896};
  int t = 0;
  #pragma unroll
  for (int i=1;i<16;i++) if (idx >= cum[i]) t = i;
  int local = idx - cum[t];
  const void* src = ps.p[t];
  float v;
  if (*flag) v = ((const float*)src)[local];
  else       v = b2f(((const bf16*)src)[local]);
  dst[idx] = v;
}

// ---------------- k_obj: object embeddings ----------------
__global__ void k_obj(const float* classIn, const float* classOut,
                      const float* attrIn, const float* attrOut,
                      const int* gtc, const int* gta,
                      float* objIn, float* objOut){
  int idx = blockIdx.x*256 + threadIdx.x;           // B*NO*E = 65536
  if (idx >= B_*NO*E_) return;
  int e = idx & 63; int bo = idx >> 6;
  int cls = gtc[bo];
  float vi = classIn[cls*E_ + e];
  float vo = classOut[cls*E_ + e];
  const int* ga = gta + bo*NAPO;
  #pragma unroll
  for (int j=0;j<NAPO;j++){
    int at = ga[j];
    vi += attrIn[at*E_ + e];
    vo += attrOut[at*E_ + e];
  }
  objIn[idx] = vi; objOut[idx] = vo;
}

// ---------------- k_meta: precompute all metas & metaH (meta is attention-independent) ----------------
__global__ void k_meta(const float* conceptOut, const float* meta_init,
                       const float* mw1, const float* mb1, const float* mw2, const float* mb2,
                       const float* aw1, const float* ab1,
                       const int* ops, const int* args,
                       float* metaAll, float* metaH){
  __shared__ float x[128]; __shared__ float hid[H_]; __shared__ float meta_s[A_];
  int b = blockIdx.x, t0 = threadIdx.x;
  if (t0 < A_) meta_s[t0] = meta_init[t0];
  __syncthreads();
  for (int t=0;t<LP;t++){
    int op  = ops[b*LP + t];
    int arg = args[b*LP + t];
    if (t0 < 64) x[t0] = meta_s[t0];
    else if (t0 < 128) x[t0] = conceptOut[arg*E_ + (t0-64)];
    __syncthreads();
    float acc = mb1[t0];
    for (int j=0;j<128;j++) acc += x[j]*mw1[j*H_ + t0];
    hid[t0] = fmaxf(acc, 0.f);
    __syncthreads();
    if (t0 < 64){
      float acc2 = mb2[t0];
      for (int h=0;h<H_;h++) acc2 += hid[h]*mw2[h*A_ + t0];
      float m = (op==0) ? 1.f : 0.f;
      float nm = m*acc2 + (1.f-m)*meta_s[t0];
      meta_s[t0] = nm;
      metaAll[(b*LP+t)*A_ + t0] = nm;
    }
    __syncthreads();
    float mh = ab1[t0];                      // b1 folded into metaH
    for (int a=0;a<A_;a++) mh += meta_s[a]*aw1[(E_+a)*H_ + t0];
    metaH[(b*LP+t)*H_ + t0] = mh;
    __syncthreads();
  }
}

// ---------------- k_Q: build Q = [1 | thoughtIn | proj_0..11 | 0 pad], and qsum = colsum(Q) ----------------
__global__ void k_Q(const float* conceptIn, const float* conceptOut, const int* args,
                    const float* objIn, const float* objOut,
                    float* Q, float* qsum){
  __shared__ float argv[LP*E_];
  __shared__ float qs[QC];
  int b = blockIdx.x / NCHUNK, chunk = blockIdx.x % NCHUNK;
  int tid = threadIdx.x;
  for (int i=tid;i<LP*E_;i+=256)
    argv[i] = conceptOut[args[b*LP + i/E_]*E_ + (i%E_)];
  for (int i=tid;i<QC;i+=256) qs[i] = 0.f;
  __syncthreads();
  int n = chunk*256 + tid;
  float dots[LP];
  #pragma unroll
  for (int t=0;t<LP;t++) dots[t]=0.f;
  if (n < NN){
    float* Qr = Q + ((size_t)b*NN + n)*QC;
    Qr[0] = 1.f;
    for (int i=0;i<E_;i++){
      int e = (i + tid) & 63;                      // stagger -> low LDS atomic contention
      float ti, to;
      if (n < NC){ ti = conceptIn[n*E_+e]; to = conceptOut[n*E_+e]; }
      else { int r = b*NO + (n-NC); ti = objIn[r*E_+e]; to = objOut[r*E_+e]; }
      Qr[1+e] = ti;
      atomicAdd(&qs[1+e], ti);
      #pragma unroll
      for (int t=0;t<LP;t++) dots[t] += to*argv[t*E_+e];
    }
    Qr[77]=0.f; Qr[78]=0.f; Qr[79]=0.f;
  }
  #pragma unroll
  for (int t=0;t<LP;t++){
    float v = dots[t] * (1.f/E_);
    if (n < NN) Q[((size_t)b*NN + n)*QC + PROJ0 + t] = v;
    float r = v;
    #pragma unroll
    for (int off=32; off>0; off>>=1) r += __shfl_down(r, off, 64);
    if ((tid & 63) == 0) atomicAdd(&qs[PROJ0+t], r);
  }
  __syncthreads();
  for (int i=tid;i<QC;i+=256) if (qs[i] != 0.f) atomicAdd(&qsum[b*QC+i], qs[i]);
  if (chunk==0 && tid==0) atomicAdd(&qsum[b*QC+0], (float)NN);   // ones column
}

// ---------------- k_base: base = thoughtOut @ axon_w1[:E] (no b1; it's in metaH) ----------------
__global__ void k_base(const float* conceptOut, const float* objOut, const float* aw1,
                       float* baseC, float* baseO){
  __shared__ float v[E_];
  int row = blockIdx.x; int h = threadIdx.x;
  if (h < E_){
    if (row < NC) v[h] = conceptOut[row*E_ + h];
    else          v[h] = objOut[(row-NC)*E_ + h];
  }
  __syncthreads();
  float acc = 0.f;
  for (int e=0;e<E_;e++) acc += v[e]*aw1[e*H_ + h];
  if (row < NC) baseC[row*H_ + h] = acc;
  else          baseO[(size_t)(row-NC)*H_ + h] = acc;
}

// ---------------- k_T: T[b,t] = relu(base_b + 1*metaH_{b,t})^T @ Q_b   (256 x 80, K=4224) ----------------
__global__ __launch_bounds__(256) void k_T(const float* baseC, const float* baseO,
                                           const float* metaH, const float* Q, float* T){
  __shared__ float Rt[32][64];
  __shared__ float Qt[32*QC];
  __shared__ float mhl[64];
  int bid = blockIdx.x;
  int ht = bid & 3; int t = (bid >> 2) % LP; int b = bid / (4*LP);
  int h0 = ht*64;
  int tid = threadIdx.x;
  if (tid < 64) mhl[tid] = metaH[(b*LP+t)*H_ + h0 + tid];
  __syncthreads();
  int hl = tid & 15, ql = tid >> 4;
  float acc[4][5];
  #pragma unroll
  for (int i=0;i<4;i++){
    #pragma unroll
    for (int j=0;j<5;j++) acc[i][j]=0.f;
  }
  const float* Qb = Q + (size_t)b*NN*QC;
  for (int n0=0; n0<NN; n0+=32){
    if (n0 < NC){
      const float* bp = baseC + (size_t)n0*H_ + h0;
      for (int i=tid;i<2048;i+=256){ int kk=i>>6, hh=i&63;
        Rt[kk][hh] = fmaxf(bp[kk*H_ + hh] + mhl[hh], 0.f); }
    } else {
      const float* bp = baseO + ((size_t)(b*NO) + (n0-NC))*H_ + h0;
      for (int i=tid;i<2048;i+=256){ int kk=i>>6, hh=i&63;
        Rt[kk][hh] = fmaxf(bp[kk*H_ + hh] + mhl[hh], 0.f); }
    }
    const float* qsrc = Qb + (size_t)n0*QC;
    for (int i=tid;i<32*QC;i+=256) Qt[i] = qsrc[i];
    __syncthreads();
    #pragma unroll 4
    for (int kk=0;kk<32;kk++){
      float4 r = *(const float4*)&Rt[kk][hl*4];
      float rr[4] = {r.x, r.y, r.z, r.w};
      const float* qp = &Qt[kk*QC + ql*5];
      #pragma unroll
      for (int j=0;j<5;j++){
        float qv = qp[j];
        #pragma unroll
        for (int i=0;i<4;i++) acc[i][j] = fmaf(rr[i], qv, acc[i][j]);
      }
    }
    __syncthreads();
  }
  float* Tp = T + ((size_t)(b*LP+t)*H_ + h0)*QC;
  #pragma unroll
  for (int i=0;i<4;i++){
    #pragma unroll
    for (int j=0;j<5;j++) Tp[(hl*4+i)*QC + ql*5+j] = acc[i][j];
  }
}

// ---------------- k_U: Utilde[b,t] = (w2^T T[b,t] + b2 (x) qsum_b) / N   (64 x 80) ----------------
__global__ __launch_bounds__(256) void k_U(const float* T, const float* w2, const float* b2v,
                                           const float* qsum, float* Ut){
  __shared__ float Wt[32][64];
  __shared__ float Tt[32*QC];
  int bt = blockIdx.x; int b = bt / LP;
  int tid = threadIdx.x;
  int el = tid & 15, ql = tid >> 4;
  float acc[4][5];
  #pragma unroll
  for (int i=0;i<4;i++){
    #pragma unroll
    for (int j=0;j<5;j++) acc[i][j]=0.f;
  }
  const float* Tb = T + (size_t)bt*H_*QC;
  for (int k0=0;k0<H_;k0+=32){
    for (int i=tid;i<2048;i+=256){ int kk=i>>6, ee=i&63;
      Wt[kk][ee] = w2[(k0+kk)*E_ + ee]; }
    const float* tsrc = Tb + (size_t)k0*QC;
    for (int i=tid;i<32*QC;i+=256) Tt[i] = tsrc[i];
    __syncthreads();
    #pragma unroll 4
    for (int kk=0;kk<32;kk++){
      float4 w = *(const float4*)&Wt[kk][el*4];
      float ww[4] = {w.x, w.y, w.z, w.w};
      const float* tp = &Tt[kk*QC + ql*5];
      #pragma unroll
      for (int j=0;j<5;j++){
        float tv = tp[j];
        #pragma unroll
        for (int i=0;i<4;i++) acc[i][j] = fmaf(ww[i], tv, acc[i][j]);
      }
    }
    __syncthreads();
  }
  const float invN = 1.f/NN;
  float be[4]; float qv[5];
  #pragma unroll
  for (int i=0;i<4;i++) be[i] = b2v[el*4+i];
  #pragma unroll
  for (int j=0;j<5;j++) qv[j] = qsum[b*QC + ql*5+j];
  float* Up = Ut + (size_t)bt*E_*QC;
  #pragma unroll
  for (int i=0;i<4;i++){
    #pragma unroll
    for (int j=0;j<5;j++)
      Up[(el*4+i)*QC + ql*5+j] = (acc[i][j] + be[i]*qv[j]) * invN;
  }
}

// ---------------- k_rec: 12-step recurrence on C (80 x 64 per batch) ----------------
__global__ __launch_bounds__(256) void k_rec(const float* Ut, const float* metaAll,
                                             const int* ops, const float* att_init, float* Cm){
  __shared__ float C[QC*A_];
  __shared__ float M[E_*A_];
  int b = blockIdx.x, tid = threadIdx.x;
  for (int i=tid;i<QC*A_;i+=256) C[i] = 0.f;
  __syncthreads();
  if (tid < A_) C[tid] = att_init[tid];       // row 0 (ones column)
  __syncthreads();
  int el = tid & 15, al = tid >> 4;
  for (int t=0;t<LP;t++){
    const float* U = Ut + (size_t)(b*LP+t)*E_*QC;
    float acc[4][4];
    #pragma unroll
    for (int i=0;i<4;i++){
      #pragma unroll
      for (int k=0;k<4;k++) acc[i][k]=0.f;
    }
    for (int j=0;j<QC;j++){
      float u[4];
      #pragma unroll
      for (int i=0;i<4;i++) u[i] = U[(el*4+i)*QC + j];
      float4 c = *(const float4*)&C[j*A_ + al*4];
      float cc[4] = {c.x, c.y, c.z, c.w};
      #pragma unroll
      for (int i=0;i<4;i++){
        #pragma unroll
        for (int k=0;k<4;k++) acc[i][k] = fmaf(u[i], cc[k], acc[i][k]);
      }
    }
    #pragma unroll
    for (int i=0;i<4;i++){
      #pragma unroll
      for (int k=0;k<4;k++) M[(el*4+i)*A_ + al*4+k] = acc[i][k];
    }
    int op = ops[b*LP + t];
    float tr  = (op==2) ? 1.f : 0.f;
    float ins = (op==1) ? 1.f : 0.f;
    __syncthreads();
    for (int i=tid;i<E_*A_;i+=256) C[A_ + i] += tr*M[i];      // rows 1..64 += tr*M
    if (tid < A_) C[(PROJ0+t)*A_ + tid] += ins*metaAll[(b*LP+t)*A_ + tid];
    __syncthreads();
  }
  for (int i=tid;i<QC*A_;i+=256) Cm[b*QC*A_ + i] = C[i];
}

// ---------------- k_out: ol[b,n] = ||C^T q_n||^2 / 64, and expsum per batch ----------------
__global__ __launch_bounds__(256) void k_out(const float* Q, const float* Cm,
                                             float* ol, float* esum){
  __shared__ float C[QC*A_];
  __shared__ float wsum[4];
  int b = blockIdx.x / NCHUNK, chunk = blockIdx.x % NCHUNK;
  int tid = threadIdx.x;
  for (int i=tid;i<QC*A_;i+=256) C[i] = Cm[b*QC*A_ + i];
  __syncthreads();
  int n = chunk*256 + tid;
  float contrib = 0.f;
  if (n < NN){
    float y[A_];
    #pragma unroll
    for (int a=0;a<A_;a++) y[a]=0.f;
    const float* Qr = Q + ((size_t)b*NN + n)*QC;
    for (int j=0;j<QC;j++){
      float qvv = Qr[j];
      const float* Cj = &C[j*A_];
      #pragma unroll
      for (int a=0;a<A_;a++) y[a] = fmaf(qvv, Cj[a], y[a]);
    }
    float s = 0.f;
    #pragma unroll
    for (int a=0;a<A_;a++) s = fmaf(y[a], y[a], s);
    float o = s * (1.f/A_);
    ol[(size_t)b*NN + n] = o;
    contrib = expf(o);                              // o ~ 1e-3, no max-shift needed
  }
  #pragma unroll
  for (int off=32; off>0; off>>=1) contrib += __shfl_down(contrib, off, 64);
  if ((tid & 63) == 0) wsum[tid>>6] = contrib;
  __syncthreads();
  if (tid == 0) atomicAdd(&esum[b], wsum[0]+wsum[1]+wsum[2]+wsum[3]);
}

// ---------------- k_fin: out = (ol - log(esum[b])) in bf16 or fp32 per flag ----------------
__global__ void k_fin(const float* ol, const float* esum, const int* flag, void* out){
  int idx = blockIdx.x*256 + threadIdx.x;
  if (idx < B_*NN){
    int b = idx / NN;
    float v = ol[idx] - logf(esum[b]);
    if (*flag) ((float*)out)[idx] = v;
    else       ((bf16*)out)[idx]  = __float2bfloat16(v);
  }
}

extern "C" void kernel_launch(void* const* d_in, const int* in_sizes, int n_in,
                              void* d_out, int out_size, void* d_ws, size_t ws_size,
                              hipStream_t stream) {
  (void)in_sizes; (void)n_in; (void)out_size; (void)ws_size;
  const int* ops  = (const int*)d_in[17];
  const int* args = (const int*)d_in[18];
  const int* gtc  = (const int*)d_in[19];
  const int* gta  = (const int*)d_in[20];

  float* ws = (float*)d_ws;
  int* flag = (int*)ws;                       // ws[0]
  float* W  = ws + 16;                        // converted fp32 inputs

  // converted-region tensor offsets (see k_convert's cum[])
  const float* classIn    = W + 0;
  const float* classOut   = W + 16384;
  const float* attrIn     = W + 32768;
  const float* attrOut    = W + 49152;
  const float* conceptIn  = W + 65536;
  const float* conceptOut = W + 327680;
  const float* meta_init  = W + 589824;
  const float* att_init   = W + 589888;
  const float* aw1        = W + 589952;
  const float* ab1        = W + 622720;
  const float* aw2        = W + 622976;
  const float* ab2        = W + 639360;
  const float* mw1        = W + 639424;
  const float* mb1        = W + 672192;
  const float* mw2        = W + 672448;
  const float* mb2        = W + 688832;

  constexpr size_t OFF0      = 16 + TOT_IN;                 // 688912
  constexpr size_t SZ_OBJ    = (size_t)B_*NO*E_;            // 65536
  constexpr size_t OFF_OBJIN = OFF0;
  constexpr size_t OFF_OBJOUT= OFF_OBJIN + SZ_OBJ;
  constexpr size_t OFF_Q     = OFF_OBJOUT + SZ_OBJ;
  constexpr size_t SZ_Q      = (size_t)B_*NN*QC;            // 2703360
  constexpr size_t OFF_BASEC = OFF_Q + SZ_Q;
  constexpr size_t SZ_BASEC  = (size_t)NC*H_;               // 1048576
  constexpr size_t OFF_BASEO = OFF_BASEC + SZ_BASEC;
  constexpr size_t SZ_BASEO  = (size_t)B_*NO*H_;            // 262144
  constexpr size_t OFF_METAALL = OFF_BASEO + SZ_BASEO;
  constexpr size_t SZ_METAALL  = (size_t)B_*LP*A_;          // 6144
  constexpr size_t OFF_METAH = OFF_METAALL + SZ_METAALL;
  constexpr size_t SZ_METAH  = (size_t)B_*LP*H_;            // 24576
  constexpr size_t OFF_QSUM  = OFF_METAH + SZ_METAH;
  constexpr size_t SZ_QSUM   = (size_t)B_*QC;               // 640
  constexpr size_t OFF_ESUM  = OFF_QSUM + SZ_QSUM;
  constexpr size_t OFF_T     = OFF_ESUM + 128;
  constexpr size_t SZ_T      = (size_t)B_*LP*H_*QC;         // 1966080
  constexpr size_t OFF_UT    = OFF_T + SZ_T;
  constexpr size_t SZ_UT     = (size_t)B_*LP*E_*QC;         // 491520
  constexpr size_t OFF_CM    = OFF_UT + SZ_UT;
  constexpr size_t SZ_CM     = (size_t)B_*QC*A_;            // 40960
  constexpr size_t OFF_OL    = OFF_CM + SZ_CM;
  // total ~7.40M floats = ~29.6 MB of workspace

  float* objIn   = ws + OFF_OBJIN;
  float* objOut  = ws + OFF_OBJOUT;
  float* Q       = ws + OFF_Q;
  float* baseC   = ws + OFF_BASEC;
  float* baseO   = ws + OFF_BASEO;
  float* metaAll = ws + OFF_METAALL;
  float* metaH   = ws + OFF_METAH;
  float* qsum    = ws + OFF_QSUM;
  float* esum    = ws + OFF_ESUM;
  float* T       = ws + OFF_T;
  float* Ut      = ws + OFF_UT;
  float* Cm      = ws + OFF_CM;
  float* ol      = ws + OFF_OL;

  hipMemsetAsync(qsum, 0, (SZ_QSUM + 8)*sizeof(float), stream);   // qsum + esum

  Ptr16 ps;
  const int src_idx[16] = {0,1,2,3,4,5,6,8,9,10,11,12,13,14,15,16};
  for (int i=0;i<16;i++) ps.p[i] = d_in[src_idx[i]];

  k_detect <<<1, 256, 0, stream>>>(d_in[4], flag);
  k_convert<<<(TOT_IN+255)/256, 256, 0, stream>>>(ps, flag, W);

  k_obj <<<256, 256, 0, stream>>>(classIn, classOut, attrIn, attrOut, gtc, gta, objIn, objOut);
  k_meta<<<B_, 256, 0, stream>>>(conceptOut, meta_init, mw1, mb1, mw2, mb2, aw1, ab1,
                                 ops, args, metaAll, metaH);
  k_Q   <<<B_*NCHUNK, 256, 0, stream>>>(conceptIn, conceptOut, args, objIn, objOut, Q, qsum);
  k_base<<<NC + B_*NO, 256, 0, stream>>>(conceptOut, objOut, aw1, baseC, baseO);
  k_T   <<<B_*LP*4, 256, 0, stream>>>(baseC, baseO, metaH, Q, T);
  k_U   <<<B_*LP, 256, 0, stream>>>(T, aw2, ab2, qsum, Ut);
  k_rec <<<B_, 256, 0, stream>>>(Ut, metaAll, ops, att_init, Cm);
  k_out <<<B_*NCHUNK, 256, 0, stream>>>(Q, Cm, ol, esum);
  k_fin <<<(B_*NN + 255)/256, 256, 0, stream>>>(ol, esum, flag, d_out);
}

// Round 3
// 1354.300 us; speedup vs baseline: 1.3703x; 1.3703x over previous
//
#include <hip/hip_runtime.h>
#include <hip/hip_bf16.h>

typedef __hip_bfloat16 bf16;
typedef float f32x4 __attribute__((ext_vector_type(4)));
typedef short s16x8 __attribute__((ext_vector_type(8)));

#define B_    8
#define LP    12
#define NC    4096
#define NO    128
#define NAPO  8
#define NN    4224
#define NB    5120    // baseT columns: 4096 concepts + 8*128 objects
#define E_    64
#define A_    64
#define H_    256
#define QC    80      // 1 + 64 thoughtIn + 12 proj + 3 pad
#define PROJ0 65
#define NCHUNK 17     // ceil(NN/256)

#define TOT_IN 688896

struct Ptr16 { const void* p[16]; };

__device__ __forceinline__ float b2f(bf16 x){ return __bfloat162float(x); }
__device__ __forceinline__ float bs2f(unsigned short s){
  union { unsigned u; float f; } x; x.u = ((unsigned)s) << 16; return x.f;
}
__device__ __forceinline__ unsigned short f2bs(float f){
  bf16 h = __float2bfloat16(f);
  union { bf16 h; unsigned short s; } x; x.h = h; return x.s;
}

// ---------------- k_detect: fp32 (flag=1) vs bf16 (flag=0) input data ----------------
__global__ void k_detect(const void* probe, int* flag){
  __shared__ int cnt;
  if (threadIdx.x == 0) cnt = 0;
  __syncthreads();
  const unsigned short* u = (const unsigned short*)probe;
  int c = 0;
  for (int i = threadIdx.x; i < 4096; i += 256){
    int e = (u[i] >> 7) & 0xFF;
    if (e >= 137) c++;
  }
  atomicAdd(&cnt, c);
  __syncthreads();
  if (threadIdx.x == 0) *flag = (cnt >= 8) ? 1 : 0;
}

// ---------------- k_convert: canonicalize all 16 float tensors to fp32 in ws ----------------
__global__ void k_convert(Ptr16 ps, const int* flag, float* dst){
  int idx = blockIdx.x*256 + threadIdx.x;
  if (idx >= TOT_IN) return;
  constexpr int cum[17] = {0,16384,32768,49152,65536,327680,589824,589888,589952,
                           622720,622976,639360,639424,672192,672448,688832,688896};
  int t = 0;
  #pragma unroll
  for (int i=1;i<16;i++) if (idx >= cum[i]) t = i;
  int local = idx - cum[t];
  const void* src = ps.p[t];
  float v;
  if (*flag) v = ((const float*)src)[local];
  else       v = b2f(((const bf16*)src)[local]);
  dst[idx] = v;
}

// ---------------- k_awfrag: pack aw1[:64] into MFMA A-fragment layout (bf16) ----------------
// flat idx = ((kc*16 + m)*64 + lane)*8 + j ; e = kc*32 + (lane>>4)*8 + j ; h = m*16 + (lane&15)
__global__ void k_awfrag(const float* aw1, unsigned short* awFrag){
  int tid = threadIdx.x;
  for (int i=0;i<64;i++){
    int idx = i*256 + tid;
    int j = idx & 7;
    int lane = (idx >> 3) & 63;
    int m = (idx >> 9) & 15;
    int kc = idx >> 13;
    int e = kc*32 + (lane>>4)*8 + j;
    int h = m*16 + (lane&15);
    awFrag[idx] = f2bs(aw1[e*H_ + h]);
  }
}

// ---------------- k_obj: object embeddings ----------------
__global__ void k_obj(const float* classIn, const float* classOut,
                      const float* attrIn, const float* attrOut,
                      const int* gtc, const int* gta,
                      float* objIn, float* objOut){
  int idx = blockIdx.x*256 + threadIdx.x;           // B*NO*E = 65536
  if (idx >= B_*NO*E_) return;
  int e = idx & 63; int bo = idx >> 6;
  int cls = gtc[bo];
  float vi = classIn[cls*E_ + e];
  float vo = classOut[cls*E_ + e];
  const int* ga = gta + bo*NAPO;
  #pragma unroll
  for (int j=0;j<NAPO;j++){
    int at = ga[j];
    vi += attrIn[at*E_ + e];
    vo += attrOut[at*E_ + e];
  }
  objIn[idx] = vi; objOut[idx] = vo;
}

// ---------------- k_meta: precompute all metas & metaH ----------------
__global__ void k_meta(const float* conceptOut, const float* meta_init,
                       const float* mw1, const float* mb1, const float* mw2, const float* mb2,
                       const float* aw1, const float* ab1,
                       const int* ops, const int* args,
                       float* metaAll, float* metaH){
  __shared__ float x[128]; __shared__ float hid[H_]; __shared__ float meta_s[A_];
  int b = blockIdx.x, t0 = threadIdx.x;
  if (t0 < A_) meta_s[t0] = meta_init[t0];
  __syncthreads();
  for (int t=0;t<LP;t++){
    int op  = ops[b*LP + t];
    int arg = args[b*LP + t];
    if (t0 < 64) x[t0] = meta_s[t0];
    else if (t0 < 128) x[t0] = conceptOut[arg*E_ + (t0-64)];
    __syncthreads();
    float acc = mb1[t0];
    for (int j=0;j<128;j++) acc += x[j]*mw1[j*H_ + t0];
    hid[t0] = fmaxf(acc, 0.f);
    __syncthreads();
    if (t0 < 64){
      float acc2 = mb2[t0];
      for (int h=0;h<H_;h++) acc2 += hid[h]*mw2[h*A_ + t0];
      float m = (op==0) ? 1.f : 0.f;
      float nm = m*acc2 + (1.f-m)*meta_s[t0];
      meta_s[t0] = nm;
      metaAll[(b*LP+t)*A_ + t0] = nm;
    }
    __syncthreads();
    float mh = ab1[t0];                      // axon b1 folded into metaH
    for (int a=0;a<A_;a++) mh += meta_s[a]*aw1[(E_+a)*H_ + t0];
    metaH[(b*LP+t)*H_ + t0] = mh;
    __syncthreads();
  }
}

// ---------------- k_QT: build QT bf16 [b][80][4224] with coalesced writes ----------------
__global__ __launch_bounds__(256) void k_QT(const float* conceptIn, const float* conceptOut,
                                            const int* args, const float* objIn, const float* objOut,
                                            unsigned short* QT){
  __shared__ float tile[256*65];
  __shared__ float argv[LP*E_];
  int b = blockIdx.x / NCHUNK, chunk = blockIdx.x % NCHUNK;
  int tid = threadIdx.x;
  int rows = (chunk < 16) ? 256 : 128;
  int n0 = chunk*256;
  int n = n0 + tid;
  bool valid = (tid < rows);
  unsigned short* QTb = QT + (size_t)b*QC*NN;
  // ---- phase A: thoughtIn -> QT rows 1..64, plus rows 0 and 77..79
  {
    const float* src = (chunk < 16) ? (conceptIn + (size_t)n0*E_) : (objIn + (size_t)b*NO*E_);
    int tot = rows*64;
    for (int i=tid; i<tot; i+=256) tile[(i>>6)*65 + (i&63)] = src[i];
    __syncthreads();
    if (valid){
      QTb[(size_t)0*NN + n] = 0x3F80;     // 1.0 bf16
      QTb[(size_t)77*NN + n] = 0;
      QTb[(size_t)78*NN + n] = 0;
      QTb[(size_t)79*NN + n] = 0;
      for (int e=0;e<64;e++)
        QTb[(size_t)(1+e)*NN + n] = f2bs(tile[tid*65 + e]);
    }
    __syncthreads();
  }
  // ---- phase B: thoughtOut dots -> proj rows 65..76
  for (int i=tid;i<LP*E_;i+=256) argv[i] = conceptOut[args[b*LP + (i>>6)]*E_ + (i&63)];
  {
    const float* src = (chunk < 16) ? (conceptOut + (size_t)n0*E_) : (objOut + (size_t)b*NO*E_);
    int tot = rows*64;
    for (int i=tid; i<tot; i+=256) tile[(i>>6)*65 + (i&63)] = src[i];
  }
  __syncthreads();
  float dots[LP];
  #pragma unroll
  for (int t=0;t<LP;t++) dots[t] = 0.f;
  for (int e=0;e<64;e++){
    float o = tile[tid*65 + e];
    #pragma unroll
    for (int t=0;t<LP;t++) dots[t] += o*argv[t*64+e];
  }
  if (valid){
    #pragma unroll
    for (int t=0;t<LP;t++)
      QTb[(size_t)(PROJ0+t)*NN + n] = f2bs(dots[t]*(1.f/E_));
  }
}

// ---------------- k_qsum: qsum[b][qc] = sum_n QT[b][qc][n] ----------------
__global__ void k_qsum(const unsigned short* QT, float* qsum){
  int bqc = blockIdx.x;                    // 640 = 8*80
  const unsigned short* p = QT + (size_t)bqc*NN;
  int tid = threadIdx.x;
  float s = 0.f;
  for (int i=tid;i<NN;i+=256) s += bs2f(p[i]);
  #pragma unroll
  for (int off=32; off>0; off>>=1) s += __shfl_down(s, off, 64);
  __shared__ float ws4[4];
  if ((tid&63)==0) ws4[tid>>6] = s;
  __syncthreads();
  if (tid==0) qsum[bqc] = ws4[0]+ws4[1]+ws4[2]+ws4[3];
}

// ---------------- k_baseT: baseT[h][n'] = sum_e aw1[e][h]*thoughtOut[n'][e]  (MFMA, bf16 out) ----------------
__global__ __launch_bounds__(256) void k_baseT(const float* conceptOut, const float* objOut,
                                               const unsigned short* awFrag, unsigned short* baseT){
  int n0 = blockIdx.x * 64;
  int tid = threadIdx.x;
  int w = tid >> 6, l = tid & 63, quad = l >> 4, lq = l & 15;
  int n = n0 + w*16 + lq;                  // this lane's B column
  const float* src = (n < NC) ? (conceptOut + (size_t)n*E_) : (objOut + (size_t)(n-NC)*E_);
  f32x4 acc[16];
  #pragma unroll
  for (int m=0;m<16;m++) acc[m] = (f32x4){0.f,0.f,0.f,0.f};
  #pragma unroll
  for (int kc=0;kc<2;kc++){
    s16x8 bfr;
    #pragma unroll
    for (int j=0;j<8;j++) bfr[j] = (short)f2bs(src[kc*32 + quad*8 + j]);
    const unsigned short* ap = awFrag + ((size_t)(kc*16)*64 + l)*8;
    #pragma unroll
    for (int m=0;m<16;m++){
      s16x8 af = *(const s16x8*)(ap + (size_t)m*64*8);
      acc[m] = __builtin_amdgcn_mfma_f32_16x16x32_bf16(af, bfr, acc[m], 0, 0, 0);
    }
  }
  #pragma unroll
  for (int m=0;m<16;m++){
    #pragma unroll
    for (int r=0;r<4;r++){
      int h = m*16 + quad*4 + r;
      baseT[(size_t)h*NB + n0 + w*16 + lq] = f2bs(acc[m][r]);
    }
  }
}

// ---------------- k_T (MFMA): T[bt][h][qc] = sum_n relu(baseT[h][n]+metaH[bt][h]) * QT[b][qc][n] ----------------
__global__ __launch_bounds__(256) void k_T(const unsigned short* baseT, const unsigned short* QT,
                                           const float* metaH, float* T){
  int bid = blockIdx.x;
  int ht = bid & 3; int bt = bid >> 2; int b = bt / LP;
  int tid = threadIdx.x;
  int w = tid >> 6, l = tid & 63, quad = l >> 4, lq = l & 15;
  int htile = ht*64 + w*16;
  int hA = htile + lq;                     // this lane's A row
  float mh = metaH[(size_t)bt*H_ + hA];
  f32x4 acc[5];
  #pragma unroll
  for (int c=0;c<5;c++) acc[c] = (f32x4){0.f,0.f,0.f,0.f};
  const unsigned short* bA = baseT + (size_t)hA*NB + quad*8;
  const unsigned short* bQ = QT + (size_t)b*QC*NN + quad*8;
  #pragma unroll 2
  for (int n0=0; n0<NN; n0+=32){
    int coln = (n0 < NC) ? n0 : (NC + b*NO + (n0 - NC));
    s16x8 araw = *(const s16x8*)(bA + coln);
    s16x8 af;
    #pragma unroll
    for (int j=0;j<8;j++){
      float v = fmaxf(bs2f((unsigned short)araw[j]) + mh, 0.f);
      af[j] = (short)f2bs(v);
    }
    #pragma unroll
    for (int c=0;c<5;c++){
      s16x8 bfr = *(const s16x8*)(bQ + (size_t)(c*16+lq)*NN + n0);
      acc[c] = __builtin_amdgcn_mfma_f32_16x16x32_bf16(af, bfr, acc[c], 0, 0, 0);
    }
  }
  float* Tp = T + (size_t)bt*H_*QC;
  #pragma unroll
  for (int c=0;c<5;c++){
    #pragma unroll
    for (int r=0;r<4;r++){
      int h = htile + quad*4 + r;
      Tp[(size_t)h*QC + c*16 + lq] = acc[c][r];
    }
  }
}

// ---------------- k_U: Utilde[b,t] = (w2^T T[b,t] + b2 (x) qsum_b) / N   (64 x 80) ----------------
__global__ __launch_bounds__(256) void k_U(const float* T, const float* w2, const float* b2v,
                                           const float* qsum, float* Ut){
  __shared__ float Wt[32][64];
  __shared__ float Tt[32*QC];
  int bt = blockIdx.x; int b = bt / LP;
  int tid = threadIdx.x;
  int el = tid & 15, ql = tid >> 4;
  float acc[4][5];
  #pragma unroll
  for (int i=0;i<4;i++){
    #pragma unroll
    for (int j=0;j<5;j++) acc[i][j]=0.f;
  }
  const float* Tb = T + (size_t)bt*H_*QC;
  for (int k0=0;k0<H_;k0+=32){
    for (int i=tid;i<2048;i+=256){ int kk=i>>6, ee=i&63;
      Wt[kk][ee] = w2[(k0+kk)*E_ + ee]; }
    const float* tsrc = Tb + (size_t)k0*QC;
    for (int i=tid;i<32*QC;i+=256) Tt[i] = tsrc[i];
    __syncthreads();
    #pragma unroll 4
    for (int kk=0;kk<32;kk++){
      float4 wv = *(const float4*)&Wt[kk][el*4];
      float ww[4] = {wv.x, wv.y, wv.z, wv.w};
      const float* tp = &Tt[kk*QC + ql*5];
      #pragma unroll
      for (int j=0;j<5;j++){
        float tv = tp[j];
        #pragma unroll
        for (int i=0;i<4;i++) acc[i][j] = fmaf(ww[i], tv, acc[i][j]);
      }
    }
    __syncthreads();
  }
  const float invN = 1.f/NN;
  float be[4]; float qv[5];
  #pragma unroll
  for (int i=0;i<4;i++) be[i] = b2v[el*4+i];
  #pragma unroll
  for (int j=0;j<5;j++) qv[j] = qsum[b*QC + ql*5+j];
  float* Up = Ut + (size_t)bt*E_*QC;
  #pragma unroll
  for (int i=0;i<4;i++){
    #pragma unroll
    for (int j=0;j<5;j++)
      Up[(el*4+i)*QC + ql*5+j] = (acc[i][j] + be[i]*qv[j]) * invN;
  }
}

// ---------------- k_rec: 12-step recurrence on C (80 x 64 per batch) ----------------
__global__ __launch_bounds__(256) void k_rec(const float* Ut, const float* metaAll,
                                             const int* ops, const float* att_init, float* Cm){
  __shared__ float C[QC*A_];
  __shared__ float M[E_*A_];
  int b = blockIdx.x, tid = threadIdx.x;
  for (int i=tid;i<QC*A_;i+=256) C[i] = 0.f;
  __syncthreads();
  if (tid < A_) C[tid] = att_init[tid];       // row 0 (ones column)
  __syncthreads();
  int el = tid & 15, al = tid >> 4;
  for (int t=0;t<LP;t++){
    const float* U = Ut + (size_t)(b*LP+t)*E_*QC;
    float acc[4][4];
    #pragma unroll
    for (int i=0;i<4;i++){
      #pragma unroll
      for (int k=0;k<4;k++) acc[i][k]=0.f;
    }
    for (int j=0;j<QC;j++){
      float u[4];
      #pragma unroll
      for (int i=0;i<4;i++) u[i] = U[(el*4+i)*QC + j];
      float4 c = *(const float4*)&C[j*A_ + al*4];
      float cc[4] = {c.x, c.y, c.z, c.w};
      #pragma unroll
      for (int i=0;i<4;i++){
        #pragma unroll
        for (int k=0;k<4;k++) acc[i][k] = fmaf(u[i], cc[k], acc[i][k]);
      }
    }
    #pragma unroll
    for (int i=0;i<4;i++){
      #pragma unroll
      for (int k=0;k<4;k++) M[(el*4+i)*A_ + al*4+k] = acc[i][k];
    }
    int op = ops[b*LP + t];
    float tr  = (op==2) ? 1.f : 0.f;
    float ins = (op==1) ? 1.f : 0.f;
    __syncthreads();
    for (int i=tid;i<E_*A_;i+=256) C[A_ + i] += tr*M[i];      // rows 1..64 += tr*M
    if (tid < A_) C[(PROJ0+t)*A_ + tid] += ins*metaAll[(b*LP+t)*A_ + tid];
    __syncthreads();
  }
  for (int i=tid;i<QC*A_;i+=256) Cm[b*QC*A_ + i] = C[i];
}

// ---------------- k_out: ol[b,n] = ||C^T q_n||^2 / 64, and expsum per batch ----------------
__global__ __launch_bounds__(256) void k_out(const unsigned short* QT, const float* Cm,
                                             float* ol, float* esum){
  __shared__ float C[QC*A_];
  __shared__ float wsum[4];
  int b = blockIdx.x / NCHUNK, chunk = blockIdx.x % NCHUNK;
  int tid = threadIdx.x;
  for (int i=tid;i<QC*A_;i+=256) C[i] = Cm[b*QC*A_ + i];
  __syncthreads();
  int n = chunk*256 + tid;
  float contrib = 0.f;
  if (n < NN){
    float y[A_];
    #pragma unroll
    for (int a=0;a<A_;a++) y[a]=0.f;
    const unsigned short* Qp = QT + (size_t)b*QC*NN + n;
    for (int j=0;j<QC;j++){
      float qvv = bs2f(Qp[(size_t)j*NN]);
      const float* Cj = &C[j*A_];
      #pragma unroll
      for (int a=0;a<A_;a++) y[a] = fmaf(qvv, Cj[a], y[a]);
    }
    float s = 0.f;
    #pragma unroll
    for (int a=0;a<A_;a++) s = fmaf(y[a], y[a], s);
    float o = s * (1.f/A_);
    ol[(size_t)b*NN + n] = o;
    contrib = expf(o);
  }
  #pragma unroll
  for (int off=32; off>0; off>>=1) contrib += __shfl_down(contrib, off, 64);
  if ((tid & 63) == 0) wsum[tid>>6] = contrib;
  __syncthreads();
  if (tid == 0) atomicAdd(&esum[b], wsum[0]+wsum[1]+wsum[2]+wsum[3]);
}

// ---------------- k_fin: out = (ol - log(esum[b])) in bf16 or fp32 per flag ----------------
__global__ void k_fin(const float* ol, const float* esum, const int* flag, void* out){
  int idx = blockIdx.x*256 + threadIdx.x;
  if (idx < B_*NN){
    int b = idx / NN;
    float v = ol[idx] - logf(esum[b]);
    if (*flag) ((float*)out)[idx] = v;
    else       ((bf16*)out)[idx]  = __float2bfloat16(v);
  }
}

extern "C" void kernel_launch(void* const* d_in, const int* in_sizes, int n_in,
                              void* d_out, int out_size, void* d_ws, size_t ws_size,
                              hipStream_t stream) {
  (void)in_sizes; (void)n_in; (void)out_size; (void)ws_size;
  const int* ops  = (const int*)d_in[17];
  const int* args = (const int*)d_in[18];
  const int* gtc  = (const int*)d_in[19];
  const int* gta  = (const int*)d_in[20];

  float* ws = (float*)d_ws;
  int* flag = (int*)ws;                       // ws[0]
  float* W  = ws + 16;                        // converted fp32 inputs

  const float* classIn    = W + 0;
  const float* classOut   = W + 16384;
  const float* attrIn     = W + 32768;
  const float* attrOut    = W + 49152;
  const float* conceptIn  = W + 65536;
  const float* conceptOut = W + 327680;
  const float* meta_init  = W + 589824;
  const float* att_init   = W + 589888;
  const float* aw1        = W + 589952;
  const float* ab1        = W + 622720;
  const float* aw2        = W + 622976;
  const float* ab2        = W + 639360;
  const float* mw1        = W + 639424;
  const float* mb1        = W + 672192;
  const float* mw2        = W + 672448;
  const float* mb2        = W + 688832;

  // ---- workspace layout (float units, all offsets multiple of 16) ----
  constexpr size_t OFF_OBJIN   = 16 + TOT_IN;                 // 688912
  constexpr size_t OFF_OBJOUT  = OFF_OBJIN  + 65536;
  constexpr size_t OFF_METAALL = OFF_OBJOUT + 65536;
  constexpr size_t OFF_METAH   = OFF_METAALL + 6144;
  constexpr size_t OFF_QSUM    = OFF_METAH  + 24576;
  constexpr size_t OFF_ESUM    = OFF_QSUM   + 640;
  constexpr size_t OFF_T       = OFF_ESUM   + 16;
  constexpr size_t OFF_UT      = OFF_T      + 1966080;        // 96*256*80
  constexpr size_t OFF_CM      = OFF_UT     + 491520;         // 96*64*80
  constexpr size_t OFF_OL      = OFF_CM     + 40960;          // 8*80*64
  constexpr size_t OFF_QT      = OFF_OL     + 33792;          // 8*4224
  constexpr size_t OFF_BASET   = OFF_QT     + 1351680;        // 8*80*4224 bf16 / 2
  constexpr size_t OFF_AWF     = OFF_BASET  + 655360;         // 256*5120 bf16 / 2
  // end = OFF_AWF + 8192 = 5,398,944 floats ~= 21.6 MB

  float* objIn   = ws + OFF_OBJIN;
  float* objOut  = ws + OFF_OBJOUT;
  float* metaAll = ws + OFF_METAALL;
  float* metaH   = ws + OFF_METAH;
  float* qsum    = ws + OFF_QSUM;
  float* esum    = ws + OFF_ESUM;
  float* T       = ws + OFF_T;
  float* Ut      = ws + OFF_UT;
  float* Cm      = ws + OFF_CM;
  float* ol      = ws + OFF_OL;
  unsigned short* QT     = (unsigned short*)(ws + OFF_QT);
  unsigned short* baseT  = (unsigned short*)(ws + OFF_BASET);
  unsigned short* awFrag = (unsigned short*)(ws + OFF_AWF);

  hipMemsetAsync(esum, 0, 8*sizeof(float), stream);

  Ptr16 ps;
  const int src_idx[16] = {0,1,2,3,4,5,6,8,9,10,11,12,13,14,15,16};
  for (int i=0;i<16;i++) ps.p[i] = d_in[src_idx[i]];

  k_detect <<<1, 256, 0, stream>>>(d_in[4], flag);
  k_convert<<<(TOT_IN+255)/256, 256, 0, stream>>>(ps, flag, W);
  k_awfrag <<<1, 256, 0, stream>>>(aw1, awFrag);

  k_obj  <<<256, 256, 0, stream>>>(classIn, classOut, attrIn, attrOut, gtc, gta, objIn, objOut);
  k_meta <<<B_, 256, 0, stream>>>(conceptOut, meta_init, mw1, mb1, mw2, mb2, aw1, ab1,
                                  ops, args, metaAll, metaH);
  k_QT   <<<B_*NCHUNK, 256, 0, stream>>>(conceptIn, conceptOut, args, objIn, objOut, QT);
  k_qsum <<<B_*QC, 256, 0, stream>>>(QT, qsum);
  k_baseT<<<NB/64, 256, 0, stream>>>(conceptOut, objOut, awFrag, baseT);
  k_T    <<<B_*LP*4, 256, 0, stream>>>(baseT, QT, metaH, T);
  k_U    <<<B_*LP, 256, 0, stream>>>(T, aw2, ab2, qsum, Ut);
  k_rec  <<<B_, 256, 0, stream>>>(Ut, metaAll, ops, att_init, Cm);
  k_out  <<<B_*NCHUNK, 256, 0, stream>>>(QT, Cm, ol, esum);
  k_fin  <<<(B_*NN + 255)/256, 256, 0, stream>>>(ol, esum, flag, d_out);
}

// Round 4
// 529.481 us; speedup vs baseline: 3.5050x; 2.5578x over previous
//
#include <hip/hip_runtime.h>
#include <hip/hip_bf16.h>

typedef __hip_bfloat16 bf16;
typedef float f32x4 __attribute__((ext_vector_type(4)));
typedef short s16x8 __attribute__((ext_vector_type(8)));

#define B_    8
#define LP    12
#define NC    4096
#define NO    128
#define NAPO  8
#define NN    4224
#define NB    5120    // baseT columns: 4096 concepts + 8*128 objects
#define E_    64
#define A_    64
#define H_    256
#define QC    80      // 1 + 64 thoughtIn + 12 proj + 3 pad
#define PROJ0 65
#define NCHUNK 17     // ceil(NN/256)

#define TOT_IN 688896

struct Ptr16 { const void* p[16]; };

__device__ __forceinline__ float b2f(bf16 x){ return __bfloat162float(x); }
__device__ __forceinline__ float bs2f(unsigned short s){
  union { unsigned u; float f; } x; x.u = ((unsigned)s) << 16; return x.f;
}
__device__ __forceinline__ unsigned short f2bs(float f){
  bf16 h = __float2bfloat16(f);
  union { bf16 h; unsigned short s; } x; x.h = h; return x.s;
}
__device__ __forceinline__ unsigned pack2(float a, float b){
  return (unsigned)f2bs(a) | ((unsigned)f2bs(b) << 16);
}
__device__ __forceinline__ float lo16f(unsigned w){
  union { unsigned u; float f; } x; x.u = w << 16; return x.f;
}
__device__ __forceinline__ float hi16f(unsigned w){
  union { unsigned u; float f; } x; x.u = w & 0xffff0000u; return x.f;
}

// ---------------- k_detect: fp32 (flag=1) vs bf16 (flag=0) input data ----------------
__global__ void k_detect(const void* probe, int* flag){
  __shared__ int cnt;
  if (threadIdx.x == 0) cnt = 0;
  __syncthreads();
  const unsigned short* u = (const unsigned short*)probe;
  int c = 0;
  for (int i = threadIdx.x; i < 4096; i += 256){
    int e = (u[i] >> 7) & 0xFF;
    if (e >= 137) c++;
  }
  atomicAdd(&cnt, c);
  __syncthreads();
  if (threadIdx.x == 0) *flag = (cnt >= 8) ? 1 : 0;
}

// ---------------- k_convert: canonicalize all 16 float tensors to fp32 in ws ----------------
__global__ void k_convert(Ptr16 ps, const int* flag, float* dst){
  int idx = blockIdx.x*256 + threadIdx.x;
  if (idx >= TOT_IN) return;
  constexpr int cum[17] = {0,16384,32768,49152,65536,327680,589824,589888,589952,
                           622720,622976,639360,639424,672192,672448,688832,688896};
  int t = 0;
  #pragma unroll
  for (int i=1;i<16;i++) if (idx >= cum[i]) t = i;
  int local = idx - cum[t];
  const void* src = ps.p[t];
  float v;
  if (*flag) v = ((const float*)src)[local];
  else       v = b2f(((const bf16*)src)[local]);
  dst[idx] = v;
}

// ---------------- k_awfrag: pack aw1[:64] into MFMA A-fragment layout (bf16) ----------------
__global__ void k_awfrag(const float* aw1, unsigned short* awFrag){
  int tid = threadIdx.x;
  for (int i=0;i<64;i++){
    int idx = i*256 + tid;
    int j = idx & 7;
    int lane = (idx >> 3) & 63;
    int m = (idx >> 9) & 15;
    int kc = idx >> 13;
    int e = kc*32 + (lane>>4)*8 + j;
    int h = m*16 + (lane&15);
    awFrag[idx] = f2bs(aw1[e*H_ + h]);
  }
}

// ---------------- k_obj: object embeddings ----------------
__global__ void k_obj(const float* classIn, const float* classOut,
                      const float* attrIn, const float* attrOut,
                      const int* gtc, const int* gta,
                      float* objIn, float* objOut){
  int idx = blockIdx.x*256 + threadIdx.x;           // B*NO*E = 65536
  if (idx >= B_*NO*E_) return;
  int e = idx & 63; int bo = idx >> 6;
  int cls = gtc[bo];
  float vi = classIn[cls*E_ + e];
  float vo = classOut[cls*E_ + e];
  const int* ga = gta + bo*NAPO;
  #pragma unroll
  for (int j=0;j<NAPO;j++){
    int at = ga[j];
    vi += attrIn[at*E_ + e];
    vo += attrOut[at*E_ + e];
  }
  objIn[idx] = vi; objOut[idx] = vo;
}

// ---------------- k_meta: LDS-resident packed-bf16 weights; latency chain removed ----------------
// Weights quantized to bf16 pairs in LDS (mw1 64KB + mw2 32KB + aw1[64:128] 32KB = 128KB).
// Inner loops: conflict-free ds_read_b32 (consec lanes -> consec words) + float2 broadcast.
__global__ __launch_bounds__(256) void k_meta(const float* conceptOut, const float* meta_init,
                       const float* mw1, const float* mb1, const float* mw2, const float* mb2,
                       const float* aw1, const float* ab1,
                       const int* ops, const int* args,
                       float* metaAll, float* metaH){
  __shared__ unsigned mw1p[64*256];   // pack(mw1[2j][t], mw1[2j+1][t])
  __shared__ unsigned mw2p[128*64];   // pack(mw2[2h][a], mw2[2h+1][a])
  __shared__ unsigned aw1p[32*256];   // pack(aw1[64+2a][t], aw1[64+2a+1][t])
  __shared__ float meta_s[A_];
  __shared__ float argx[E_];
  __shared__ float hid[H_];
  __shared__ float part[4*A_];
  int b = blockIdx.x, tid = threadIdx.x;

  for (int i=tid; i<64*256; i+=256){
    int j2 = i >> 8, t = i & 255;
    mw1p[i] = pack2(mw1[(2*j2)*H_ + t], mw1[(2*j2+1)*H_ + t]);
  }
  for (int i=tid; i<128*64; i+=256){
    int h2 = i >> 6, a = i & 63;
    mw2p[i] = pack2(mw2[(2*h2)*A_ + a], mw2[(2*h2+1)*A_ + a]);
  }
  for (int i=tid; i<32*256; i+=256){
    int a2 = i >> 8, t = i & 255;
    aw1p[i] = pack2(aw1[(E_+2*a2)*H_ + t], aw1[(E_+2*a2+1)*H_ + t]);
  }
  float r_mb1 = mb1[tid];
  float r_ab1 = ab1[tid];
  float r_mb2 = (tid < A_) ? mb2[tid] : 0.f;
  if (tid < A_) meta_s[tid] = meta_init[tid];
  __syncthreads();

  for (int t=0;t<LP;t++){
    int op  = ops[b*LP + t];
    int arg = args[b*LP + t];
    if (tid >= 64 && tid < 128) argx[tid-64] = conceptOut[arg*E_ + (tid-64)];
    __syncthreads();
    // layer1: hid[t0] = relu(mb1 + [meta;arg] . mw1[:,t0])
    float acc = r_mb1;
    for (int j2=0;j2<32;j2++){
      unsigned w = mw1p[j2*256 + tid];
      float2 xp = *(const float2*)&meta_s[2*j2];
      acc = fmaf(xp.x, lo16f(w), acc);
      acc = fmaf(xp.y, hi16f(w), acc);
    }
    for (int j2=0;j2<32;j2++){
      unsigned w = mw1p[(32+j2)*256 + tid];
      float2 xp = *(const float2*)&argx[2*j2];
      acc = fmaf(xp.x, lo16f(w), acc);
      acc = fmaf(xp.y, hi16f(w), acc);
    }
    hid[tid] = fmaxf(acc, 0.f);
    __syncthreads();
    // layer2: split K=256 across 4 waves, LDS-reduce
    int wv_ = tid >> 6, l = tid & 63;
    float acc2 = 0.f;
    for (int h2 = wv_*32; h2 < wv_*32+32; h2++){
      unsigned w = mw2p[h2*64 + l];
      float2 hp = *(const float2*)&hid[2*h2];
      acc2 = fmaf(hp.x, lo16f(w), acc2);
      acc2 = fmaf(hp.y, hi16f(w), acc2);
    }
    part[wv_*64 + l] = acc2;
    __syncthreads();
    if (tid < A_){
      float s = part[tid] + part[64+tid] + part[128+tid] + part[192+tid] + r_mb2;
      float nm = (op==0) ? s : meta_s[tid];
      meta_s[tid] = nm;
      metaAll[(b*LP+t)*A_ + tid] = nm;
    }
    __syncthreads();
    // metaH[t0] = ab1[t0] + meta . aw1[64:,t0]
    float mh = r_ab1;
    for (int a2=0;a2<32;a2++){
      unsigned w = aw1p[a2*256 + tid];
      float2 mp = *(const float2*)&meta_s[2*a2];
      mh = fmaf(mp.x, lo16f(w), mh);
      mh = fmaf(mp.y, hi16f(w), mh);
    }
    metaH[(b*LP+t)*H_ + tid] = mh;
  }
}

// ---------------- k_QT: build QT bf16 [b][80][4224] with coalesced writes ----------------
__global__ __launch_bounds__(256) void k_QT(const float* conceptIn, const float* conceptOut,
                                            const int* args, const float* objIn, const float* objOut,
                                            unsigned short* QT){
  __shared__ float tile[256*65];
  __shared__ float argv[LP*E_];
  int b = blockIdx.x / NCHUNK, chunk = blockIdx.x % NCHUNK;
  int tid = threadIdx.x;
  int rows = (chunk < 16) ? 256 : 128;
  int n0 = chunk*256;
  int n = n0 + tid;
  bool valid = (tid < rows);
  unsigned short* QTb = QT + (size_t)b*QC*NN;
  // ---- phase A: thoughtIn -> QT rows 1..64, plus rows 0 and 77..79
  {
    const float* src = (chunk < 16) ? (conceptIn + (size_t)n0*E_) : (objIn + (size_t)b*NO*E_);
    int tot = rows*64;
    for (int i=tid; i<tot; i+=256) tile[(i>>6)*65 + (i&63)] = src[i];
    __syncthreads();
    if (valid){
      QTb[(size_t)0*NN + n] = 0x3F80;     // 1.0 bf16
      QTb[(size_t)77*NN + n] = 0;
      QTb[(size_t)78*NN + n] = 0;
      QTb[(size_t)79*NN + n] = 0;
      for (int e=0;e<64;e++)
        QTb[(size_t)(1+e)*NN + n] = f2bs(tile[tid*65 + e]);
    }
    __syncthreads();
  }
  // ---- phase B: thoughtOut dots -> proj rows 65..76
  for (int i=tid;i<LP*E_;i+=256) argv[i] = conceptOut[args[b*LP + (i>>6)]*E_ + (i&63)];
  {
    const float* src = (chunk < 16) ? (conceptOut + (size_t)n0*E_) : (objOut + (size_t)b*NO*E_);
    int tot = rows*64;
    for (int i=tid; i<tot; i+=256) tile[(i>>6)*65 + (i&63)] = src[i];
  }
  __syncthreads();
  float dots[LP];
  #pragma unroll
  for (int t=0;t<LP;t++) dots[t] = 0.f;
  for (int e=0;e<64;e++){
    float o = tile[tid*65 + e];
    #pragma unroll
    for (int t=0;t<LP;t++) dots[t] += o*argv[t*64+e];
  }
  if (valid){
    #pragma unroll
    for (int t=0;t<LP;t++)
      QTb[(size_t)(PROJ0+t)*NN + n] = f2bs(dots[t]*(1.f/E_));
  }
}

// ---------------- k_qsum: qsum[b][qc] = sum_n QT[b][qc][n] ----------------
__global__ void k_qsum(const unsigned short* QT, float* qsum){
  int bqc = blockIdx.x;                    // 640 = 8*80
  const unsigned short* p = QT + (size_t)bqc*NN;
  int tid = threadIdx.x;
  float s = 0.f;
  for (int i=tid;i<NN;i+=256) s += bs2f(p[i]);
  #pragma unroll
  for (int off=32; off>0; off>>=1) s += __shfl_down(s, off, 64);
  __shared__ float ws4[4];
  if ((tid&63)==0) ws4[tid>>6] = s;
  __syncthreads();
  if (tid==0) qsum[bqc] = ws4[0]+ws4[1]+ws4[2]+ws4[3];
}

// ---------------- k_baseT: baseT[h][n'] = sum_e aw1[e][h]*thoughtOut[n'][e]  (MFMA, bf16 out) ----------------
__global__ __launch_bounds__(256) void k_baseT(const float* conceptOut, const float* objOut,
                                               const unsigned short* awFrag, unsigned short* baseT){
  int n0 = blockIdx.x * 64;
  int tid = threadIdx.x;
  int w = tid >> 6, l = tid & 63, quad = l >> 4, lq = l & 15;
  int n = n0 + w*16 + lq;                  // this lane's B column
  const float* src = (n < NC) ? (conceptOut + (size_t)n*E_) : (objOut + (size_t)(n-NC)*E_);
  f32x4 acc[16];
  #pragma unroll
  for (int m=0;m<16;m++) acc[m] = (f32x4){0.f,0.f,0.f,0.f};
  #pragma unroll
  for (int kc=0;kc<2;kc++){
    s16x8 bfr;
    #pragma unroll
    for (int j=0;j<8;j++) bfr[j] = (short)f2bs(src[kc*32 + quad*8 + j]);
    const unsigned short* ap = awFrag + ((size_t)(kc*16)*64 + l)*8;
    #pragma unroll
    for (int m=0;m<16;m++){
      s16x8 af = *(const s16x8*)(ap + (size_t)m*64*8);
      acc[m] = __builtin_amdgcn_mfma_f32_16x16x32_bf16(af, bfr, acc[m], 0, 0, 0);
    }
  }
  #pragma unroll
  for (int m=0;m<16;m++){
    #pragma unroll
    for (int r=0;r<4;r++){
      int h = m*16 + quad*4 + r;
      baseT[(size_t)h*NB + n0 + w*16 + lq] = f2bs(acc[m][r]);
    }
  }
}

// ---------------- k_T (MFMA): T[bt][h][qc] = sum_n relu(baseT[h][n]+metaH[bt][h]) * QT[b][qc][n] ----------------
__global__ __launch_bounds__(256) void k_T(const unsigned short* baseT, const unsigned short* QT,
                                           const float* metaH, float* T){
  int bid = blockIdx.x;
  int ht = bid & 3; int bt = bid >> 2; int b = bt / LP;
  int tid = threadIdx.x;
  int w = tid >> 6, l = tid & 63, quad = l >> 4, lq = l & 15;
  int htile = ht*64 + w*16;
  int hA = htile + lq;                     // this lane's A row
  float mh = metaH[(size_t)bt*H_ + hA];
  f32x4 acc[5];
  #pragma unroll
  for (int c=0;c<5;c++) acc[c] = (f32x4){0.f,0.f,0.f,0.f};
  const unsigned short* bA = baseT + (size_t)hA*NB + quad*8;
  const unsigned short* bQ = QT + (size_t)b*QC*NN + quad*8;
  #pragma unroll 2
  for (int n0=0; n0<NN; n0+=32){
    int coln = (n0 < NC) ? n0 : (NC + b*NO + (n0 - NC));
    s16x8 araw = *(const s16x8*)(bA + coln);
    s16x8 af;
    #pragma unroll
    for (int j=0;j<8;j++){
      float v = fmaxf(bs2f((unsigned short)araw[j]) + mh, 0.f);
      af[j] = (short)f2bs(v);
    }
    #pragma unroll
    for (int c=0;c<5;c++){
      s16x8 bfr = *(const s16x8*)(bQ + (size_t)(c*16+lq)*NN + n0);
      acc[c] = __builtin_amdgcn_mfma_f32_16x16x32_bf16(af, bfr, acc[c], 0, 0, 0);
    }
  }
  float* Tp = T + (size_t)bt*H_*QC;
  #pragma unroll
  for (int c=0;c<5;c++){
    #pragma unroll
    for (int r=0;r<4;r++){
      int h = htile + quad*4 + r;
      Tp[(size_t)h*QC + c*16 + lq] = acc[c][r];
    }
  }
}

// ---------------- k_U: Utilde[b,t] = (w2^T T[b,t] + b2 (x) qsum_b) / N   (64 x 80) ----------------
__global__ __launch_bounds__(256) void k_U(const float* T, const float* w2, const float* b2v,
                                           const float* qsum, float* Ut){
  __shared__ float Wt[32][64];
  __shared__ float Tt[32*QC];
  int bt = blockIdx.x; int b = bt / LP;
  int tid = threadIdx.x;
  int el = tid & 15, ql = tid >> 4;
  float acc[4][5];
  #pragma unroll
  for (int i=0;i<4;i++){
    #pragma unroll
    for (int j=0;j<5;j++) acc[i][j]=0.f;
  }
  const float* Tb = T + (size_t)bt*H_*QC;
  for (int k0=0;k0<H_;k0+=32){
    for (int i=tid;i<2048;i+=256){ int kk=i>>6, ee=i&63;
      Wt[kk][ee] = w2[(k0+kk)*E_ + ee]; }
    const float* tsrc = Tb + (size_t)k0*QC;
    for (int i=tid;i<32*QC;i+=256) Tt[i] = tsrc[i];
    __syncthreads();
    #pragma unroll 4
    for (int kk=0;kk<32;kk++){
      float4 wv = *(const float4*)&Wt[kk][el*4];
      float ww[4] = {wv.x, wv.y, wv.z, wv.w};
      const float* tp = &Tt[kk*QC + ql*5];
      #pragma unroll
      for (int j=0;j<5;j++){
        float tv = tp[j];
        #pragma unroll
        for (int i=0;i<4;i++) acc[i][j] = fmaf(ww[i], tv, acc[i][j]);
      }
    }
    __syncthreads();
  }
  const float invN = 1.f/NN;
  float be[4]; float qv[5];
  #pragma unroll
  for (int i=0;i<4;i++) be[i] = b2v[el*4+i];
  #pragma unroll
  for (int j=0;j<5;j++) qv[j] = qsum[b*QC + ql*5+j];
  float* Up = Ut + (size_t)bt*E_*QC;
  #pragma unroll
  for (int i=0;i<4;i++){
    #pragma unroll
    for (int j=0;j<5;j++)
      Up[(el*4+i)*QC + ql*5+j] = (acc[i][j] + be[i]*qv[j]) * invN;
  }
}

// ---------------- k_rec: 12-step recurrence on C; U staged in LDS (stride 81) ----------------
__global__ __launch_bounds__(256) void k_rec(const float* Ut, const float* metaAll,
                                             const int* ops, const float* att_init, float* Cm){
  __shared__ float C[QC*A_];
  __shared__ float M[E_*A_];
  __shared__ float Ul[E_*81];
  int b = blockIdx.x, tid = threadIdx.x;
  for (int i=tid;i<QC*A_;i+=256) C[i] = 0.f;
  __syncthreads();
  if (tid < A_) C[tid] = att_init[tid];       // row 0 (ones column)
  __syncthreads();
  int el = tid & 15, al = tid >> 4;
  for (int t=0;t<LP;t++){
    const float* U = Ut + (size_t)(b*LP+t)*E_*QC;
    for (int i=tid;i<E_*QC;i+=256){ int r = i/QC, c = i - r*QC; Ul[r*81 + c] = U[i]; }
    __syncthreads();
    float acc[4][4];
    #pragma unroll
    for (int i=0;i<4;i++){
      #pragma unroll
      for (int k=0;k<4;k++) acc[i][k]=0.f;
    }
    for (int j=0;j<QC;j++){
      float u[4];
      #pragma unroll
      for (int i=0;i<4;i++) u[i] = Ul[(el*4+i)*81 + j];
      float4 c = *(const float4*)&C[j*A_ + al*4];
      float cc[4] = {c.x, c.y, c.z, c.w};
      #pragma unroll
      for (int i=0;i<4;i++){
        #pragma unroll
        for (int k=0;k<4;k++) acc[i][k] = fmaf(u[i], cc[k], acc[i][k]);
      }
    }
    #pragma unroll
    for (int i=0;i<4;i++){
      #pragma unroll
      for (int k=0;k<4;k++) M[(el*4+i)*A_ + al*4+k] = acc[i][k];
    }
    int op = ops[b*LP + t];
    float tr  = (op==2) ? 1.f : 0.f;
    float ins = (op==1) ? 1.f : 0.f;
    __syncthreads();
    for (int i=tid;i<E_*A_;i+=256) C[A_ + i] += tr*M[i];      // rows 1..64 += tr*M
    if (tid < A_) C[(PROJ0+t)*A_ + tid] += ins*metaAll[(b*LP+t)*A_ + tid];
    __syncthreads();
  }
  for (int i=tid;i<QC*A_;i+=256) Cm[b*QC*A_ + i] = C[i];
}

// ---------------- k_out: ol[b,n] = ||C^T q_n||^2 / 64, and expsum per batch ----------------
__global__ __launch_bounds__(256) void k_out(const unsigned short* QT, const float* Cm,
                                             float* ol, float* esum){
  __shared__ float C[QC*A_];
  __shared__ float wsum[4];
  int b = blockIdx.x / NCHUNK, chunk = blockIdx.x % NCHUNK;
  int tid = threadIdx.x;
  for (int i=tid;i<QC*A_;i+=256) C[i] = Cm[b*QC*A_ + i];
  __syncthreads();
  int n = chunk*256 + tid;
  float contrib = 0.f;
  if (n < NN){
    float y[A_];
    #pragma unroll
    for (int a=0;a<A_;a++) y[a]=0.f;
    const unsigned short* Qp = QT + (size_t)b*QC*NN + n;
    for (int j=0;j<QC;j++){
      float qvv = bs2f(Qp[(size_t)j*NN]);
      const float* Cj = &C[j*A_];
      #pragma unroll
      for (int a=0;a<A_;a++) y[a] = fmaf(qvv, Cj[a], y[a]);
    }
    float s = 0.f;
    #pragma unroll
    for (int a=0;a<A_;a++) s = fmaf(y[a], y[a], s);
    float o = s * (1.f/A_);
    ol[(size_t)b*NN + n] = o;
    contrib = expf(o);
  }
  #pragma unroll
  for (int off=32; off>0; off>>=1) contrib += __shfl_down(contrib, off, 64);
  if ((tid & 63) == 0) wsum[tid>>6] = contrib;
  __syncthreads();
  if (tid == 0) atomicAdd(&esum[b], wsum[0]+wsum[1]+wsum[2]+wsum[3]);
}

// ---------------- k_fin: out = (ol - log(esum[b])) in bf16 or fp32 per flag ----------------
__global__ void k_fin(const float* ol, const float* esum, const int* flag, void* out){
  int idx = blockIdx.x*256 + threadIdx.x;
  if (idx < B_*NN){
    int b = idx / NN;
    float v = ol[idx] - logf(esum[b]);
    if (*flag) ((float*)out)[idx] = v;
    else       ((bf16*)out)[idx]  = __float2bfloat16(v);
  }
}

extern "C" void kernel_launch(void* const* d_in, const int* in_sizes, int n_in,
                              void* d_out, int out_size, void* d_ws, size_t ws_size,
                              hipStream_t stream) {
  (void)in_sizes; (void)n_in; (void)out_size; (void)ws_size;
  const int* ops  = (const int*)d_in[17];
  const int* args = (const int*)d_in[18];
  const int* gtc  = (const int*)d_in[19];
  const int* gta  = (const int*)d_in[20];

  float* ws = (float*)d_ws;
  int* flag = (int*)ws;                       // ws[0]
  float* W  = ws + 16;                        // converted fp32 inputs

  const float* classIn    = W + 0;
  const float* classOut   = W + 16384;
  const float* attrIn     = W + 32768;
  const float* attrOut    = W + 49152;
  const float* conceptIn  = W + 65536;
  const float* conceptOut = W + 327680;
  const float* meta_init  = W + 589824;
  const float* att_init   = W + 589888;
  const float* aw1        = W + 589952;
  const float* ab1        = W + 622720;
  const float* aw2        = W + 622976;
  const float* ab2        = W + 639360;
  const float* mw1        = W + 639424;
  const float* mb1        = W + 672192;
  const float* mw2        = W + 672448;
  const float* mb2        = W + 688832;

  // ---- workspace layout (float units, all offsets multiple of 16) ----
  constexpr size_t OFF_OBJIN   = 16 + TOT_IN;                 // 688912
  constexpr size_t OFF_OBJOUT  = OFF_OBJIN  + 65536;
  constexpr size_t OFF_METAALL = OFF_OBJOUT + 65536;
  constexpr size_t OFF_METAH   = OFF_METAALL + 6144;
  constexpr size_t OFF_QSUM    = OFF_METAH  + 24576;
  constexpr size_t OFF_ESUM    = OFF_QSUM   + 640;
  constexpr size_t OFF_T       = OFF_ESUM   + 16;
  constexpr size_t OFF_UT      = OFF_T      + 1966080;        // 96*256*80
  constexpr size_t OFF_CM      = OFF_UT     + 491520;         // 96*64*80
  constexpr size_t OFF_OL      = OFF_CM     + 40960;          // 8*80*64
  constexpr size_t OFF_QT      = OFF_OL     + 33792;          // 8*4224
  constexpr size_t OFF_BASET   = OFF_QT     + 1351680;        // 8*80*4224 bf16 / 2
  constexpr size_t OFF_AWF     = OFF_BASET  + 655360;         // 256*5120 bf16 / 2
  // end = OFF_AWF + 8192 = 5,398,944 floats ~= 21.6 MB

  float* objIn   = ws + OFF_OBJIN;
  float* objOut  = ws + OFF_OBJOUT;
  float* metaAll = ws + OFF_METAALL;
  float* metaH   = ws + OFF_METAH;
  float* qsum    = ws + OFF_QSUM;
  float* esum    = ws + OFF_ESUM;
  float* T       = ws + OFF_T;
  float* Ut      = ws + OFF_UT;
  float* Cm      = ws + OFF_CM;
  float* ol      = ws + OFF_OL;
  unsigned short* QT     = (unsigned short*)(ws + OFF_QT);
  unsigned short* baseT  = (unsigned short*)(ws + OFF_BASET);
  unsigned short* awFrag = (unsigned short*)(ws + OFF_AWF);

  hipMemsetAsync(esum, 0, 8*sizeof(float), stream);

  Ptr16 ps;
  const int src_idx[16] = {0,1,2,3,4,5,6,8,9,10,11,12,13,14,15,16};
  for (int i=0;i<16;i++) ps.p[i] = d_in[src_idx[i]];

  k_detect <<<1, 256, 0, stream>>>(d_in[4], flag);
  k_convert<<<(TOT_IN+255)/256, 256, 0, stream>>>(ps, flag, W);
  k_awfrag <<<1, 256, 0, stream>>>(aw1, awFrag);

  k_obj  <<<256, 256, 0, stream>>>(classIn, classOut, attrIn, attrOut, gtc, gta, objIn, objOut);
  k_meta <<<B_, 256, 0, stream>>>(conceptOut, meta_init, mw1, mb1, mw2, mb2, aw1, ab1,
                                  ops, args, metaAll, metaH);
  k_QT   <<<B_*NCHUNK, 256, 0, stream>>>(conceptIn, conceptOut, args, objIn, objOut, QT);
  k_qsum <<<B_*QC, 256, 0, stream>>>(QT, qsum);
  k_baseT<<<NB/64, 256, 0, stream>>>(conceptOut, objOut, awFrag, baseT);
  k_T    <<<B_*LP*4, 256, 0, stream>>>(baseT, QT, metaH, T);
  k_U    <<<B_*LP, 256, 0, stream>>>(T, aw2, ab2, qsum, Ut);
  k_rec  <<<B_, 256, 0, stream>>>(Ut, metaAll, ops, att_init, Cm);
  k_out  <<<B_*NCHUNK, 256, 0, stream>>>(QT, Cm, ol, esum);
  k_fin  <<<(B_*NN + 255)/256, 256, 0, stream>>>(ol, esum, flag, d_out);
}

// Round 5
// 424.248 us; speedup vs baseline: 4.3744x; 1.2480x over previous
//
#include <hip/hip_runtime.h>
#include <hip/hip_bf16.h>

typedef __hip_bfloat16 bf16;
typedef float f32x4 __attribute__((ext_vector_type(4)));
typedef short s16x8 __attribute__((ext_vector_type(8)));

#define B_    8
#define LP    12
#define NC    4096
#define NO    128
#define NAPO  8
#define NN    4224
#define NB    5120    // baseT columns: 4096 concepts + 8*128 objects
#define E_    64
#define A_    64
#define H_    256
#define QC    80      // 1 + 64 thoughtIn + 12 proj + 3 pad
#define PROJ0 65
#define NCHUNK 17     // ceil(NN/256)

#define TOT_IN 688896

struct Ptr16 { const void* p[16]; };

__device__ __forceinline__ float b2f(bf16 x){ return __bfloat162float(x); }
__device__ __forceinline__ float bs2f(unsigned short s){
  union { unsigned u; float f; } x; x.u = ((unsigned)s) << 16; return x.f;
}
__device__ __forceinline__ unsigned short f2bs(float f){
  bf16 h = __float2bfloat16(f);
  union { bf16 h; unsigned short s; } x; x.h = h; return x.s;
}
__device__ __forceinline__ unsigned pack2(float a, float b){
  return (unsigned)f2bs(a) | ((unsigned)f2bs(b) << 16);
}
__device__ __forceinline__ float lo16f(unsigned w){
  union { unsigned u; float f; } x; x.u = w << 16; return x.f;
}
__device__ __forceinline__ float hi16f(unsigned w){
  union { unsigned u; float f; } x; x.u = w & 0xffff0000u; return x.f;
}

// ---------------- k_detect: fp32 (flag=1) vs bf16 (flag=0) input data ----------------
__global__ void k_detect(const void* probe, int* flag){
  __shared__ int cnt;
  if (threadIdx.x == 0) cnt = 0;
  __syncthreads();
  const unsigned short* u = (const unsigned short*)probe;
  int c = 0;
  for (int i = threadIdx.x; i < 4096; i += 256){
    int e = (u[i] >> 7) & 0xFF;
    if (e >= 137) c++;
  }
  atomicAdd(&cnt, c);
  __syncthreads();
  if (threadIdx.x == 0) *flag = (cnt >= 8) ? 1 : 0;
}

// ---------------- k_convert: canonicalize all 16 float tensors to fp32 in ws ----------------
__global__ void k_convert(Ptr16 ps, const int* flag, float* dst){
  int idx = blockIdx.x*256 + threadIdx.x;
  if (idx >= TOT_IN) return;
  constexpr int cum[17] = {0,16384,32768,49152,65536,327680,589824,589888,589952,
                           622720,622976,639360,639424,672192,672448,688832,688896};
  int t = 0;
  #pragma unroll
  for (int i=1;i<16;i++) if (idx >= cum[i]) t = i;
  int local = idx - cum[t];
  const void* src = ps.p[t];
  float v;
  if (*flag) v = ((const float*)src)[local];
  else       v = b2f(((const bf16*)src)[local]);
  dst[idx] = v;
}

// ---------------- k_awfrag: pack aw1[:64] into MFMA A-fragment layout (bf16) ----------------
__global__ void k_awfrag(const float* aw1, unsigned short* awFrag){
  int tid = threadIdx.x;
  for (int i=0;i<64;i++){
    int idx = i*256 + tid;
    int j = idx & 7;
    int lane = (idx >> 3) & 63;
    int m = (idx >> 9) & 15;
    int kc = idx >> 13;
    int e = kc*32 + (lane>>4)*8 + j;
    int h = m*16 + (lane&15);
    awFrag[idx] = f2bs(aw1[e*H_ + h]);
  }
}

// ---------------- k_obj: object embeddings ----------------
__global__ void k_obj(const float* classIn, const float* classOut,
                      const float* attrIn, const float* attrOut,
                      const int* gtc, const int* gta,
                      float* objIn, float* objOut){
  int idx = blockIdx.x*256 + threadIdx.x;           // B*NO*E = 65536
  if (idx >= B_*NO*E_) return;
  int e = idx & 63; int bo = idx >> 6;
  int cls = gtc[bo];
  float vi = classIn[cls*E_ + e];
  float vo = classOut[cls*E_ + e];
  const int* ga = gta + bo*NAPO;
  #pragma unroll
  for (int j=0;j<NAPO;j++){
    int at = ga[j];
    vi += attrIn[at*E_ + e];
    vo += attrOut[at*E_ + e];
  }
  objIn[idx] = vi; objOut[idx] = vo;
}

// ---------------- k_meta: LDS-resident packed-bf16 weights ----------------
__global__ __launch_bounds__(256) void k_meta(const float* conceptOut, const float* meta_init,
                       const float* mw1, const float* mb1, const float* mw2, const float* mb2,
                       const float* aw1, const float* ab1,
                       const int* ops, const int* args,
                       float* metaAll, float* metaH){
  __shared__ unsigned mw1p[64*256];   // pack(mw1[2j][t], mw1[2j+1][t])
  __shared__ unsigned mw2p[128*64];   // pack(mw2[2h][a], mw2[2h+1][a])
  __shared__ unsigned aw1p[32*256];   // pack(aw1[64+2a][t], aw1[64+2a+1][t])
  __shared__ float meta_s[A_];
  __shared__ float argx[E_];
  __shared__ float hid[H_];
  __shared__ float part[4*A_];
  int b = blockIdx.x, tid = threadIdx.x;

  for (int i=tid; i<64*256; i+=256){
    int j2 = i >> 8, t = i & 255;
    mw1p[i] = pack2(mw1[(2*j2)*H_ + t], mw1[(2*j2+1)*H_ + t]);
  }
  for (int i=tid; i<128*64; i+=256){
    int h2 = i >> 6, a = i & 63;
    mw2p[i] = pack2(mw2[(2*h2)*A_ + a], mw2[(2*h2+1)*A_ + a]);
  }
  for (int i=tid; i<32*256; i+=256){
    int a2 = i >> 8, t = i & 255;
    aw1p[i] = pack2(aw1[(E_+2*a2)*H_ + t], aw1[(E_+2*a2+1)*H_ + t]);
  }
  float r_mb1 = mb1[tid];
  float r_ab1 = ab1[tid];
  float r_mb2 = (tid < A_) ? mb2[tid] : 0.f;
  if (tid < A_) meta_s[tid] = meta_init[tid];
  __syncthreads();

  for (int t=0;t<LP;t++){
    int op  = ops[b*LP + t];
    int arg = args[b*LP + t];
    if (tid >= 64 && tid < 128) argx[tid-64] = conceptOut[arg*E_ + (tid-64)];
    __syncthreads();
    float acc = r_mb1;
    for (int j2=0;j2<32;j2++){
      unsigned w = mw1p[j2*256 + tid];
      float2 xp = *(const float2*)&meta_s[2*j2];
      acc = fmaf(xp.x, lo16f(w), acc);
      acc = fmaf(xp.y, hi16f(w), acc);
    }
    for (int j2=0;j2<32;j2++){
      unsigned w = mw1p[(32+j2)*256 + tid];
      float2 xp = *(const float2*)&argx[2*j2];
      acc = fmaf(xp.x, lo16f(w), acc);
      acc = fmaf(xp.y, hi16f(w), acc);
    }
    hid[tid] = fmaxf(acc, 0.f);
    __syncthreads();
    int wv_ = tid >> 6, l = tid & 63;
    float acc2 = 0.f;
    for (int h2 = wv_*32; h2 < wv_*32+32; h2++){
      unsigned w = mw2p[h2*64 + l];
      float2 hp = *(const float2*)&hid[2*h2];
      acc2 = fmaf(hp.x, lo16f(w), acc2);
      acc2 = fmaf(hp.y, hi16f(w), acc2);
    }
    part[wv_*64 + l] = acc2;
    __syncthreads();
    if (tid < A_){
      float s = part[tid] + part[64+tid] + part[128+tid] + part[192+tid] + r_mb2;
      float nm = (op==0) ? s : meta_s[tid];
      meta_s[tid] = nm;
      metaAll[(b*LP+t)*A_ + tid] = nm;
    }
    __syncthreads();
    float mh = r_ab1;
    for (int a2=0;a2<32;a2++){
      unsigned w = aw1p[a2*256 + tid];
      float2 mp = *(const float2*)&meta_s[2*a2];
      mh = fmaf(mp.x, lo16f(w), mh);
      mh = fmaf(mp.y, hi16f(w), mh);
    }
    metaH[(b*LP+t)*H_ + tid] = mh;
  }
}

// ---------------- k_QT: build QT bf16 [b][80][4224] with coalesced writes ----------------
__global__ __launch_bounds__(256) void k_QT(const float* conceptIn, const float* conceptOut,
                                            const int* args, const float* objIn, const float* objOut,
                                            unsigned short* QT){
  __shared__ float tile[256*65];
  __shared__ float argv[LP*E_];
  int b = blockIdx.x / NCHUNK, chunk = blockIdx.x % NCHUNK;
  int tid = threadIdx.x;
  int rows = (chunk < 16) ? 256 : 128;
  int n0 = chunk*256;
  int n = n0 + tid;
  bool valid = (tid < rows);
  unsigned short* QTb = QT + (size_t)b*QC*NN;
  {
    const float* src = (chunk < 16) ? (conceptIn + (size_t)n0*E_) : (objIn + (size_t)b*NO*E_);
    int tot = rows*64;
    for (int i=tid; i<tot; i+=256) tile[(i>>6)*65 + (i&63)] = src[i];
    __syncthreads();
    if (valid){
      QTb[(size_t)0*NN + n] = 0x3F80;     // 1.0 bf16
      QTb[(size_t)77*NN + n] = 0;
      QTb[(size_t)78*NN + n] = 0;
      QTb[(size_t)79*NN + n] = 0;
      for (int e=0;e<64;e++)
        QTb[(size_t)(1+e)*NN + n] = f2bs(tile[tid*65 + e]);
    }
    __syncthreads();
  }
  for (int i=tid;i<LP*E_;i+=256) argv[i] = conceptOut[args[b*LP + (i>>6)]*E_ + (i&63)];
  {
    const float* src = (chunk < 16) ? (conceptOut + (size_t)n0*E_) : (objOut + (size_t)b*NO*E_);
    int tot = rows*64;
    for (int i=tid; i<tot; i+=256) tile[(i>>6)*65 + (i&63)] = src[i];
  }
  __syncthreads();
  float dots[LP];
  #pragma unroll
  for (int t=0;t<LP;t++) dots[t] = 0.f;
  for (int e=0;e<64;e++){
    float o = tile[tid*65 + e];
    #pragma unroll
    for (int t=0;t<LP;t++) dots[t] += o*argv[t*64+e];
  }
  if (valid){
    #pragma unroll
    for (int t=0;t<LP;t++)
      QTb[(size_t)(PROJ0+t)*NN + n] = f2bs(dots[t]*(1.f/E_));
  }
}

// ---------------- k_qsum: qsum[b][qc] = sum_n QT[b][qc][n] ----------------
__global__ void k_qsum(const unsigned short* QT, float* qsum){
  int bqc = blockIdx.x;                    // 640 = 8*80
  const unsigned short* p = QT + (size_t)bqc*NN;
  int tid = threadIdx.x;
  float s = 0.f;
  for (int i=tid;i<NN;i+=256) s += bs2f(p[i]);
  #pragma unroll
  for (int off=32; off>0; off>>=1) s += __shfl_down(s, off, 64);
  __shared__ float ws4[4];
  if ((tid&63)==0) ws4[tid>>6] = s;
  __syncthreads();
  if (tid==0) qsum[bqc] = ws4[0]+ws4[1]+ws4[2]+ws4[3];
}

// ---------------- k_baseT: baseT[h][n'] = sum_e aw1[e][h]*thoughtOut[n'][e]  (MFMA, bf16 out) ----------------
__global__ __launch_bounds__(256) void k_baseT(const float* conceptOut, const float* objOut,
                                               const unsigned short* awFrag, unsigned short* baseT){
  int n0 = blockIdx.x * 64;
  int tid = threadIdx.x;
  int w = tid >> 6, l = tid & 63, quad = l >> 4, lq = l & 15;
  int n = n0 + w*16 + lq;                  // this lane's B column
  const float* src = (n < NC) ? (conceptOut + (size_t)n*E_) : (objOut + (size_t)(n-NC)*E_);
  f32x4 acc[16];
  #pragma unroll
  for (int m=0;m<16;m++) acc[m] = (f32x4){0.f,0.f,0.f,0.f};
  #pragma unroll
  for (int kc=0;kc<2;kc++){
    s16x8 bfr;
    #pragma unroll
    for (int j=0;j<8;j++) bfr[j] = (short)f2bs(src[kc*32 + quad*8 + j]);
    const unsigned short* ap = awFrag + ((size_t)(kc*16)*64 + l)*8;
    #pragma unroll
    for (int m=0;m<16;m++){
      s16x8 af = *(const s16x8*)(ap + (size_t)m*64*8);
      acc[m] = __builtin_amdgcn_mfma_f32_16x16x32_bf16(af, bfr, acc[m], 0, 0, 0);
    }
  }
  #pragma unroll
  for (int m=0;m<16;m++){
    #pragma unroll
    for (int r=0;r<4;r++){
      int h = m*16 + quad*4 + r;
      baseT[(size_t)h*NB + n0 + w*16 + lq] = f2bs(acc[m][r]);
    }
  }
}

// ---------------- k_T (MFMA v2): waves split K; 4 h-subtiles share B-frags; LDS reduce ----------------
// T[bt][h][qc] = sum_n relu(baseT[h][n]+metaH[bt][h]) * QT[b][qc][n]
__global__ __launch_bounds__(256) void k_T(const unsigned short* baseT, const unsigned short* QT,
                                           const float* metaH, float* T){
  __shared__ float Lred[4*5120];           // 80 KB: per-wave partial T tiles
  int bid = blockIdx.x;
  int ht = bid & 3; int bt = bid >> 2; int b = bt / LP;
  int tid = threadIdx.x;
  int w = tid >> 6, l = tid & 63, quad = l >> 4, lq = l & 15;
  float mh[4];
  const unsigned short* bA[4];
  #pragma unroll
  for (int s=0;s<4;s++){
    int hA = ht*64 + s*16 + lq;
    mh[s] = metaH[(size_t)bt*H_ + hA];
    bA[s] = baseT + (size_t)hA*NB + quad*8;
  }
  const unsigned short* bQ = QT + (size_t)b*QC*NN + quad*8;
  f32x4 acc[4][5];
  #pragma unroll
  for (int s=0;s<4;s++){
    #pragma unroll
    for (int c=0;c<5;c++) acc[s][c] = (f32x4){0.f,0.f,0.f,0.f};
  }
  int nbase = w*1056;                      // this wave's K-quarter (33 iters of 32)
  for (int it=0; it<33; it++){
    int n0 = nbase + it*32;
    int coln = (n0 < NC) ? n0 : (NC + b*NO + (n0 - NC));
    s16x8 bfr[5];
    #pragma unroll
    for (int c=0;c<5;c++) bfr[c] = *(const s16x8*)(bQ + (size_t)(c*16+lq)*NN + n0);
    #pragma unroll
    for (int s=0;s<4;s++){
      s16x8 araw = *(const s16x8*)(bA[s] + coln);
      s16x8 af;
      #pragma unroll
      for (int j=0;j<8;j++){
        float v = fmaxf(bs2f((unsigned short)araw[j]) + mh[s], 0.f);
        af[j] = (short)f2bs(v);
      }
      #pragma unroll
      for (int c=0;c<5;c++)
        acc[s][c] = __builtin_amdgcn_mfma_f32_16x16x32_bf16(af, bfr[c], acc[s][c], 0, 0, 0);
    }
  }
  #pragma unroll
  for (int s=0;s<4;s++){
    #pragma unroll
    for (int c=0;c<5;c++)
      *(f32x4*)&Lred[w*5120 + (s*5+c)*256 + l*4] = acc[s][c];
  }
  __syncthreads();
  float* Tp = T + (size_t)bt*H_*QC;
  for (int i=tid; i<5120; i+=256){
    float v = Lred[i] + Lred[5120+i] + Lred[2*5120+i] + Lred[3*5120+i];
    int sc = i >> 8, ll = (i>>2)&63, r = i&3;
    int s = sc/5, c = sc - s*5;
    int h = ht*64 + s*16 + (ll>>4)*4 + r;
    int qc = c*16 + (ll&15);
    Tp[(size_t)h*QC + qc] = v;
  }
}

// ---------------- k_U: Utilde[b,t] = (w2^T T[b,t] + b2 (x) qsum_b) / N   (64 x 80) ----------------
__global__ __launch_bounds__(256) void k_U(const float* T, const float* w2, const float* b2v,
                                           const float* qsum, float* Ut){
  __shared__ float Wt[32][64];
  __shared__ float Tt[32*QC];
  int bt = blockIdx.x; int b = bt / LP;
  int tid = threadIdx.x;
  int el = tid & 15, ql = tid >> 4;
  float acc[4][5];
  #pragma unroll
  for (int i=0;i<4;i++){
    #pragma unroll
    for (int j=0;j<5;j++) acc[i][j]=0.f;
  }
  const float* Tb = T + (size_t)bt*H_*QC;
  for (int k0=0;k0<H_;k0+=32){
    for (int i=tid;i<2048;i+=256){ int kk=i>>6, ee=i&63;
      Wt[kk][ee] = w2[(k0+kk)*E_ + ee]; }
    const float* tsrc = Tb + (size_t)k0*QC;
    for (int i=tid;i<32*QC;i+=256) Tt[i] = tsrc[i];
    __syncthreads();
    #pragma unroll 4
    for (int kk=0;kk<32;kk++){
      float4 wv = *(const float4*)&Wt[kk][el*4];
      float ww[4] = {wv.x, wv.y, wv.z, wv.w};
      const float* tp = &Tt[kk*QC + ql*5];
      #pragma unroll
      for (int j=0;j<5;j++){
        float tv = tp[j];
        #pragma unroll
        for (int i=0;i<4;i++) acc[i][j] = fmaf(ww[i], tv, acc[i][j]);
      }
    }
    __syncthreads();
  }
  const float invN = 1.f/NN;
  float be[4]; float qv[5];
  #pragma unroll
  for (int i=0;i<4;i++) be[i] = b2v[el*4+i];
  #pragma unroll
  for (int j=0;j<5;j++) qv[j] = qsum[b*QC + ql*5+j];
  float* Up = Ut + (size_t)bt*E_*QC;
  #pragma unroll
  for (int i=0;i<4;i++){
    #pragma unroll
    for (int j=0;j<5;j++)
      Up[(el*4+i)*QC + ql*5+j] = (acc[i][j] + be[i]*qv[j]) * invN;
  }
}

// ---------------- k_rec: 12-step recurrence on C; U staged in LDS (stride 81) ----------------
__global__ __launch_bounds__(256) void k_rec(const float* Ut, const float* metaAll,
                                             const int* ops, const float* att_init, float* Cm){
  __shared__ float C[QC*A_];
  __shared__ float M[E_*A_];
  __shared__ float Ul[E_*81];
  int b = blockIdx.x, tid = threadIdx.x;
  for (int i=tid;i<QC*A_;i+=256) C[i] = 0.f;
  __syncthreads();
  if (tid < A_) C[tid] = att_init[tid];       // row 0 (ones column)
  __syncthreads();
  int el = tid & 15, al = tid >> 4;
  for (int t=0;t<LP;t++){
    const float* U = Ut + (size_t)(b*LP+t)*E_*QC;
    for (int i=tid;i<E_*QC;i+=256){ int r = i/QC, c = i - r*QC; Ul[r*81 + c] = U[i]; }
    __syncthreads();
    float acc[4][4];
    #pragma unroll
    for (int i=0;i<4;i++){
      #pragma unroll
      for (int k=0;k<4;k++) acc[i][k]=0.f;
    }
    for (int j=0;j<QC;j++){
      float u[4];
      #pragma unroll
      for (int i=0;i<4;i++) u[i] = Ul[(el*4+i)*81 + j];
      float4 c = *(const float4*)&C[j*A_ + al*4];
      float cc[4] = {c.x, c.y, c.z, c.w};
      #pragma unroll
      for (int i=0;i<4;i++){
        #pragma unroll
        for (int k=0;k<4;k++) acc[i][k] = fmaf(u[i], cc[k], acc[i][k]);
      }
    }
    #pragma unroll
    for (int i=0;i<4;i++){
      #pragma unroll
      for (int k=0;k<4;k++) M[(el*4+i)*A_ + al*4+k] = acc[i][k];
    }
    int op = ops[b*LP + t];
    float tr  = (op==2) ? 1.f : 0.f;
    float ins = (op==1) ? 1.f : 0.f;
    __syncthreads();
    for (int i=tid;i<E_*A_;i+=256) C[A_ + i] += tr*M[i];      // rows 1..64 += tr*M
    if (tid < A_) C[(PROJ0+t)*A_ + tid] += ins*metaAll[(b*LP+t)*A_ + tid];
    __syncthreads();
  }
  for (int i=tid;i<QC*A_;i+=256) Cm[b*QC*A_ + i] = C[i];
}

// ---------------- k_out: ol[b,n] = ||C^T q_n||^2 / 64, and expsum per batch ----------------
__global__ __launch_bounds__(256) void k_out(const unsigned short* QT, const float* Cm,
                                             float* ol, float* esum){
  __shared__ float C[QC*A_];
  __shared__ float wsum[4];
  int b = blockIdx.x / NCHUNK, chunk = blockIdx.x % NCHUNK;
  int tid = threadIdx.x;
  for (int i=tid;i<QC*A_;i+=256) C[i] = Cm[b*QC*A_ + i];
  __syncthreads();
  int n = chunk*256 + tid;
  float contrib = 0.f;
  if (n < NN){
    float y[A_];
    #pragma unroll
    for (int a=0;a<A_;a++) y[a]=0.f;
    const unsigned short* Qp = QT + (size_t)b*QC*NN + n;
    for (int j=0;j<QC;j++){
      float qvv = bs2f(Qp[(size_t)j*NN]);
      const float* Cj = &C[j*A_];
      #pragma unroll
      for (int a=0;a<A_;a++) y[a] = fmaf(qvv, Cj[a], y[a]);
    }
    float s = 0.f;
    #pragma unroll
    for (int a=0;a<A_;a++) s = fmaf(y[a], y[a], s);
    float o = s * (1.f/A_);
    ol[(size_t)b*NN + n] = o;
    contrib = expf(o);
  }
  #pragma unroll
  for (int off=32; off>0; off>>=1) contrib += __shfl_down(contrib, off, 64);
  if ((tid & 63) == 0) wsum[tid>>6] = contrib;
  __syncthreads();
  if (tid == 0) atomicAdd(&esum[b], wsum[0]+wsum[1]+wsum[2]+wsum[3]);
}

// ---------------- k_fin: out = (ol - log(esum[b])) in bf16 or fp32 per flag ----------------
__global__ void k_fin(const float* ol, const float* esum, const int* flag, void* out){
  int idx = blockIdx.x*256 + threadIdx.x;
  if (idx < B_*NN){
    int b = idx / NN;
    float v = ol[idx] - logf(esum[b]);
    if (*flag) ((float*)out)[idx] = v;
    else       ((bf16*)out)[idx]  = __float2bfloat16(v);
  }
}

extern "C" void kernel_launch(void* const* d_in, const int* in_sizes, int n_in,
                              void* d_out, int out_size, void* d_ws, size_t ws_size,
                              hipStream_t stream) {
  (void)in_sizes; (void)n_in; (void)out_size; (void)ws_size;
  const int* ops  = (const int*)d_in[17];
  const int* args = (const int*)d_in[18];
  const int* gtc  = (const int*)d_in[19];
  const int* gta  = (const int*)d_in[20];

  float* ws = (float*)d_ws;
  int* flag = (int*)ws;                       // ws[0]
  float* W  = ws + 16;                        // converted fp32 inputs

  const float* classIn    = W + 0;
  const float* classOut   = W + 16384;
  const float* attrIn     = W + 32768;
  const float* attrOut    = W + 49152;
  const float* conceptIn  = W + 65536;
  const float* conceptOut = W + 327680;
  const float* meta_init  = W + 589824;
  const float* att_init   = W + 589888;
  const float* aw1        = W + 589952;
  const float* ab1        = W + 622720;
  const float* aw2        = W + 622976;
  const float* ab2        = W + 639360;
  const float* mw1        = W + 639424;
  const float* mb1        = W + 672192;
  const float* mw2        = W + 672448;
  const float* mb2        = W + 688832;

  // ---- workspace layout (float units, all offsets multiple of 16) ----
  constexpr size_t OFF_OBJIN   = 16 + TOT_IN;                 // 688912
  constexpr size_t OFF_OBJOUT  = OFF_OBJIN  + 65536;
  constexpr size_t OFF_METAALL = OFF_OBJOUT + 65536;
  constexpr size_t OFF_METAH   = OFF_METAALL + 6144;
  constexpr size_t OFF_QSUM    = OFF_METAH  + 24576;
  constexpr size_t OFF_ESUM    = OFF_QSUM   + 640;
  constexpr size_t OFF_T       = OFF_ESUM   + 16;
  constexpr size_t OFF_UT      = OFF_T      + 1966080;        // 96*256*80
  constexpr size_t OFF_CM      = OFF_UT     + 491520;         // 96*64*80
  constexpr size_t OFF_OL      = OFF_CM     + 40960;          // 8*80*64
  constexpr size_t OFF_QT      = OFF_OL     + 33792;          // 8*4224
  constexpr size_t OFF_BASET   = OFF_QT     + 1351680;        // 8*80*4224 bf16 / 2
  constexpr size_t OFF_AWF     = OFF_BASET  + 655360;         // 256*5120 bf16 / 2
  // end = OFF_AWF + 8192 = 5,398,944 floats ~= 21.6 MB

  float* objIn   = ws + OFF_OBJIN;
  float* objOut  = ws + OFF_OBJOUT;
  float* metaAll = ws + OFF_METAALL;
  float* metaH   = ws + OFF_METAH;
  float* qsum    = ws + OFF_QSUM;
  float* esum    = ws + OFF_ESUM;
  float* T       = ws + OFF_T;
  float* Ut      = ws + OFF_UT;
  float* Cm      = ws + OFF_CM;
  float* ol      = ws + OFF_OL;
  unsigned short* QT     = (unsigned short*)(ws + OFF_QT);
  unsigned short* baseT  = (unsigned short*)(ws + OFF_BASET);
  unsigned short* awFrag = (unsigned short*)(ws + OFF_AWF);

  hipMemsetAsync(esum, 0, 8*sizeof(float), stream);

  Ptr16 ps;
  const int src_idx[16] = {0,1,2,3,4,5,6,8,9,10,11,12,13,14,15,16};
  for (int i=0;i<16;i++) ps.p[i] = d_in[src_idx[i]];

  k_detect <<<1, 256, 0, stream>>>(d_in[4], flag);
  k_convert<<<(TOT_IN+255)/256, 256, 0, stream>>>(ps, flag, W);
  k_awfrag <<<1, 256, 0, stream>>>(aw1, awFrag);

  k_obj  <<<256, 256, 0, stream>>>(classIn, classOut, attrIn, attrOut, gtc, gta, objIn, objOut);
  k_meta <<<B_, 256, 0, stream>>>(conceptOut, meta_init, mw1, mb1, mw2, mb2, aw1, ab1,
                                  ops, args, metaAll, metaH);
  k_QT   <<<B_*NCHUNK, 256, 0, stream>>>(conceptIn, conceptOut, args, objIn, objOut, QT);
  k_qsum <<<B_*QC, 256, 0, stream>>>(QT, qsum);
  k_baseT<<<NB/64, 256, 0, stream>>>(conceptOut, objOut, awFrag, baseT);
  k_T    <<<B_*LP*4, 256, 0, stream>>>(baseT, QT, metaH, T);
  k_U    <<<B_*LP, 256, 0, stream>>>(T, aw2, ab2, qsum, Ut);
  k_rec  <<<B_, 256, 0, stream>>>(Ut, metaAll, ops, att_init, Cm);
  k_out  <<<B_*NCHUNK, 256, 0, stream>>>(QT, Cm, ol, esum);
  k_fin  <<<(B_*NN + 255)/256, 256, 0, stream>>>(ol, esum, flag, d_out);
}

// Round 6
// 390.483 us; speedup vs baseline: 4.7527x; 1.0865x over previous
//
#include <hip/hip_runtime.h>
#include <hip/hip_bf16.h>

typedef __hip_bfloat16 bf16;
typedef float f32x4 __attribute__((ext_vector_type(4)));
typedef short s16x8 __attribute__((ext_vector_type(8)));

#define B_    8
#define LP    12
#define NC    4096
#define NO    128
#define NAPO  8
#define NN    4224
#define E_    64
#define A_    64
#define H_    256
#define QC    80
#define PROJ0 65
#define NCHUNK 17

#define TOT_IN 688896
#define QTF_C  67584     // 132*512 shorts per (b,c) group
#define QTF_B  337920    // 5*QTF_C per batch

struct Ptr16 { const void* p[16]; };

__device__ __forceinline__ float b2f(bf16 x){ return __bfloat162float(x); }
__device__ __forceinline__ float bs2f(unsigned short s){
  union { unsigned u; float f; } x; x.u = ((unsigned)s) << 16; return x.f;
}
__device__ __forceinline__ unsigned short f2bs(float f){
  bf16 h = __float2bfloat16(f);
  union { bf16 h; unsigned short s; } x; x.h = h; return x.s;
}
__device__ __forceinline__ unsigned pack2(float a, float b){
  return (unsigned)f2bs(a) | ((unsigned)f2bs(b) << 16);
}
__device__ __forceinline__ float lo16f(unsigned w){
  union { unsigned u; float f; } x; x.u = w << 16; return x.f;
}
__device__ __forceinline__ float hi16f(unsigned w){
  union { unsigned u; float f; } x; x.u = w & 0xffff0000u; return x.f;
}
__device__ __forceinline__ float rdval(const void* p, int i, int fl){
  return fl ? ((const float*)p)[i] : bs2f(((const unsigned short*)p)[i]);
}

// ---------------- k_detect: fp32 (flag=1) vs bf16 (flag=0) input data ----------------
__global__ void k_detect(const void* probe, int* flag){
  __shared__ int cnt;
  if (threadIdx.x == 0) cnt = 0;
  __syncthreads();
  const unsigned short* u = (const unsigned short*)probe;
  int c = 0;
  for (int i = threadIdx.x; i < 4096; i += 256){
    int e = (u[i] >> 7) & 0xFF;
    if (e >= 137) c++;
  }
  atomicAdd(&cnt, c);
  __syncthreads();
  if (threadIdx.x == 0) *flag = (cnt >= 8) ? 1 : 0;
}

// ---------------- k_prep: convert(2691) + awFrag pack(64) + obj embeddings(256) ----------------
__global__ void k_prep(Ptr16 ps, const int* flag, float* dst,
                       unsigned short* awFrag,
                       const int* gtc, const int* gta,
                       float* objIn, float* objOut){
  int mb = blockIdx.x;
  int fl = *flag;
  if (mb < 2691){
    int idx = mb*256 + threadIdx.x;
    if (idx >= TOT_IN) return;
    constexpr int cum[17] = {0,16384,32768,49152,65536,327680,589824,589888,589952,
                             622720,622976,639360,639424,672192,672448,688832,688896};
    int t = 0;
    #pragma unroll
    for (int i=1;i<16;i++) if (idx >= cum[i]) t = i;
    dst[idx] = rdval(ps.p[t], idx - cum[t], fl);
  } else if (mb < 2755){
    int idx = (mb-2691)*256 + threadIdx.x;      // < 16384
    int j = idx & 7;
    int lane = (idx >> 3) & 63;
    int m = (idx >> 9) & 15;
    int kc = idx >> 13;
    int e = kc*32 + (lane>>4)*8 + j;
    int h = m*16 + (lane&15);
    awFrag[idx] = f2bs(rdval(ps.p[8], e*H_ + h, fl));
  } else {
    int idx = (mb-2755)*256 + threadIdx.x;      // < 65536
    int e = idx & 63; int bo = idx >> 6;
    int cls = gtc[bo];
    float vi = rdval(ps.p[0], cls*E_ + e, fl);
    float vo = rdval(ps.p[1], cls*E_ + e, fl);
    const int* ga = gta + bo*NAPO;
    #pragma unroll
    for (int j=0;j<NAPO;j++){
      int at = ga[j];
      vi += rdval(ps.p[2], at*E_ + e, fl);
      vo += rdval(ps.p[3], at*E_ + e, fl);
    }
    objIn[idx] = vi; objOut[idx] = vo;
  }
}

// ================ k_mid: meta(8) | QTf+qsum(136) | baseT->Aopt(80) ================
__device__ __forceinline__ void mid_meta(char* smem, int b,
                       const float* conceptOut, const float* meta_init,
                       const float* mw1, const float* mb1, const float* mw2, const float* mb2,
                       const float* aw1, const float* ab1,
                       const int* ops, const int* args,
                       float* metaAll, float* metaH){
  unsigned* mw1p = (unsigned*)smem;               // 64*256 = 65536 B
  unsigned* mw2p = (unsigned*)(smem + 65536);     // 128*64 = 32768 B
  unsigned* aw1p = (unsigned*)(smem + 98304);     // 32*256 = 32768 B
  float* meta_s  = (float*)(smem + 131072);       // 256 B
  float* argx    = (float*)(smem + 131328);       // 256 B
  float* hid     = (float*)(smem + 131584);       // 1024 B
  float* part    = (float*)(smem + 132608);       // 1024 B
  int tid = threadIdx.x;

  for (int i=tid; i<64*256; i+=256){
    int j2 = i >> 8, t = i & 255;
    mw1p[i] = pack2(mw1[(2*j2)*H_ + t], mw1[(2*j2+1)*H_ + t]);
  }
  for (int i=tid; i<128*64; i+=256){
    int h2 = i >> 6, a = i & 63;
    mw2p[i] = pack2(mw2[(2*h2)*A_ + a], mw2[(2*h2+1)*A_ + a]);
  }
  for (int i=tid; i<32*256; i+=256){
    int a2 = i >> 8, t = i & 255;
    aw1p[i] = pack2(aw1[(E_+2*a2)*H_ + t], aw1[(E_+2*a2+1)*H_ + t]);
  }
  float r_mb1 = mb1[tid];
  float r_ab1 = ab1[tid];
  float r_mb2 = (tid < A_) ? mb2[tid] : 0.f;
  if (tid < A_) meta_s[tid] = meta_init[tid];
  __syncthreads();

  for (int t=0;t<LP;t++){
    int op  = ops[b*LP + t];
    int arg = args[b*LP + t];
    if (tid >= 64 && tid < 128) argx[tid-64] = conceptOut[arg*E_ + (tid-64)];
    __syncthreads();
    float acc = r_mb1;
    for (int j2=0;j2<32;j2++){
      unsigned w = mw1p[j2*256 + tid];
      float2 xp = *(const float2*)&meta_s[2*j2];
      acc = fmaf(xp.x, lo16f(w), acc);
      acc = fmaf(xp.y, hi16f(w), acc);
    }
    for (int j2=0;j2<32;j2++){
      unsigned w = mw1p[(32+j2)*256 + tid];
      float2 xp = *(const float2*)&argx[2*j2];
      acc = fmaf(xp.x, lo16f(w), acc);
      acc = fmaf(xp.y, hi16f(w), acc);
    }
    hid[tid] = fmaxf(acc, 0.f);
    __syncthreads();
    int wv_ = tid >> 6, l = tid & 63;
    float acc2 = 0.f;
    for (int h2 = wv_*32; h2 < wv_*32+32; h2++){
      unsigned w = mw2p[h2*64 + l];
      float2 hp = *(const float2*)&hid[2*h2];
      acc2 = fmaf(hp.x, lo16f(w), acc2);
      acc2 = fmaf(hp.y, hi16f(w), acc2);
    }
    part[wv_*64 + l] = acc2;
    __syncthreads();
    if (tid < A_){
      float s = part[tid] + part[64+tid] + part[128+tid] + part[192+tid] + r_mb2;
      float nm = (op==0) ? s : meta_s[tid];
      meta_s[tid] = nm;
      metaAll[(b*LP+t)*A_ + tid] = nm;
    }
    __syncthreads();
    float mh = r_ab1;
    for (int a2=0;a2<32;a2++){
      unsigned w = aw1p[a2*256 + tid];
      float2 mp = *(const float2*)&meta_s[2*a2];
      mh = fmaf(mp.x, lo16f(w), mh);
      mh = fmaf(mp.y, hi16f(w), mh);
    }
    metaH[(b*LP+t)*H_ + tid] = mh;
  }
}

__device__ __forceinline__ void mid_qt(char* smem, int idx,
                       const float* conceptIn, const float* conceptOut, const int* args,
                       const float* objIn, const float* objOut,
                       unsigned short* QTf, float* qsum){
  float* tile = (float*)smem;                  // 256*65*4 = 66560 B
  float* argv = (float*)(smem + 66560);        // 768*4 = 3072 B
  float* qs   = (float*)(smem + 69632);        // 320 B
  int b = idx / NCHUNK, chunk = idx % NCHUNK;
  int tid = threadIdx.x;
  int rows = (chunk < 16) ? 256 : 128;
  int n0 = chunk*256;
  int n = n0 + tid;
  bool valid = (tid < rows);
  if (tid < 80) qs[tid] = 0.f;
  unsigned short* Qb = QTf + (size_t)b*QTF_B + ((n>>5)*512 + (n&31));
  // ---- phase A: thoughtIn -> QTf rows 1..64, 0, 77..79; row sums
  {
    const float* src = (chunk < 16) ? (conceptIn + (size_t)n0*E_) : (objIn + (size_t)b*NO*E_);
    int tot = rows*64;
    for (int i=tid; i<tot; i+=256) tile[(i>>6)*65 + (i&63)] = src[i];
  }
  __syncthreads();
  if (valid){
    Qb[0] = 0x3F80;                               // qc 0 = 1.0
    Qb[4*QTF_C + 13*32] = 0;                      // qc 77
    Qb[4*QTF_C + 14*32] = 0;                      // qc 78
    Qb[4*QTF_C + 15*32] = 0;                      // qc 79
    for (int e=0;e<64;e++){
      int qc = 1+e;
      Qb[(qc>>4)*QTF_C + (qc&15)*32] = f2bs(tile[tid*65 + e]);
    }
    for (int i=0;i<64;i++){
      int e = (i + tid) & 63;                     // stagger -> conflict-free LDS atomics
      atomicAdd(&qs[1+e], tile[tid*65+e]);
    }
  }
  __syncthreads();
  // ---- phase B: thoughtOut dots -> proj rows 65..76
  for (int i=tid;i<LP*E_;i+=256) argv[i] = conceptOut[args[b*LP + (i>>6)]*E_ + (i&63)];
  {
    const float* src = (chunk < 16) ? (conceptOut + (size_t)n0*E_) : (objOut + (size_t)b*NO*E_);
    int tot = rows*64;
    for (int i=tid; i<tot; i+=256) tile[(i>>6)*65 + (i&63)] = src[i];
  }
  __syncthreads();
  float dots[LP];
  #pragma unroll
  for (int t=0;t<LP;t++) dots[t] = 0.f;
  for (int e=0;e<64;e++){
    float o = tile[tid*65 + e];
    #pragma unroll
    for (int t=0;t<LP;t++) dots[t] += o*argv[t*64+e];
  }
  #pragma unroll
  for (int t=0;t<LP;t++){
    float v = valid ? dots[t]*(1.f/E_) : 0.f;
    if (valid){
      int qc = PROJ0+t;
      Qb[(qc>>4)*QTF_C + (qc&15)*32] = f2bs(v);
    }
    float r = v;
    #pragma unroll
    for (int off=32; off>0; off>>=1) r += __shfl_down(r, off, 64);
    if ((tid & 63) == 0) atomicAdd(&qs[PROJ0+t], r);
  }
  __syncthreads();
  if (tid < 80) atomicAdd(&qsum[b*QC + tid], qs[tid]);
  if (chunk == 0 && tid == 0) atomicAdd(&qsum[b*QC], (float)NN);
}

__device__ __forceinline__ void mid_base(int blk,
                       const float* conceptOut, const float* objOut,
                       const unsigned short* awFrag,
                       unsigned short* AoptC, unsigned short* AoptO){
  int n0 = blk * 64;
  int tid = threadIdx.x;
  int w = tid >> 6, l = tid & 63, quad = l >> 4, lq = l & 15;
  int n = n0 + w*16 + lq;
  const float* src = (n < NC) ? (conceptOut + (size_t)n*E_) : (objOut + (size_t)(n-NC)*E_);
  f32x4 acc[16];
  #pragma unroll
  for (int m=0;m<16;m++) acc[m] = (f32x4){0.f,0.f,0.f,0.f};
  #pragma unroll
  for (int kc=0;kc<2;kc++){
    s16x8 bfr;
    #pragma unroll
    for (int j=0;j<8;j++) bfr[j] = (short)f2bs(src[kc*32 + quad*8 + j]);
    const unsigned short* ap = awFrag + ((size_t)(kc*16)*64 + l)*8;
    #pragma unroll
    for (int m=0;m<16;m++){
      s16x8 af = *(const s16x8*)(ap + (size_t)m*64*8);
      acc[m] = __builtin_amdgcn_mfma_f32_16x16x32_bf16(af, bfr, acc[m], 0, 0, 0);
    }
  }
  int nl = n & 31;
  if (n < NC){
    int nch = n >> 5;
    #pragma unroll
    for (int m=0;m<16;m++){
      #pragma unroll
      for (int r=0;r<4;r++)
        AoptC[(size_t)(m*128 + nch)*512 + (quad*4+r)*32 + nl] = f2bs(acc[m][r]);
    }
  } else {
    int no = n - NC; int bb = no >> 7; int oc = (no & 127) >> 5;
    #pragma unroll
    for (int m=0;m<16;m++){
      #pragma unroll
      for (int r=0;r<4;r++)
        AoptO[(size_t)((bb*16 + m)*4 + oc)*512 + (quad*4+r)*32 + nl] = f2bs(acc[m][r]);
    }
  }
}

__global__ __launch_bounds__(256) void k_mid(
    const float* conceptIn, const float* conceptOut,
    const float* meta_init, const float* mw1, const float* mb1, const float* mw2, const float* mb2,
    const float* aw1, const float* ab1, const int* ops, const int* args,
    const float* objIn, const float* objOut, const unsigned short* awFrag,
    float* metaAll, float* metaH, unsigned short* QTf, float* qsum,
    unsigned short* AoptC, unsigned short* AoptO){
  __shared__ __align__(16) char smem[133888];
  int mb = blockIdx.x;
  if (mb < 8)
    mid_meta(smem, mb, conceptOut, meta_init, mw1, mb1, mw2, mb2, aw1, ab1, ops, args, metaAll, metaH);
  else if (mb < 144)
    mid_qt(smem, mb-8, conceptIn, conceptOut, args, objIn, objOut, QTf, qsum);
  else
    mid_base(mb-144, conceptOut, objOut, awFrag, AoptC, AoptO);
}

// ---------------- k_T (MFMA v3): fragment-contiguous loads; waves split K; LDS reduce ----------------
__global__ __launch_bounds__(256) void k_T(const unsigned short* AoptC, const unsigned short* AoptO,
                                           const unsigned short* QTf, const float* metaH, float* T){
  __shared__ float Lred[4*5120];
  int bid = blockIdx.x;
  int ht = bid & 3; int bt = bid >> 2; int b = bt / LP;
  int tid = threadIdx.x;
  int w = tid >> 6, l = tid & 63, quad = l >> 4, lq = l & 15;
  int off = lq*32 + quad*8;
  float mh[4];
  const unsigned short* aC[4];
  const unsigned short* aO[4];
  #pragma unroll
  for (int s=0;s<4;s++){
    int hA = ht*64 + s*16 + lq;
    mh[s] = metaH[(size_t)bt*H_ + hA];
    aC[s] = AoptC + (size_t)(ht*4+s)*128*512 + off;
    aO[s] = AoptO + (size_t)(b*16 + ht*4+s)*4*512 + off;
  }
  const unsigned short* bQ[5];
  #pragma unroll
  for (int c=0;c<5;c++) bQ[c] = QTf + (size_t)(b*5+c)*QTF_C + off;
  f32x4 acc[4][5];
  #pragma unroll
  for (int s=0;s<4;s++){
    #pragma unroll
    for (int c=0;c<5;c++) acc[s][c] = (f32x4){0.f,0.f,0.f,0.f};
  }
  int c0 = w*33;                            // this wave's chunk quarter
  #pragma unroll 2
  for (int it=0; it<33; it++){
    int nchunk = c0 + it;
    s16x8 bfr[5];
    #pragma unroll
    for (int c=0;c<5;c++) bfr[c] = *(const s16x8*)(bQ[c] + (size_t)nchunk*512);
    #pragma unroll
    for (int s=0;s<4;s++){
      s16x8 araw = (nchunk < 128) ? *(const s16x8*)(aC[s] + (size_t)nchunk*512)
                                  : *(const s16x8*)(aO[s] + (size_t)(nchunk-128)*512);
      s16x8 af;
      #pragma unroll
      for (int j=0;j<8;j++){
        float v = fmaxf(bs2f((unsigned short)araw[j]) + mh[s], 0.f);
        af[j] = (short)f2bs(v);
      }
      #pragma unroll
      for (int c=0;c<5;c++)
        acc[s][c] = __builtin_amdgcn_mfma_f32_16x16x32_bf16(af, bfr[c], acc[s][c], 0, 0, 0);
    }
  }
  #pragma unroll
  for (int s=0;s<4;s++){
    #pragma unroll
    for (int c=0;c<5;c++)
      *(f32x4*)&Lred[w*5120 + (s*5+c)*256 + l*4] = acc[s][c];
  }
  __syncthreads();
  float* Tp = T + (size_t)bt*H_*QC;
  for (int i=tid; i<5120; i+=256){
    float v = Lred[i] + Lred[5120+i] + Lred[2*5120+i] + Lred[3*5120+i];
    int sc = i >> 8, ll = (i>>2)&63, r = i&3;
    int s = sc/5, c = sc - s*5;
    int h = ht*64 + s*16 + (ll>>4)*4 + r;
    int qc = c*16 + (ll&15);
    Tp[(size_t)h*QC + qc] = v;
  }
}

// ---------------- k_U: Utilde[b,t] = (w2^T T[b,t] + b2 (x) qsum_b) / N ----------------
__global__ __launch_bounds__(256) void k_U(const float* T, const float* w2, const float* b2v,
                                           const float* qsum, float* Ut){
  __shared__ float Wt[32][64];
  __shared__ float Tt[32*QC];
  int bt = blockIdx.x; int b = bt / LP;
  int tid = threadIdx.x;
  int el = tid & 15, ql = tid >> 4;
  float acc[4][5];
  #pragma unroll
  for (int i=0;i<4;i++){
    #pragma unroll
    for (int j=0;j<5;j++) acc[i][j]=0.f;
  }
  const float* Tb = T + (size_t)bt*H_*QC;
  for (int k0=0;k0<H_;k0+=32){
    for (int i=tid;i<2048;i+=256){ int kk=i>>6, ee=i&63;
      Wt[kk][ee] = w2[(k0+kk)*E_ + ee]; }
    const float* tsrc = Tb + (size_t)k0*QC;
    for (int i=tid;i<32*QC;i+=256) Tt[i] = tsrc[i];
    __syncthreads();
    #pragma unroll 4
    for (int kk=0;kk<32;kk++){
      float4 wv = *(const float4*)&Wt[kk][el*4];
      float ww[4] = {wv.x, wv.y, wv.z, wv.w};
      const float* tp = &Tt[kk*QC + ql*5];
      #pragma unroll
      for (int j=0;j<5;j++){
        float tv = tp[j];
        #pragma unroll
        for (int i=0;i<4;i++) acc[i][j] = fmaf(ww[i], tv, acc[i][j]);
      }
    }
    __syncthreads();
  }
  const float invN = 1.f/NN;
  float be[4]; float qv[5];
  #pragma unroll
  for (int i=0;i<4;i++) be[i] = b2v[el*4+i];
  #pragma unroll
  for (int j=0;j<5;j++) qv[j] = qsum[b*QC + ql*5+j];
  float* Up = Ut + (size_t)bt*E_*QC;
  #pragma unroll
  for (int i=0;i<4;i++){
    #pragma unroll
    for (int j=0;j<5;j++)
      Up[(el*4+i)*QC + ql*5+j] = (acc[i][j] + be[i]*qv[j]) * invN;
  }
}

// ---------------- k_rec: 12-step recurrence; double-buffered U staging ----------------
__global__ __launch_bounds__(256) void k_rec(const float* Ut, const float* metaAll,
                                             const int* ops, const float* att_init, float* Cm){
  __shared__ float C[QC*A_];
  __shared__ float M[E_*A_];
  __shared__ float Ul[2][64*81];
  int b = blockIdx.x, tid = threadIdx.x;
  for (int i=tid;i<QC*A_;i+=256) C[i] = 0.f;
  __syncthreads();
  if (tid < A_) C[tid] = att_init[tid];
  // preload t=0
  {
    const float* U = Ut + (size_t)(b*LP)*E_*QC;
    #pragma unroll
    for (int k=0;k<5;k++){
      int i = tid*4 + k*1024;
      float4 v = *(const float4*)&U[i];
      int r = i/80, c = i%80;
      Ul[0][r*81+c] = v.x; Ul[0][r*81+c+1] = v.y; Ul[0][r*81+c+2] = v.z; Ul[0][r*81+c+3] = v.w;
    }
  }
  __syncthreads();
  int el = tid & 15, al = tid >> 4;
  for (int t=0;t<LP;t++){
    float4 rv[5];
    if (t < LP-1){
      const float* U = Ut + (size_t)(b*LP+t+1)*E_*QC;
      #pragma unroll
      for (int k=0;k<5;k++) rv[k] = *(const float4*)&U[tid*4 + k*1024];
    }
    const float* Uc = Ul[t&1];
    float acc[4][4];
    #pragma unroll
    for (int i=0;i<4;i++){
      #pragma unroll
      for (int k=0;k<4;k++) acc[i][k]=0.f;
    }
    for (int j=0;j<QC;j++){
      float u[4];
      #pragma unroll
      for (int i=0;i<4;i++) u[i] = Uc[(el*4+i)*81 + j];
      float4 c4 = *(const float4*)&C[j*A_ + al*4];
      float cc[4] = {c4.x, c4.y, c4.z, c4.w};
      #pragma unroll
      for (int i=0;i<4;i++){
        #pragma unroll
        for (int k=0;k<4;k++) acc[i][k] = fmaf(u[i], cc[k], acc[i][k]);
      }
    }
    #pragma unroll
    for (int i=0;i<4;i++){
      #pragma unroll
      for (int k=0;k<4;k++) M[(el*4+i)*A_ + al*4+k] = acc[i][k];
    }
    int op = ops[b*LP + t];
    float tr  = (op==2) ? 1.f : 0.f;
    float ins = (op==1) ? 1.f : 0.f;
    __syncthreads();
    for (int i=tid;i<E_*A_;i+=256) C[A_ + i] += tr*M[i];
    if (tid < A_) C[(PROJ0+t)*A_ + tid] += ins*metaAll[(b*LP+t)*A_ + tid];
    if (t < LP-1){
      float* Un = Ul[(t+1)&1];
      #pragma unroll
      for (int k=0;k<5;k++){
        int i = tid*4 + k*1024;
        int r = i/80, c = i%80;
        Un[r*81+c]=rv[k].x; Un[r*81+c+1]=rv[k].y; Un[r*81+c+2]=rv[k].z; Un[r*81+c+3]=rv[k].w;
      }
    }
    __syncthreads();
  }
  for (int i=tid;i<QC*A_;i+=256) Cm[b*QC*A_ + i] = C[i];
}

// ---------------- k_out: ol[b,n] = ||C^T q_n||^2 / 64 (reads QTf layout) ----------------
__global__ __launch_bounds__(256) void k_out(const unsigned short* QTf, const float* Cm,
                                             float* ol, float* esum){
  __shared__ float C[QC*A_];
  __shared__ float wsum[4];
  int b = blockIdx.x / NCHUNK, chunk = blockIdx.x % NCHUNK;
  int tid = threadIdx.x;
  for (int i=tid;i<QC*A_;i+=256) C[i] = Cm[b*QC*A_ + i];
  __syncthreads();
  int n = chunk*256 + tid;
  float contrib = 0.f;
  if (n < NN){
    float y[A_];
    #pragma unroll
    for (int a=0;a<A_;a++) y[a]=0.f;
    const unsigned short* Qb = QTf + (size_t)b*QTF_B + ((n>>5)*512 + (n&31));
    for (int j=0;j<QC;j++){
      float qvv = bs2f(Qb[(j>>4)*QTF_C + (j&15)*32]);
      const float* Cj = &C[j*A_];
      #pragma unroll
      for (int a=0;a<A_;a++) y[a] = fmaf(qvv, Cj[a], y[a]);
    }
    float s = 0.f;
    #pragma unroll
    for (int a=0;a<A_;a++) s = fmaf(y[a], y[a], s);
    float o = s * (1.f/A_);
    ol[(size_t)b*NN + n] = o;
    contrib = expf(o);
  }
  #pragma unroll
  for (int off=32; off>0; off>>=1) contrib += __shfl_down(contrib, off, 64);
  if ((tid & 63) == 0) wsum[tid>>6] = contrib;
  __syncthreads();
  if (tid == 0) atomicAdd(&esum[b], wsum[0]+wsum[1]+wsum[2]+wsum[3]);
}

// ---------------- k_fin ----------------
__global__ void k_fin(const float* ol, const float* esum, const int* flag, void* out){
  int idx = blockIdx.x*256 + threadIdx.x;
  if (idx < B_*NN){
    int b = idx / NN;
    float v = ol[idx] - logf(esum[b]);
    if (*flag) ((float*)out)[idx] = v;
    else       ((bf16*)out)[idx]  = __float2bfloat16(v);
  }
}

extern "C" void kernel_launch(void* const* d_in, const int* in_sizes, int n_in,
                              void* d_out, int out_size, void* d_ws, size_t ws_size,
                              hipStream_t stream) {
  (void)in_sizes; (void)n_in; (void)out_size; (void)ws_size;
  const int* ops  = (const int*)d_in[17];
  const int* args = (const int*)d_in[18];
  const int* gtc  = (const int*)d_in[19];
  const int* gta  = (const int*)d_in[20];

  float* ws = (float*)d_ws;
  int* flag = (int*)ws;
  float* W  = ws + 16;

  const float* conceptIn  = W + 65536;
  const float* conceptOut = W + 327680;
  const float* meta_init  = W + 589824;
  const float* att_init   = W + 589888;
  const float* aw1        = W + 589952;
  const float* ab1        = W + 622720;
  const float* aw2        = W + 622976;
  const float* ab2        = W + 639360;
  const float* mw1        = W + 639424;
  const float* mb1        = W + 672192;
  const float* mw2        = W + 672448;
  const float* mb2        = W + 688832;

  constexpr size_t OFF_OBJIN   = 16 + TOT_IN;            // 688912
  constexpr size_t OFF_OBJOUT  = OFF_OBJIN  + 65536;
  constexpr size_t OFF_METAALL = OFF_OBJOUT + 65536;
  constexpr size_t OFF_METAH   = OFF_METAALL + 6144;
  constexpr size_t OFF_QSUM    = OFF_METAH  + 24576;
  constexpr size_t OFF_ESUM    = OFF_QSUM   + 640;
  constexpr size_t OFF_T       = OFF_ESUM   + 16;
  constexpr size_t OFF_UT      = OFF_T      + 1966080;
  constexpr size_t OFF_CM      = OFF_UT     + 491520;
  constexpr size_t OFF_OL      = OFF_CM     + 40960;
  constexpr size_t OFF_QTF     = OFF_OL     + 33792;     // 8*5*132*512 shorts = 1351680 floats
  constexpr size_t OFF_AOPTC   = OFF_QTF    + 1351680;   // 16*128*512 shorts = 524288 floats
  constexpr size_t OFF_AOPTO   = OFF_AOPTC  + 524288;    // 8*16*4*512 shorts = 131072 floats
  constexpr size_t OFF_AWF     = OFF_AOPTO  + 131072;    // 16384 shorts = 8192 floats
  // end = OFF_AWF + 8192 = 5,398,944 floats ~= 21.6 MB

  float* objIn   = ws + OFF_OBJIN;
  float* objOut  = ws + OFF_OBJOUT;
  float* metaAll = ws + OFF_METAALL;
  float* metaH   = ws + OFF_METAH;
  float* qsum    = ws + OFF_QSUM;
  float* esum    = ws + OFF_ESUM;
  float* T       = ws + OFF_T;
  float* Ut      = ws + OFF_UT;
  float* Cm      = ws + OFF_CM;
  float* ol      = ws + OFF_OL;
  unsigned short* QTf    = (unsigned short*)(ws + OFF_QTF);
  unsigned short* AoptC  = (unsigned short*)(ws + OFF_AOPTC);
  unsigned short* AoptO  = (unsigned short*)(ws + OFF_AOPTO);
  unsigned short* awFrag = (unsigned short*)(ws + OFF_AWF);

  hipMemsetAsync(qsum, 0, (640 + 16)*sizeof(float), stream);   // qsum + esum

  Ptr16 ps;
  const int src_idx[16] = {0,1,2,3,4,5,6,8,9,10,11,12,13,14,15,16};
  for (int i=0;i<16;i++) ps.p[i] = d_in[src_idx[i]];

  k_detect<<<1, 256, 0, stream>>>(d_in[4], flag);
  k_prep  <<<3011, 256, 0, stream>>>(ps, flag, W, awFrag, gtc, gta, objIn, objOut);
  k_mid   <<<224, 256, 0, stream>>>(conceptIn, conceptOut, meta_init, mw1, mb1, mw2, mb2,
                                    aw1, ab1, ops, args, objIn, objOut, awFrag,
                                    metaAll, metaH, QTf, qsum, AoptC, AoptO);
  k_T     <<<B_*LP*4, 256, 0, stream>>>(AoptC, AoptO, QTf, metaH, T);
  k_U     <<<B_*LP, 256, 0, stream>>>(T, aw2, ab2, qsum, Ut);
  k_rec   <<<B_, 256, 0, stream>>>(Ut, metaAll, ops, att_init, Cm);
  k_out   <<<B_*NCHUNK, 256, 0, stream>>>(QTf, Cm, ol, esum);
  k_fin   <<<(B_*NN + 255)/256, 256, 0, stream>>>(ol, esum, flag, d_out);
}

// Round 7
// 336.298 us; speedup vs baseline: 5.5185x; 1.1611x over previous
//
#include <hip/hip_runtime.h>
#include <hip/hip_bf16.h>

typedef __hip_bfloat16 bf16;
typedef float f32x4 __attribute__((ext_vector_type(4)));
typedef short s16x8 __attribute__((ext_vector_type(8)));

#define B_    8
#define LP    12
#define NC    4096
#define NO    128
#define NAPO  8
#define NN    4224
#define E_    64
#define A_    64
#define H_    256
#define QC    80
#define PROJ0 65
#define NCHUNK 17

#define TOT_IN 688896
#define QTF_C  67584     // 132*512 shorts per (b,c) group
#define QTF_B  337920    // 5*QTF_C per batch

struct Ptr16 { const void* p[16]; };
union U8 { s16x8 v; unsigned u[4]; };

__device__ __forceinline__ float b2f(bf16 x){ return __bfloat162float(x); }
__device__ __forceinline__ float bs2f(unsigned short s){
  union { unsigned u; float f; } x; x.u = ((unsigned)s) << 16; return x.f;
}
__device__ __forceinline__ unsigned short f2bs(float f){
  bf16 h = __float2bfloat16(f);
  union { bf16 h; unsigned short s; } x; x.h = h; return x.s;
}
__device__ __forceinline__ unsigned pack2(float a, float b){
  return (unsigned)f2bs(a) | ((unsigned)f2bs(b) << 16);
}
__device__ __forceinline__ float lo16f(unsigned w){
  union { unsigned u; float f; } x; x.u = w << 16; return x.f;
}
__device__ __forceinline__ float hi16f(unsigned w){
  union { unsigned u; float f; } x; x.u = w & 0xffff0000u; return x.f;
}
__device__ __forceinline__ float rdval(const void* p, int i, int fl){
  return fl ? ((const float*)p)[i] : bs2f(((const unsigned short*)p)[i]);
}

// ---------------- k_detect: fp32 (flag=1) vs bf16 (flag=0) input data ----------------
__global__ void k_detect(const void* probe, int* flag){
  __shared__ int cnt;
  if (threadIdx.x == 0) cnt = 0;
  __syncthreads();
  const unsigned short* u = (const unsigned short*)probe;
  int c = 0;
  for (int i = threadIdx.x; i < 4096; i += 256){
    int e = (u[i] >> 7) & 0xFF;
    if (e >= 137) c++;
  }
  atomicAdd(&cnt, c);
  __syncthreads();
  if (threadIdx.x == 0) *flag = (cnt >= 8) ? 1 : 0;
}

// ---------------- k_prep: convert(2691) + awFrag pack(64) + obj embeddings(256) ----------------
__global__ void k_prep(Ptr16 ps, const int* flag, float* dst,
                       unsigned short* awFrag,
                       const int* gtc, const int* gta,
                       float* objIn, float* objOut){
  int mb = blockIdx.x;
  int fl = *flag;
  if (mb < 2691){
    int idx = mb*256 + threadIdx.x;
    if (idx >= TOT_IN) return;
    constexpr int cum[17] = {0,16384,32768,49152,65536,327680,589824,589888,589952,
                             622720,622976,639360,639424,672192,672448,688832,688896};
    int t = 0;
    #pragma unroll
    for (int i=1;i<16;i++) if (idx >= cum[i]) t = i;
    dst[idx] = rdval(ps.p[t], idx - cum[t], fl);
  } else if (mb < 2755){
    int idx = (mb-2691)*256 + threadIdx.x;      // < 16384
    int j = idx & 7;
    int lane = (idx >> 3) & 63;
    int m = (idx >> 9) & 15;
    int kc = idx >> 13;
    int e = kc*32 + (lane>>4)*8 + j;
    int h = m*16 + (lane&15);
    awFrag[idx] = f2bs(rdval(ps.p[8], e*H_ + h, fl));
  } else {
    int idx = (mb-2755)*256 + threadIdx.x;      // < 65536
    int e = idx & 63; int bo = idx >> 6;
    int cls = gtc[bo];
    float vi = rdval(ps.p[0], cls*E_ + e, fl);
    float vo = rdval(ps.p[1], cls*E_ + e, fl);
    const int* ga = gta + bo*NAPO;
    #pragma unroll
    for (int j=0;j<NAPO;j++){
      int at = ga[j];
      vi += rdval(ps.p[2], at*E_ + e, fl);
      vo += rdval(ps.p[3], at*E_ + e, fl);
    }
    objIn[idx] = vi; objOut[idx] = vo;
  }
}

// ================ k_mid: meta(8) | QTf+qsum(136) | baseT->Aopt(80) ================
__device__ __forceinline__ void mid_meta(char* smem, int b,
                       const float* conceptOut, const float* meta_init,
                       const float* mw1, const float* mb1, const float* mw2, const float* mb2,
                       const float* aw1, const float* ab1,
                       const int* ops, const int* args,
                       float* metaAll, float* metaH){
  unsigned* mw1p = (unsigned*)smem;               // 64*256 = 65536 B
  unsigned* mw2p = (unsigned*)(smem + 65536);     // 128*64 = 32768 B
  unsigned* aw1p = (unsigned*)(smem + 98304);     // 32*256 = 32768 B
  float* meta_s  = (float*)(smem + 131072);
  float* argx    = (float*)(smem + 131328);
  float* hid     = (float*)(smem + 131584);
  float* part    = (float*)(smem + 132608);
  int tid = threadIdx.x;

  for (int i=tid; i<64*256; i+=256){
    int j2 = i >> 8, t = i & 255;
    mw1p[i] = pack2(mw1[(2*j2)*H_ + t], mw1[(2*j2+1)*H_ + t]);
  }
  for (int i=tid; i<128*64; i+=256){
    int h2 = i >> 6, a = i & 63;
    mw2p[i] = pack2(mw2[(2*h2)*A_ + a], mw2[(2*h2+1)*A_ + a]);
  }
  for (int i=tid; i<32*256; i+=256){
    int a2 = i >> 8, t = i & 255;
    aw1p[i] = pack2(aw1[(E_+2*a2)*H_ + t], aw1[(E_+2*a2+1)*H_ + t]);
  }
  float r_mb1 = mb1[tid];
  float r_ab1 = ab1[tid];
  float r_mb2 = (tid < A_) ? mb2[tid] : 0.f;
  if (tid < A_) meta_s[tid] = meta_init[tid];
  __syncthreads();

  for (int t=0;t<LP;t++){
    int op  = ops[b*LP + t];
    int arg = args[b*LP + t];
    if (tid >= 64 && tid < 128) argx[tid-64] = conceptOut[arg*E_ + (tid-64)];
    __syncthreads();
    float acc = r_mb1;
    for (int j2=0;j2<32;j2++){
      unsigned w = mw1p[j2*256 + tid];
      float2 xp = *(const float2*)&meta_s[2*j2];
      acc = fmaf(xp.x, lo16f(w), acc);
      acc = fmaf(xp.y, hi16f(w), acc);
    }
    for (int j2=0;j2<32;j2++){
      unsigned w = mw1p[(32+j2)*256 + tid];
      float2 xp = *(const float2*)&argx[2*j2];
      acc = fmaf(xp.x, lo16f(w), acc);
      acc = fmaf(xp.y, hi16f(w), acc);
    }
    hid[tid] = fmaxf(acc, 0.f);
    __syncthreads();
    int wv_ = tid >> 6, l = tid & 63;
    float acc2 = 0.f;
    for (int h2 = wv_*32; h2 < wv_*32+32; h2++){
      unsigned w = mw2p[h2*64 + l];
      float2 hp = *(const float2*)&hid[2*h2];
      acc2 = fmaf(hp.x, lo16f(w), acc2);
      acc2 = fmaf(hp.y, hi16f(w), acc2);
    }
    part[wv_*64 + l] = acc2;
    __syncthreads();
    if (tid < A_){
      float s = part[tid] + part[64+tid] + part[128+tid] + part[192+tid] + r_mb2;
      float nm = (op==0) ? s : meta_s[tid];
      meta_s[tid] = nm;
      metaAll[(b*LP+t)*A_ + tid] = nm;
    }
    __syncthreads();
    float mh = r_ab1;
    for (int a2=0;a2<32;a2++){
      unsigned w = aw1p[a2*256 + tid];
      float2 mp = *(const float2*)&meta_s[2*a2];
      mh = fmaf(mp.x, lo16f(w), mh);
      mh = fmaf(mp.y, hi16f(w), mh);
    }
    metaH[(b*LP+t)*H_ + tid] = mh;
  }
}

__device__ __forceinline__ void mid_qt(char* smem, int idx,
                       const float* conceptIn, const float* conceptOut, const int* args,
                       const float* objIn, const float* objOut,
                       unsigned short* QTf, float* qsum){
  float* tile = (float*)smem;                  // 256*65*4 = 66560 B
  float* argv = (float*)(smem + 66560);
  float* qs   = (float*)(smem + 69632);
  int b = idx / NCHUNK, chunk = idx % NCHUNK;
  int tid = threadIdx.x;
  int rows = (chunk < 16) ? 256 : 128;
  int n0 = chunk*256;
  int n = n0 + tid;
  bool valid = (tid < rows);
  if (tid < 80) qs[tid] = 0.f;
  unsigned short* Qb = QTf + (size_t)b*QTF_B + ((n>>5)*512 + (n&31));
  {
    const float* src = (chunk < 16) ? (conceptIn + (size_t)n0*E_) : (objIn + (size_t)b*NO*E_);
    int tot = rows*64;
    for (int i=tid; i<tot; i+=256) tile[(i>>6)*65 + (i&63)] = src[i];
  }
  __syncthreads();
  if (valid){
    Qb[0] = 0x3F80;
    Qb[4*QTF_C + 13*32] = 0;
    Qb[4*QTF_C + 14*32] = 0;
    Qb[4*QTF_C + 15*32] = 0;
    for (int e=0;e<64;e++){
      int qc = 1+e;
      Qb[(qc>>4)*QTF_C + (qc&15)*32] = f2bs(tile[tid*65 + e]);
    }
    for (int i=0;i<64;i++){
      int e = (i + tid) & 63;
      atomicAdd(&qs[1+e], tile[tid*65+e]);
    }
  }
  __syncthreads();
  for (int i=tid;i<LP*E_;i+=256) argv[i] = conceptOut[args[b*LP + (i>>6)]*E_ + (i&63)];
  {
    const float* src = (chunk < 16) ? (conceptOut + (size_t)n0*E_) : (objOut + (size_t)b*NO*E_);
    int tot = rows*64;
    for (int i=tid; i<tot; i+=256) tile[(i>>6)*65 + (i&63)] = src[i];
  }
  __syncthreads();
  float dots[LP];
  #pragma unroll
  for (int t=0;t<LP;t++) dots[t] = 0.f;
  for (int e=0;e<64;e++){
    float o = tile[tid*65 + e];
    #pragma unroll
    for (int t=0;t<LP;t++) dots[t] += o*argv[t*64+e];
  }
  #pragma unroll
  for (int t=0;t<LP;t++){
    float v = valid ? dots[t]*(1.f/E_) : 0.f;
    if (valid){
      int qc = PROJ0+t;
      Qb[(qc>>4)*QTF_C + (qc&15)*32] = f2bs(v);
    }
    float r = v;
    #pragma unroll
    for (int off=32; off>0; off>>=1) r += __shfl_down(r, off, 64);
    if ((tid & 63) == 0) atomicAdd(&qs[PROJ0+t], r);
  }
  __syncthreads();
  if (tid < 80) atomicAdd(&qsum[b*QC + tid], qs[tid]);
  if (chunk == 0 && tid == 0) atomicAdd(&qsum[b*QC], (float)NN);
}

__device__ __forceinline__ void mid_base(int blk,
                       const float* conceptOut, const float* objOut,
                       const unsigned short* awFrag,
                       unsigned short* AoptC, unsigned short* AoptO){
  int n0 = blk * 64;
  int tid = threadIdx.x;
  int w = tid >> 6, l = tid & 63, quad = l >> 4, lq = l & 15;
  int n = n0 + w*16 + lq;
  const float* src = (n < NC) ? (conceptOut + (size_t)n*E_) : (objOut + (size_t)(n-NC)*E_);
  f32x4 acc[16];
  #pragma unroll
  for (int m=0;m<16;m++) acc[m] = (f32x4){0.f,0.f,0.f,0.f};
  #pragma unroll
  for (int kc=0;kc<2;kc++){
    s16x8 bfr;
    #pragma unroll
    for (int j=0;j<8;j++) bfr[j] = (short)f2bs(src[kc*32 + quad*8 + j]);
    const unsigned short* ap = awFrag + ((size_t)(kc*16)*64 + l)*8;
    #pragma unroll
    for (int m=0;m<16;m++){
      s16x8 af = *(const s16x8*)(ap + (size_t)m*64*8);
      acc[m] = __builtin_amdgcn_mfma_f32_16x16x32_bf16(af, bfr, acc[m], 0, 0, 0);
    }
  }
  int nl = n & 31;
  if (n < NC){
    int nch = n >> 5;
    #pragma unroll
    for (int m=0;m<16;m++){
      #pragma unroll
      for (int r=0;r<4;r++)
        AoptC[(size_t)(m*128 + nch)*512 + (quad*4+r)*32 + nl] = f2bs(acc[m][r]);
    }
  } else {
    int no = n - NC; int bb = no >> 7; int oc = (no & 127) >> 5;
    #pragma unroll
    for (int m=0;m<16;m++){
      #pragma unroll
      for (int r=0;r<4;r++)
        AoptO[(size_t)((bb*16 + m)*4 + oc)*512 + (quad*4+r)*32 + nl] = f2bs(acc[m][r]);
    }
  }
}

__global__ __launch_bounds__(256) void k_mid(
    const float* conceptIn, const float* conceptOut,
    const float* meta_init, const float* mw1, const float* mb1, const float* mw2, const float* mb2,
    const float* aw1, const float* ab1, const int* ops, const int* args,
    const float* objIn, const float* objOut, const unsigned short* awFrag,
    float* metaAll, float* metaH, unsigned short* QTf, float* qsum,
    unsigned short* AoptC, unsigned short* AoptO){
  __shared__ __align__(16) char smem[133888];
  int mb = blockIdx.x;
  if (mb < 8)
    mid_meta(smem, mb, conceptOut, meta_init, mw1, mb1, mw2, mb2, aw1, ab1, ops, args, metaAll, metaH);
  else if (mb < 144)
    mid_qt(smem, mb-8, conceptIn, conceptOut, args, objIn, objOut, QTf, qsum);
  else
    mid_base(mb-144, conceptOut, objOut, awFrag, AoptC, AoptO);
}

// ---------------- k_T (MFMA v4): 2x K-split grid, uniform-base addressing, ----------------
// dword-domain relu + truncation bf16 pack, 40KB two-stage LDS reduce, dual partial outputs.
__global__ __launch_bounds__(256) void k_T(const unsigned short* AoptC, const unsigned short* AoptO,
                                           const unsigned short* QTf, const float* metaH,
                                           float* Tp0, float* Tp1){
  __shared__ float Lred[2*5120];
  int bid = blockIdx.x;
  int kh = bid & 1; int ht = (bid >> 1) & 3; int bt = bid >> 3; int b = bt / LP;
  int tid = threadIdx.x;
  int w = tid >> 6, l = tid & 63, quad = l >> 4, lq = l & 15;
  int off = lq*32 + quad*8;
  int start = kh*66 + ((w<2) ? (w*17) : (34 + (w-2)*16));
  int count = (w<2) ? 17 : 16;
  float mh[4];
  #pragma unroll
  for (int s=0;s<4;s++) mh[s] = metaH[(size_t)bt*H_ + ht*64 + s*16 + lq];
  f32x4 acc[4][5];
  #pragma unroll
  for (int s=0;s<4;s++){
    #pragma unroll
    for (int c=0;c<5;c++) acc[s][c] = (f32x4){0.f,0.f,0.f,0.f};
  }
  const unsigned short* QTb = QTf + (size_t)b*QTF_B + off;
  const unsigned short* AC  = AoptC + (size_t)(ht*4)*65536 + off;       // 65536 = 128*512
  const unsigned short* AO  = AoptO + (size_t)(b*16 + ht*4)*2048 + off; // 2048 = 4*512
  for (int it=0; it<count; it++){
    int nchunk = start + it;
    U8 bfr[5];
    #pragma unroll
    for (int c=0;c<5;c++)
      bfr[c].v = *(const s16x8*)(QTb + (size_t)c*QTF_C + (size_t)nchunk*512);
    bool isC = (nchunk < 128);
    #pragma unroll
    for (int s=0;s<4;s++){
      U8 a;
      a.v = isC ? *(const s16x8*)(AC + (size_t)s*65536 + (size_t)nchunk*512)
                : *(const s16x8*)(AO + (size_t)s*2048 + (size_t)(nchunk-128)*512);
      float mhs = mh[s];
      U8 af;
      #pragma unroll
      for (int d=0;d<4;d++){
        unsigned wv = a.u[d];
        float lo = fmaxf(__uint_as_float(wv << 16) + mhs, 0.f);
        float hi = fmaxf(__uint_as_float(wv & 0xffff0000u) + mhs, 0.f);
        af.u[d] = (__float_as_uint(hi) & 0xffff0000u) | (__float_as_uint(lo) >> 16);
      }
      #pragma unroll
      for (int c=0;c<5;c++)
        acc[s][c] = __builtin_amdgcn_mfma_f32_16x16x32_bf16(af.v, bfr[c].v, acc[s][c], 0, 0, 0);
    }
  }
  // two-stage reduce: waves 2,3 stash; waves 0,1 merge; then pairwise sum on store
  if (w >= 2){
    #pragma unroll
    for (int s=0;s<4;s++){
      #pragma unroll
      for (int c=0;c<5;c++)
        *(f32x4*)&Lred[(w-2)*5120 + (s*5+c)*256 + l*4] = acc[s][c];
    }
  }
  __syncthreads();
  if (w < 2){
    #pragma unroll
    for (int s=0;s<4;s++){
      #pragma unroll
      for (int c=0;c<5;c++){
        f32x4 v = *(const f32x4*)&Lred[w*5120 + (s*5+c)*256 + l*4];
        v = v + acc[s][c];
        *(f32x4*)&Lred[w*5120 + (s*5+c)*256 + l*4] = v;
      }
    }
  }
  __syncthreads();
  float* Tp = (kh ? Tp1 : Tp0) + (size_t)bt*H_*QC;
  for (int i=tid; i<5120; i+=256){
    float v = Lred[i] + Lred[5120+i];
    int sc = i >> 8, ll = (i>>2)&63, r = i&3;
    int s = sc/5, c = sc - s*5;
    int h = ht*64 + s*16 + (ll>>4)*4 + r;
    int qc = c*16 + (ll&15);
    Tp[(size_t)h*QC + qc] = v;
  }
}

// ---------------- k_U: Utilde[b,t] = (w2^T (T0+T1) + b2 (x) qsum_b) / N ----------------
__global__ __launch_bounds__(256) void k_U(const float* T0, const float* T1,
                                           const float* w2, const float* b2v,
                                           const float* qsum, float* Ut){
  __shared__ float Wt[32][64];
  __shared__ float Tt[32*QC];
  int bt = blockIdx.x; int b = bt / LP;
  int tid = threadIdx.x;
  int el = tid & 15, ql = tid >> 4;
  float acc[4][5];
  #pragma unroll
  for (int i=0;i<4;i++){
    #pragma unroll
    for (int j=0;j<5;j++) acc[i][j]=0.f;
  }
  const float* Tb0 = T0 + (size_t)bt*H_*QC;
  const float* Tb1 = T1 + (size_t)bt*H_*QC;
  for (int k0=0;k0<H_;k0+=32){
    for (int i=tid;i<2048;i+=256){ int kk=i>>6, ee=i&63;
      Wt[kk][ee] = w2[(k0+kk)*E_ + ee]; }
    const float* t0 = Tb0 + (size_t)k0*QC;
    const float* t1 = Tb1 + (size_t)k0*QC;
    for (int i=tid;i<32*QC;i+=256) Tt[i] = t0[i] + t1[i];
    __syncthreads();
    #pragma unroll 4
    for (int kk=0;kk<32;kk++){
      float4 wv = *(const float4*)&Wt[kk][el*4];
      float ww[4] = {wv.x, wv.y, wv.z, wv.w};
      const float* tp = &Tt[kk*QC + ql*5];
      #pragma unroll
      for (int j=0;j<5;j++){
        float tv = tp[j];
        #pragma unroll
        for (int i=0;i<4;i++) acc[i][j] = fmaf(ww[i], tv, acc[i][j]);
      }
    }
    __syncthreads();
  }
  const float invN = 1.f/NN;
  float be[4]; float qv[5];
  #pragma unroll
  for (int i=0;i<4;i++) be[i] = b2v[el*4+i];
  #pragma unroll
  for (int j=0;j<5;j++) qv[j] = qsum[b*QC + ql*5+j];
  float* Up = Ut + (size_t)bt*E_*QC;
  #pragma unroll
  for (int i=0;i<4;i++){
    #pragma unroll
    for (int j=0;j<5;j++)
      Up[(el*4+i)*QC + ql*5+j] = (acc[i][j] + be[i]*qv[j]) * invN;
  }
}

// ---------------- k_rec: 12-step recurrence; double-buffered U staging ----------------
__global__ __launch_bounds__(256) void k_rec(const float* Ut, const float* metaAll,
                                             const int* ops, const float* att_init, float* Cm){
  __shared__ float C[QC*A_];
  __shared__ float M[E_*A_];
  __shared__ float Ul[2][64*81];
  int b = blockIdx.x, tid = threadIdx.x;
  for (int i=tid;i<QC*A_;i+=256) C[i] = 0.f;
  __syncthreads();
  if (tid < A_) C[tid] = att_init[tid];
  {
    const float* U = Ut + (size_t)(b*LP)*E_*QC;
    #pragma unroll
    for (int k=0;k<5;k++){
      int i = tid*4 + k*1024;
      float4 v = *(const float4*)&U[i];
      int r = i/80, c = i%80;
      Ul[0][r*81+c] = v.x; Ul[0][r*81+c+1] = v.y; Ul[0][r*81+c+2] = v.z; Ul[0][r*81+c+3] = v.w;
    }
  }
  __syncthreads();
  int el = tid & 15, al = tid >> 4;
  for (int t=0;t<LP;t++){
    float4 rv[5];
    if (t < LP-1){
      const float* U = Ut + (size_t)(b*LP+t+1)*E_*QC;
      #pragma unroll
      for (int k=0;k<5;k++) rv[k] = *(const float4*)&U[tid*4 + k*1024];
    }
    const float* Uc = Ul[t&1];
    float acc[4][4];
    #pragma unroll
    for (int i=0;i<4;i++){
      #pragma unroll
      for (int k=0;k<4;k++) acc[i][k]=0.f;
    }
    for (int j=0;j<QC;j++){
      float u[4];
      #pragma unroll
      for (int i=0;i<4;i++) u[i] = Uc[(el*4+i)*81 + j];
      float4 c4 = *(const float4*)&C[j*A_ + al*4];
      float cc[4] = {c4.x, c4.y, c4.z, c4.w};
      #pragma unroll
      for (int i=0;i<4;i++){
        #pragma unroll
        for (int k=0;k<4;k++) acc[i][k] = fmaf(u[i], cc[k], acc[i][k]);
      }
    }
    #pragma unroll
    for (int i=0;i<4;i++){
      #pragma unroll
      for (int k=0;k<4;k++) M[(el*4+i)*A_ + al*4+k] = acc[i][k];
    }
    int op = ops[b*LP + t];
    float tr  = (op==2) ? 1.f : 0.f;
    float ins = (op==1) ? 1.f : 0.f;
    __syncthreads();
    for (int i=tid;i<E_*A_;i+=256) C[A_ + i] += tr*M[i];
    if (tid < A_) C[(PROJ0+t)*A_ + tid] += ins*metaAll[(b*LP+t)*A_ + tid];
    if (t < LP-1){
      float* Un = Ul[(t+1)&1];
      #pragma unroll
      for (int k=0;k<5;k++){
        int i = tid*4 + k*1024;
        int r = i/80, c = i%80;
        Un[r*81+c]=rv[k].x; Un[r*81+c+1]=rv[k].y; Un[r*81+c+2]=rv[k].z; Un[r*81+c+3]=rv[k].w;
      }
    }
    __syncthreads();
  }
  for (int i=tid;i<QC*A_;i+=256) Cm[b*QC*A_ + i] = C[i];
}

// ---------------- k_out: ol[b,n] = ||C^T q_n||^2 / 64 (reads QTf layout) ----------------
__global__ __launch_bounds__(256) void k_out(const unsigned short* QTf, const float* Cm,
                                             float* ol, float* esum){
  __shared__ float C[QC*A_];
  __shared__ float wsum[4];
  int b = blockIdx.x / NCHUNK, chunk = blockIdx.x % NCHUNK;
  int tid = threadIdx.x;
  for (int i=tid;i<QC*A_;i+=256) C[i] = Cm[b*QC*A_ + i];
  __syncthreads();
  int n = chunk*256 + tid;
  float contrib = 0.f;
  if (n < NN){
    float y[A_];
    #pragma unroll
    for (int a=0;a<A_;a++) y[a]=0.f;
    const unsigned short* Qb = QTf + (size_t)b*QTF_B + ((n>>5)*512 + (n&31));
    for (int j=0;j<QC;j++){
      float qvv = bs2f(Qb[(j>>4)*QTF_C + (j&15)*32]);
      const float* Cj = &C[j*A_];
      #pragma unroll
      for (int a=0;a<A_;a++) y[a] = fmaf(qvv, Cj[a], y[a]);
    }
    float s = 0.f;
    #pragma unroll
    for (int a=0;a<A_;a++) s = fmaf(y[a], y[a], s);
    float o = s * (1.f/A_);
    ol[(size_t)b*NN + n] = o;
    contrib = expf(o);
  }
  #pragma unroll
  for (int off=32; off>0; off>>=1) contrib += __shfl_down(contrib, off, 64);
  if ((tid & 63) == 0) wsum[tid>>6] = contrib;
  __syncthreads();
  if (tid == 0) atomicAdd(&esum[b], wsum[0]+wsum[1]+wsum[2]+wsum[3]);
}

// ---------------- k_fin ----------------
__global__ void k_fin(const float* ol, const float* esum, const int* flag, void* out){
  int idx = blockIdx.x*256 + threadIdx.x;
  if (idx < B_*NN){
    int b = idx / NN;
    float v = ol[idx] - logf(esum[b]);
    if (*flag) ((float*)out)[idx] = v;
    else       ((bf16*)out)[idx]  = __float2bfloat16(v);
  }
}

extern "C" void kernel_launch(void* const* d_in, const int* in_sizes, int n_in,
                              void* d_out, int out_size, void* d_ws, size_t ws_size,
                              hipStream_t stream) {
  (void)in_sizes; (void)n_in; (void)out_size; (void)ws_size;
  const int* ops  = (const int*)d_in[17];
  const int* args = (const int*)d_in[18];
  const int* gtc  = (const int*)d_in[19];
  const int* gta  = (const int*)d_in[20];

  float* ws = (float*)d_ws;
  int* flag = (int*)ws;
  float* W  = ws + 16;

  const float* conceptIn  = W + 65536;
  const float* conceptOut = W + 327680;
  const float* meta_init  = W + 589824;
  const float* att_init   = W + 589888;
  const float* aw1        = W + 589952;
  const float* ab1        = W + 622720;
  const float* aw2        = W + 622976;
  const float* ab2        = W + 639360;
  const float* mw1        = W + 639424;
  const float* mb1        = W + 672192;
  const float* mw2        = W + 672448;
  const float* mb2        = W + 688832;

  constexpr size_t OFF_OBJIN   = 16 + TOT_IN;            // 688912
  constexpr size_t OFF_OBJOUT  = OFF_OBJIN  + 65536;
  constexpr size_t OFF_METAALL = OFF_OBJOUT + 65536;
  constexpr size_t OFF_METAH   = OFF_METAALL + 6144;
  constexpr size_t OFF_QSUM    = OFF_METAH  + 24576;
  constexpr size_t OFF_ESUM    = OFF_QSUM   + 640;
  constexpr size_t OFF_T       = OFF_ESUM   + 16;
  constexpr size_t OFF_UT      = OFF_T      + 1966080;
  constexpr size_t OFF_CM      = OFF_UT     + 491520;
  constexpr size_t OFF_OL      = OFF_CM     + 40960;
  constexpr size_t OFF_QTF     = OFF_OL     + 33792;
  constexpr size_t OFF_AOPTC   = OFF_QTF    + 1351680;
  constexpr size_t OFF_AOPTO   = OFF_AOPTC  + 524288;
  constexpr size_t OFF_AWF     = OFF_AOPTO  + 131072;
  constexpr size_t OFF_T1      = OFF_AWF    + 8192;      // second K-half partial
  // end = OFF_T1 + 1966080 = 7,365,024 floats ~= 29.5 MB (fits: r1/r2 used 29.6 MB)

  float* objIn   = ws + OFF_OBJIN;
  float* objOut  = ws + OFF_OBJOUT;
  float* metaAll = ws + OFF_METAALL;
  float* metaH   = ws + OFF_METAH;
  float* qsum    = ws + OFF_QSUM;
  float* esum    = ws + OFF_ESUM;
  float* T0      = ws + OFF_T;
  float* T1      = ws + OFF_T1;
  float* Ut      = ws + OFF_UT;
  float* Cm      = ws + OFF_CM;
  float* ol      = ws + OFF_OL;
  unsigned short* QTf    = (unsigned short*)(ws + OFF_QTF);
  unsigned short* AoptC  = (unsigned short*)(ws + OFF_AOPTC);
  unsigned short* AoptO  = (unsigned short*)(ws + OFF_AOPTO);
  unsigned short* awFrag = (unsigned short*)(ws + OFF_AWF);

  hipMemsetAsync(qsum, 0, (640 + 16)*sizeof(float), stream);   // qsum + esum

  Ptr16 ps;
  const int src_idx[16] = {0,1,2,3,4,5,6,8,9,10,11,12,13,14,15,16};
  for (int i=0;i<16;i++) ps.p[i] = d_in[src_idx[i]];

  k_detect<<<1, 256, 0, stream>>>(d_in[4], flag);
  k_prep  <<<3011, 256, 0, stream>>>(ps, flag, W, awFrag, gtc, gta, objIn, objOut);
  k_mid   <<<224, 256, 0, stream>>>(conceptIn, conceptOut, meta_init, mw1, mb1, mw2, mb2,
                                    aw1, ab1, ops, args, objIn, objOut, awFrag,
                                    metaAll, metaH, QTf, qsum, AoptC, AoptO);
  k_T     <<<B_*LP*4*2, 256, 0, stream>>>(AoptC, AoptO, QTf, metaH, T0, T1);
  k_U     <<<B_*LP, 256, 0, stream>>>(T0, T1, aw2, ab2, qsum, Ut);
  k_rec   <<<B_, 256, 0, stream>>>(Ut, metaAll, ops, att_init, Cm);
  k_out   <<<B_*NCHUNK, 256, 0, stream>>>(QTf, Cm, ol, esum);
  k_fin   <<<(B_*NN + 255)/256, 256, 0, stream>>>(ol, esum, flag, d_out);
}

// Round 8
// 282.618 us; speedup vs baseline: 6.5666x; 1.1899x over previous
//
#include <hip/hip_runtime.h>
#include <hip/hip_bf16.h>

typedef __hip_bfloat16 bf16;
typedef float f32x4 __attribute__((ext_vector_type(4)));
typedef short s16x8 __attribute__((ext_vector_type(8)));

#define B_    8
#define LP    12
#define NC    4096
#define NO    128
#define NAPO  8
#define NN    4224
#define E_    64
#define A_    64
#define H_    256
#define QC    80
#define PROJ0 65
#define NCHUNK 17

#define TOT_IN 688896
#define QTF_C  67584     // 132*512 shorts per (b,c) group
#define QTF_B  337920    // 5*QTF_C per batch

struct Ptr16 { const void* p[16]; };
union U8 { s16x8 v; unsigned u[4]; };

__device__ __forceinline__ float b2f(bf16 x){ return __bfloat162float(x); }
__device__ __forceinline__ float bs2f(unsigned short s){
  union { unsigned u; float f; } x; x.u = ((unsigned)s) << 16; return x.f;
}
__device__ __forceinline__ unsigned short f2bs(float f){
  bf16 h = __float2bfloat16(f);
  union { bf16 h; unsigned short s; } x; x.h = h; return x.s;
}
__device__ __forceinline__ unsigned pack2(float a, float b){
  return (unsigned)f2bs(a) | ((unsigned)f2bs(b) << 16);
}
__device__ __forceinline__ float lo16f(unsigned w){
  union { unsigned u; float f; } x; x.u = w << 16; return x.f;
}
__device__ __forceinline__ float hi16f(unsigned w){
  union { unsigned u; float f; } x; x.u = w & 0xffff0000u; return x.f;
}
__device__ __forceinline__ float rdval(const void* p, int i, int fl){
  return fl ? ((const float*)p)[i] : bs2f(((const unsigned short*)p)[i]);
}

// ---------------- k_detect: fp32 (flag=1) vs bf16 (flag=0) input data ----------------
__global__ void k_detect(const void* probe, int* flag){
  __shared__ int cnt;
  if (threadIdx.x == 0) cnt = 0;
  __syncthreads();
  const unsigned short* u = (const unsigned short*)probe;
  int c = 0;
  for (int i = threadIdx.x; i < 4096; i += 256){
    int e = (u[i] >> 7) & 0xFF;
    if (e >= 137) c++;
  }
  atomicAdd(&cnt, c);
  __syncthreads();
  if (threadIdx.x == 0) *flag = (cnt >= 8) ? 1 : 0;
}

// ---------------- k_prep: convert(2691) + awFrag pack(64) + obj embeddings(256) ----------------
__global__ void k_prep(Ptr16 ps, const int* flag, float* dst,
                       unsigned short* awFrag,
                       const int* gtc, const int* gta,
                       float* objIn, float* objOut){
  int mb = blockIdx.x;
  int fl = *flag;
  if (mb < 2691){
    int idx = mb*256 + threadIdx.x;
    if (idx >= TOT_IN) return;
    constexpr int cum[17] = {0,16384,32768,49152,65536,327680,589824,589888,589952,
                             622720,622976,639360,639424,672192,672448,688832,688896};
    int t = 0;
    #pragma unroll
    for (int i=1;i<16;i++) if (idx >= cum[i]) t = i;
    dst[idx] = rdval(ps.p[t], idx - cum[t], fl);
  } else if (mb < 2755){
    int idx = (mb-2691)*256 + threadIdx.x;      // < 16384
    int j = idx & 7;
    int lane = (idx >> 3) & 63;
    int m = (idx >> 9) & 15;
    int kc = idx >> 13;
    int e = kc*32 + (lane>>4)*8 + j;
    int h = m*16 + (lane&15);
    awFrag[idx] = f2bs(rdval(ps.p[8], e*H_ + h, fl));
  } else {
    int idx = (mb-2755)*256 + threadIdx.x;      // < 65536
    int e = idx & 63; int bo = idx >> 6;
    int cls = gtc[bo];
    float vi = rdval(ps.p[0], cls*E_ + e, fl);
    float vo = rdval(ps.p[1], cls*E_ + e, fl);
    const int* ga = gta + bo*NAPO;
    #pragma unroll
    for (int j=0;j<NAPO;j++){
      int at = ga[j];
      vi += rdval(ps.p[2], at*E_ + e, fl);
      vo += rdval(ps.p[3], at*E_ + e, fl);
    }
    objIn[idx] = vi; objOut[idx] = vo;
  }
}

// ================ k_mid: meta(8) | QTf+qsum(136) | baseT->Aopt(80) ================
__device__ __forceinline__ void mid_meta(char* smem, int b,
                       const float* conceptOut, const float* meta_init,
                       const float* mw1, const float* mb1, const float* mw2, const float* mb2,
                       const float* aw1, const float* ab1,
                       const int* ops, const int* args,
                       float* metaAll, float* metaH){
  unsigned* mw1p = (unsigned*)smem;               // 64*256 = 65536 B
  unsigned* mw2p = (unsigned*)(smem + 65536);     // 128*64 = 32768 B
  unsigned* aw1p = (unsigned*)(smem + 98304);     // 32*256 = 32768 B
  float* meta_s  = (float*)(smem + 131072);
  float* argx    = (float*)(smem + 131328);
  float* hid     = (float*)(smem + 131584);
  float* part    = (float*)(smem + 132608);
  int tid = threadIdx.x;

  for (int i=tid; i<64*256; i+=256){
    int j2 = i >> 8, t = i & 255;
    mw1p[i] = pack2(mw1[(2*j2)*H_ + t], mw1[(2*j2+1)*H_ + t]);
  }
  for (int i=tid; i<128*64; i+=256){
    int h2 = i >> 6, a = i & 63;
    mw2p[i] = pack2(mw2[(2*h2)*A_ + a], mw2[(2*h2+1)*A_ + a]);
  }
  for (int i=tid; i<32*256; i+=256){
    int a2 = i >> 8, t = i & 255;
    aw1p[i] = pack2(aw1[(E_+2*a2)*H_ + t], aw1[(E_+2*a2+1)*H_ + t]);
  }
  float r_mb1 = mb1[tid];
  float r_ab1 = ab1[tid];
  float r_mb2 = (tid < A_) ? mb2[tid] : 0.f;
  if (tid < A_) meta_s[tid] = meta_init[tid];
  __syncthreads();

  for (int t=0;t<LP;t++){
    int op  = ops[b*LP + t];
    int arg = args[b*LP + t];
    if (tid >= 64 && tid < 128) argx[tid-64] = conceptOut[arg*E_ + (tid-64)];
    __syncthreads();
    float acc = r_mb1;
    for (int j2=0;j2<32;j2++){
      unsigned w = mw1p[j2*256 + tid];
      float2 xp = *(const float2*)&meta_s[2*j2];
      acc = fmaf(xp.x, lo16f(w), acc);
      acc = fmaf(xp.y, hi16f(w), acc);
    }
    for (int j2=0;j2<32;j2++){
      unsigned w = mw1p[(32+j2)*256 + tid];
      float2 xp = *(const float2*)&argx[2*j2];
      acc = fmaf(xp.x, lo16f(w), acc);
      acc = fmaf(xp.y, hi16f(w), acc);
    }
    hid[tid] = fmaxf(acc, 0.f);
    __syncthreads();
    int wv_ = tid >> 6, l = tid & 63;
    float acc2 = 0.f;
    for (int h2 = wv_*32; h2 < wv_*32+32; h2++){
      unsigned w = mw2p[h2*64 + l];
      float2 hp = *(const float2*)&hid[2*h2];
      acc2 = fmaf(hp.x, lo16f(w), acc2);
      acc2 = fmaf(hp.y, hi16f(w), acc2);
    }
    part[wv_*64 + l] = acc2;
    __syncthreads();
    if (tid < A_){
      float s = part[tid] + part[64+tid] + part[128+tid] + part[192+tid] + r_mb2;
      float nm = (op==0) ? s : meta_s[tid];
      meta_s[tid] = nm;
      metaAll[(b*LP+t)*A_ + tid] = nm;
    }
    __syncthreads();
    float mh = r_ab1;
    for (int a2=0;a2<32;a2++){
      unsigned w = aw1p[a2*256 + tid];
      float2 mp = *(const float2*)&meta_s[2*a2];
      mh = fmaf(mp.x, lo16f(w), mh);
      mh = fmaf(mp.y, hi16f(w), mh);
    }
    metaH[(b*LP+t)*H_ + tid] = mh;
  }
}

__device__ __forceinline__ void mid_qt(char* smem, int idx,
                       const float* conceptIn, const float* conceptOut, const int* args,
                       const float* objIn, const float* objOut,
                       unsigned short* QTf, float* qsum){
  float* tile = (float*)smem;                  // 256*65*4 = 66560 B
  float* argv = (float*)(smem + 66560);
  float* qs   = (float*)(smem + 69632);
  int b = idx / NCHUNK, chunk = idx % NCHUNK;
  int tid = threadIdx.x;
  int rows = (chunk < 16) ? 256 : 128;
  int n0 = chunk*256;
  int n = n0 + tid;
  bool valid = (tid < rows);
  if (tid < 80) qs[tid] = 0.f;
  unsigned short* Qb = QTf + (size_t)b*QTF_B + ((n>>5)*512 + (n&31));
  {
    const float* src = (chunk < 16) ? (conceptIn + (size_t)n0*E_) : (objIn + (size_t)b*NO*E_);
    int tot = rows*64;
    for (int i=tid; i<tot; i+=256) tile[(i>>6)*65 + (i&63)] = src[i];
  }
  __syncthreads();
  if (valid){
    Qb[0] = 0x3F80;
    Qb[4*QTF_C + 13*32] = 0;
    Qb[4*QTF_C + 14*32] = 0;
    Qb[4*QTF_C + 15*32] = 0;
    for (int e=0;e<64;e++){
      int qc = 1+e;
      Qb[(qc>>4)*QTF_C + (qc&15)*32] = f2bs(tile[tid*65 + e]);
    }
    for (int i=0;i<64;i++){
      int e = (i + tid) & 63;
      atomicAdd(&qs[1+e], tile[tid*65+e]);
    }
  }
  __syncthreads();
  for (int i=tid;i<LP*E_;i+=256) argv[i] = conceptOut[args[b*LP + (i>>6)]*E_ + (i&63)];
  {
    const float* src = (chunk < 16) ? (conceptOut + (size_t)n0*E_) : (objOut + (size_t)b*NO*E_);
    int tot = rows*64;
    for (int i=tid; i<tot; i+=256) tile[(i>>6)*65 + (i&63)] = src[i];
  }
  __syncthreads();
  float dots[LP];
  #pragma unroll
  for (int t=0;t<LP;t++) dots[t] = 0.f;
  for (int e=0;e<64;e++){
    float o = tile[tid*65 + e];
    #pragma unroll
    for (int t=0;t<LP;t++) dots[t] += o*argv[t*64+e];
  }
  #pragma unroll
  for (int t=0;t<LP;t++){
    float v = valid ? dots[t]*(1.f/E_) : 0.f;
    if (valid){
      int qc = PROJ0+t;
      Qb[(qc>>4)*QTF_C + (qc&15)*32] = f2bs(v);
    }
    float r = v;
    #pragma unroll
    for (int off=32; off>0; off>>=1) r += __shfl_down(r, off, 64);
    if ((tid & 63) == 0) atomicAdd(&qs[PROJ0+t], r);
  }
  __syncthreads();
  if (tid < 80) atomicAdd(&qsum[b*QC + tid], qs[tid]);
  if (chunk == 0 && tid == 0) atomicAdd(&qsum[b*QC], (float)NN);
}

__device__ __forceinline__ void mid_base(int blk,
                       const float* conceptOut, const float* objOut,
                       const unsigned short* awFrag,
                       unsigned short* AoptC, unsigned short* AoptO){
  int n0 = blk * 64;
  int tid = threadIdx.x;
  int w = tid >> 6, l = tid & 63, quad = l >> 4, lq = l & 15;
  int n = n0 + w*16 + lq;
  const float* src = (n < NC) ? (conceptOut + (size_t)n*E_) : (objOut + (size_t)(n-NC)*E_);
  f32x4 acc[16];
  #pragma unroll
  for (int m=0;m<16;m++) acc[m] = (f32x4){0.f,0.f,0.f,0.f};
  #pragma unroll
  for (int kc=0;kc<2;kc++){
    s16x8 bfr;
    #pragma unroll
    for (int j=0;j<8;j++) bfr[j] = (short)f2bs(src[kc*32 + quad*8 + j]);
    const unsigned short* ap = awFrag + ((size_t)(kc*16)*64 + l)*8;
    #pragma unroll
    for (int m=0;m<16;m++){
      s16x8 af = *(const s16x8*)(ap + (size_t)m*64*8);
      acc[m] = __builtin_amdgcn_mfma_f32_16x16x32_bf16(af, bfr, acc[m], 0, 0, 0);
    }
  }
  int nl = n & 31;
  if (n < NC){
    int nch = n >> 5;
    #pragma unroll
    for (int m=0;m<16;m++){
      #pragma unroll
      for (int r=0;r<4;r++)
        AoptC[(size_t)(m*128 + nch)*512 + (quad*4+r)*32 + nl] = f2bs(acc[m][r]);
    }
  } else {
    int no = n - NC; int bb = no >> 7; int oc = (no & 127) >> 5;
    #pragma unroll
    for (int m=0;m<16;m++){
      #pragma unroll
      for (int r=0;r<4;r++)
        AoptO[(size_t)((bb*16 + m)*4 + oc)*512 + (quad*4+r)*32 + nl] = f2bs(acc[m][r]);
    }
  }
}

__global__ __launch_bounds__(256) void k_mid(
    const float* conceptIn, const float* conceptOut,
    const float* meta_init, const float* mw1, const float* mb1, const float* mw2, const float* mb2,
    const float* aw1, const float* ab1, const int* ops, const int* args,
    const float* objIn, const float* objOut, const unsigned short* awFrag,
    float* metaAll, float* metaH, unsigned short* QTf, float* qsum,
    unsigned short* AoptC, unsigned short* AoptO){
  __shared__ __align__(16) char smem[133888];
  int mb = blockIdx.x;
  if (mb < 8)
    mid_meta(smem, mb, conceptOut, meta_init, mw1, mb1, mw2, mb2, aw1, ab1, ops, args, metaAll, metaH);
  else if (mb < 144)
    mid_qt(smem, mb-8, conceptIn, conceptOut, args, objIn, objOut, QTf, qsum);
  else
    mid_base(mb-144, conceptOut, objOut, awFrag, AoptC, AoptO);
}

// ---------------- k_T (MFMA v5): as v4, but T output is bf16 packed in Lred order ----------------
// TB layout: [bt][ht][2560 dwords], dword i2 packs Lred flat indices (2*i2, 2*i2+1).
__global__ __launch_bounds__(256) void k_T(const unsigned short* AoptC, const unsigned short* AoptO,
                                           const unsigned short* QTf, const float* metaH,
                                           unsigned* TB0, unsigned* TB1){
  __shared__ float Lred[2*5120];
  int bid = blockIdx.x;
  int kh = bid & 1; int ht = (bid >> 1) & 3; int bt = bid >> 3; int b = bt / LP;
  int tid = threadIdx.x;
  int w = tid >> 6, l = tid & 63, quad = l >> 4, lq = l & 15;
  int off = lq*32 + quad*8;
  int start = kh*66 + ((w<2) ? (w*17) : (34 + (w-2)*16));
  int count = (w<2) ? 17 : 16;
  float mh[4];
  #pragma unroll
  for (int s=0;s<4;s++) mh[s] = metaH[(size_t)bt*H_ + ht*64 + s*16 + lq];
  f32x4 acc[4][5];
  #pragma unroll
  for (int s=0;s<4;s++){
    #pragma unroll
    for (int c=0;c<5;c++) acc[s][c] = (f32x4){0.f,0.f,0.f,0.f};
  }
  const unsigned short* QTb = QTf + (size_t)b*QTF_B + off;
  const unsigned short* AC  = AoptC + (size_t)(ht*4)*65536 + off;       // 65536 = 128*512
  const unsigned short* AO  = AoptO + (size_t)(b*16 + ht*4)*2048 + off; // 2048 = 4*512
  for (int it=0; it<count; it++){
    int nchunk = start + it;
    U8 bfr[5];
    #pragma unroll
    for (int c=0;c<5;c++)
      bfr[c].v = *(const s16x8*)(QTb + (size_t)c*QTF_C + (size_t)nchunk*512);
    bool isC = (nchunk < 128);
    #pragma unroll
    for (int s=0;s<4;s++){
      U8 a;
      a.v = isC ? *(const s16x8*)(AC + (size_t)s*65536 + (size_t)nchunk*512)
                : *(const s16x8*)(AO + (size_t)s*2048 + (size_t)(nchunk-128)*512);
      float mhs = mh[s];
      U8 af;
      #pragma unroll
      for (int d=0;d<4;d++){
        unsigned wv = a.u[d];
        float lo = fmaxf(__uint_as_float(wv << 16) + mhs, 0.f);
        float hi = fmaxf(__uint_as_float(wv & 0xffff0000u) + mhs, 0.f);
        af.u[d] = (__float_as_uint(hi) & 0xffff0000u) | (__float_as_uint(lo) >> 16);
      }
      #pragma unroll
      for (int c=0;c<5;c++)
        acc[s][c] = __builtin_amdgcn_mfma_f32_16x16x32_bf16(af.v, bfr[c].v, acc[s][c], 0, 0, 0);
    }
  }
  // two-stage reduce: waves 2,3 stash; waves 0,1 merge
  if (w >= 2){
    #pragma unroll
    for (int s=0;s<4;s++){
      #pragma unroll
      for (int c=0;c<5;c++)
        *(f32x4*)&Lred[(w-2)*5120 + (s*5+c)*256 + l*4] = acc[s][c];
    }
  }
  __syncthreads();
  if (w < 2){
    #pragma unroll
    for (int s=0;s<4;s++){
      #pragma unroll
      for (int c=0;c<5;c++){
        f32x4 v = *(const f32x4*)&Lred[w*5120 + (s*5+c)*256 + l*4];
        v = v + acc[s][c];
        *(f32x4*)&Lred[w*5120 + (s*5+c)*256 + l*4] = v;
      }
    }
  }
  __syncthreads();
  unsigned* Tp = (kh ? TB1 : TB0) + ((size_t)bt*4 + ht)*2560;
  for (int i2=tid; i2<2560; i2+=256){
    float lo = Lred[2*i2]   + Lred[5120 + 2*i2];
    float hi = Lred[2*i2+1] + Lred[5120 + 2*i2+1];
    Tp[i2] = pack2(lo, hi);
  }
}

// ---------------- k_U v2: K-split x2; reads bf16 T in Lred order; writes Ut partials ----------------
// Up[kq][bt][e][qc] = invN * ( sum_{h in kq-range} w2[h][e]*T[h][qc]  (+ kq==0: b2[e]*qsum[qc]) )
__global__ __launch_bounds__(256) void k_U(const unsigned* TB0, const unsigned* TB1,
                                           const float* w2, const float* b2v,
                                           const float* qsum, float* Ut0, float* Ut1){
  __shared__ float Wt[128*64];
  __shared__ float Tt[128*81];
  int bid = blockIdx.x;
  int kq = bid & 1; int bt = bid >> 1; int b = bt / LP;
  int tid = threadIdx.x;
  for (int i=tid; i<8192; i+=256){
    int hl = i >> 6, e = i & 63;
    Wt[i] = w2[(kq*128 + hl)*E_ + e];
  }
  #pragma unroll
  for (int half=0; half<2; half++){
    const unsigned* s0 = TB0 + ((size_t)bt*4 + kq*2 + half)*2560;
    const unsigned* s1 = TB1 + ((size_t)bt*4 + kq*2 + half)*2560;
    for (int i2=tid; i2<2560; i2+=256){
      unsigned w0 = s0[i2], w1 = s1[i2];
      int idx = 2*i2;
      int sc = idx >> 8; int ll = (idx >> 2) & 63; int r = idx & 3;
      int s = sc/5, c = sc - s*5;
      int hl = half*64 + s*16 + ((ll>>4)<<2) + r;
      int qc = c*16 + (ll&15);
      Tt[hl*81 + qc]     = lo16f(w0) + lo16f(w1);
      Tt[(hl+1)*81 + qc] = hi16f(w0) + hi16f(w1);
    }
  }
  __syncthreads();
  int el = tid & 15, ql = tid >> 4;
  float acc[4][5];
  #pragma unroll
  for (int i=0;i<4;i++){
    #pragma unroll
    for (int j=0;j<5;j++) acc[i][j]=0.f;
  }
  #pragma unroll 4
  for (int kk=0; kk<128; kk++){
    float4 wv = *(const float4*)&Wt[kk*64 + el*4];
    float ww[4] = {wv.x, wv.y, wv.z, wv.w};
    const float* tp = &Tt[kk*81 + ql*5];
    #pragma unroll
    for (int j=0;j<5;j++){
      float tv = tp[j];
      #pragma unroll
      for (int i=0;i<4;i++) acc[i][j] = fmaf(ww[i], tv, acc[i][j]);
    }
  }
  const float invN = 1.f/NN;
  float* Up = (kq ? Ut1 : Ut0) + (size_t)bt*5120;
  if (kq == 0){
    float be[4], qv[5];
    #pragma unroll
    for (int i=0;i<4;i++) be[i] = b2v[el*4+i];
    #pragma unroll
    for (int j=0;j<5;j++) qv[j] = qsum[b*QC + ql*5+j];
    #pragma unroll
    for (int i=0;i<4;i++){
      #pragma unroll
      for (int j=0;j<5;j++)
        Up[(el*4+i)*QC + ql*5+j] = (acc[i][j] + be[i]*qv[j]) * invN;
    }
  } else {
    #pragma unroll
    for (int i=0;i<4;i++){
      #pragma unroll
      for (int j=0;j<5;j++)
        Up[(el*4+i)*QC + ql*5+j] = acc[i][j] * invN;
    }
  }
}

// ---------------- k_rec: 12-step recurrence; stages sum of 2 U partials, double-buffered ----------------
__global__ __launch_bounds__(256) void k_rec(const float* Ut0, const float* Ut1, const float* metaAll,
                                             const int* ops, const float* att_init, float* Cm){
  __shared__ float C[QC*A_];
  __shared__ float M[E_*A_];
  __shared__ float Ul[2][64*81];
  int b = blockIdx.x, tid = threadIdx.x;
  for (int i=tid;i<QC*A_;i+=256) C[i] = 0.f;
  __syncthreads();
  if (tid < A_) C[tid] = att_init[tid];
  {
    const float* U0 = Ut0 + (size_t)(b*LP)*5120;
    const float* U1 = Ut1 + (size_t)(b*LP)*5120;
    #pragma unroll
    for (int k=0;k<5;k++){
      int i = tid*4 + k*1024;
      float4 v0 = *(const float4*)&U0[i];
      float4 v1 = *(const float4*)&U1[i];
      int r = i/80, c = i%80;
      Ul[0][r*81+c]   = v0.x+v1.x; Ul[0][r*81+c+1] = v0.y+v1.y;
      Ul[0][r*81+c+2] = v0.z+v1.z; Ul[0][r*81+c+3] = v0.w+v1.w;
    }
  }
  __syncthreads();
  int el = tid & 15, al = tid >> 4;
  for (int t=0;t<LP;t++){
    float4 rv0[5], rv1[5];
    if (t < LP-1){
      const float* U0 = Ut0 + (size_t)(b*LP+t+1)*5120;
      const float* U1 = Ut1 + (size_t)(b*LP+t+1)*5120;
      #pragma unroll
      for (int k=0;k<5;k++){
        rv0[k] = *(const float4*)&U0[tid*4 + k*1024];
        rv1[k] = *(const float4*)&U1[tid*4 + k*1024];
      }
    }
    const float* Uc = Ul[t&1];
    float acc[4][4];
    #pragma unroll
    for (int i=0;i<4;i++){
      #pragma unroll
      for (int k=0;k<4;k++) acc[i][k]=0.f;
    }
    for (int j=0;j<QC;j++){
      float u[4];
      #pragma unroll
      for (int i=0;i<4;i++) u[i] = Uc[(el*4+i)*81 + j];
      float4 c4 = *(const float4*)&C[j*A_ + al*4];
      float cc[4] = {c4.x, c4.y, c4.z, c4.w};
      #pragma unroll
      for (int i=0;i<4;i++){
        #pragma unroll
        for (int k=0;k<4;k++) acc[i][k] = fmaf(u[i], cc[k], acc[i][k]);
      }
    }
    #pragma unroll
    for (int i=0;i<4;i++){
      #pragma unroll
      for (int k=0;k<4;k++) M[(el*4+i)*A_ + al*4+k] = acc[i][k];
    }
    int op = ops[b*LP + t];
    float tr  = (op==2) ? 1.f : 0.f;
    float ins = (op==1) ? 1.f : 0.f;
    __syncthreads();
    for (int i=tid;i<E_*A_;i+=256) C[A_ + i] += tr*M[i];
    if (tid < A_) C[(PROJ0+t)*A_ + tid] += ins*metaAll[(b*LP+t)*A_ + tid];
    if (t < LP-1){
      float* Un = Ul[(t+1)&1];
      #pragma unroll
      for (int k=0;k<5;k++){
        int i = tid*4 + k*1024;
        int r = i/80, c = i%80;
        Un[r*81+c]   = rv0[k].x+rv1[k].x; Un[r*81+c+1] = rv0[k].y+rv1[k].y;
        Un[r*81+c+2] = rv0[k].z+rv1[k].z; Un[r*81+c+3] = rv0[k].w+rv1[k].w;
      }
    }
    __syncthreads();
  }
  for (int i=tid;i<QC*A_;i+=256) Cm[b*QC*A_ + i] = C[i];
}

// ---------------- k_out: 128-thread blocks, 264 blocks; ol[b,n] = ||C^T q_n||^2 / 64 ----------------
__global__ __launch_bounds__(128) void k_out(const unsigned short* QTf, const float* Cm,
                                             float* ol, float* esum){
  __shared__ float C[QC*A_];
  __shared__ float wsum[2];
  int b = blockIdx.x / 33, rem = blockIdx.x % 33;
  int tid = threadIdx.x;
  for (int i=tid;i<QC*A_;i+=128) C[i] = Cm[b*QC*A_ + i];
  __syncthreads();
  int n = rem*128 + tid;                      // 33*128 = 4224 = NN, always valid
  float y[A_];
  #pragma unroll
  for (int a=0;a<A_;a++) y[a]=0.f;
  const unsigned short* Qb = QTf + (size_t)b*QTF_B + ((n>>5)*512 + (n&31));
  for (int j=0;j<QC;j++){
    float qvv = bs2f(Qb[(j>>4)*QTF_C + (j&15)*32]);
    const float* Cj = &C[j*A_];
    #pragma unroll
    for (int a=0;a<A_;a++) y[a] = fmaf(qvv, Cj[a], y[a]);
  }
  float s = 0.f;
  #pragma unroll
  for (int a=0;a<A_;a++) s = fmaf(y[a], y[a], s);
  float o = s * (1.f/A_);
  ol[(size_t)b*NN + n] = o;
  float contrib = expf(o);
  #pragma unroll
  for (int off=32; off>0; off>>=1) contrib += __shfl_down(contrib, off, 64);
  if ((tid & 63) == 0) wsum[tid>>6] = contrib;
  __syncthreads();
  if (tid == 0) atomicAdd(&esum[b], wsum[0]+wsum[1]);
}

// ---------------- k_fin ----------------
__global__ void k_fin(const float* ol, const float* esum, const int* flag, void* out){
  int idx = blockIdx.x*256 + threadIdx.x;
  if (idx < B_*NN){
    int b = idx / NN;
    float v = ol[idx] - logf(esum[b]);
    if (*flag) ((float*)out)[idx] = v;
    else       ((bf16*)out)[idx]  = __float2bfloat16(v);
  }
}

extern "C" void kernel_launch(void* const* d_in, const int* in_sizes, int n_in,
                              void* d_out, int out_size, void* d_ws, size_t ws_size,
                              hipStream_t stream) {
  (void)in_sizes; (void)n_in; (void)out_size; (void)ws_size;
  const int* ops  = (const int*)d_in[17];
  const int* args = (const int*)d_in[18];
  const int* gtc  = (const int*)d_in[19];
  const int* gta  = (const int*)d_in[20];

  float* ws = (float*)d_ws;
  int* flag = (int*)ws;
  float* W  = ws + 16;

  const float* conceptIn  = W + 65536;
  const float* conceptOut = W + 327680;
  const float* meta_init  = W + 589824;
  const float* att_init   = W + 589888;
  const float* aw1        = W + 589952;
  const float* ab1        = W + 622720;
  const float* aw2        = W + 622976;
  const float* ab2        = W + 639360;
  const float* mw1        = W + 639424;
  const float* mb1        = W + 672192;
  const float* mw2        = W + 672448;
  const float* mb2        = W + 688832;

  constexpr size_t OFF_OBJIN   = 16 + TOT_IN;            // 688912
  constexpr size_t OFF_OBJOUT  = OFF_OBJIN  + 65536;     // 754448
  constexpr size_t OFF_METAALL = OFF_OBJOUT + 65536;     // 819984
  constexpr size_t OFF_METAH   = OFF_METAALL + 6144;     // 826128
  constexpr size_t OFF_QSUM    = OFF_METAH  + 24576;     // 850704
  constexpr size_t OFF_ESUM    = OFF_QSUM   + 640;       // 851344
  constexpr size_t OFF_UT0     = OFF_ESUM   + 16;        // 851360, 491520
  constexpr size_t OFF_UT1     = OFF_UT0    + 491520;    // 1342880, 491520
  constexpr size_t OFF_CM      = OFF_UT1    + 491520;    // 1834400, 40960
  constexpr size_t OFF_OL      = OFF_CM     + 40960;     // 1875360, 33792
  constexpr size_t OFF_QTF     = OFF_OL     + 33792;     // 1909152, 1351680
  constexpr size_t OFF_AOPTC   = OFF_QTF    + 1351680;   // 3260832, 524288
  constexpr size_t OFF_AOPTO   = OFF_AOPTC  + 524288;    // 3785120, 131072
  constexpr size_t OFF_AWF     = OFF_AOPTO  + 131072;    // 3916192, 8192
  constexpr size_t OFF_TB0     = OFF_AWF    + 8192;      // 3924384, 983040 dwords
  constexpr size_t OFF_TB1     = OFF_TB0    + 983040;    // 4907424, 983040 dwords
  // end = 5,890,464 floats ~= 23.6 MB

  float* objIn   = ws + OFF_OBJIN;
  float* objOut  = ws + OFF_OBJOUT;
  float* metaAll = ws + OFF_METAALL;
  float* metaH   = ws + OFF_METAH;
  float* qsum    = ws + OFF_QSUM;
  float* esum    = ws + OFF_ESUM;
  float* Ut0     = ws + OFF_UT0;
  float* Ut1     = ws + OFF_UT1;
  float* Cm      = ws + OFF_CM;
  float* ol      = ws + OFF_OL;
  unsigned short* QTf    = (unsigned short*)(ws + OFF_QTF);
  unsigned short* AoptC  = (unsigned short*)(ws + OFF_AOPTC);
  unsigned short* AoptO  = (unsigned short*)(ws + OFF_AOPTO);
  unsigned short* awFrag = (unsigned short*)(ws + OFF_AWF);
  unsigned* TB0          = (unsigned*)(ws + OFF_TB0);
  unsigned* TB1          = (unsigned*)(ws + OFF_TB1);

  hipMemsetAsync(qsum, 0, (640 + 16)*sizeof(float), stream);   // qsum + esum

  Ptr16 ps;
  const int src_idx[16] = {0,1,2,3,4,5,6,8,9,10,11,12,13,14,15,16};
  for (int i=0;i<16;i++) ps.p[i] = d_in[src_idx[i]];

  k_detect<<<1, 256, 0, stream>>>(d_in[4], flag);
  k_prep  <<<3011, 256, 0, stream>>>(ps, flag, W, awFrag, gtc, gta, objIn, objOut);
  k_mid   <<<224, 256, 0, stream>>>(conceptIn, conceptOut, meta_init, mw1, mb1, mw2, mb2,
                                    aw1, ab1, ops, args, objIn, objOut, awFrag,
                                    metaAll, metaH, QTf, qsum, AoptC, AoptO);
  k_T     <<<B_*LP*4*2, 256, 0, stream>>>(AoptC, AoptO, QTf, metaH, TB0, TB1);
  k_U     <<<B_*LP*2, 256, 0, stream>>>(TB0, TB1, aw2, ab2, qsum, Ut0, Ut1);
  k_rec   <<<B_, 256, 0, stream>>>(Ut0, Ut1, metaAll, ops, att_init, Cm);
  k_out   <<<B_*33, 128, 0, stream>>>(QTf, Cm, ol, esum);
  k_fin   <<<(B_*NN + 255)/256, 256, 0, stream>>>(ol, esum, flag, d_out);
}

// Round 9
// 272.587 us; speedup vs baseline: 6.8083x; 1.0368x over previous
//
#include <hip/hip_runtime.h>
#include <hip/hip_bf16.h>

typedef __hip_bfloat16 bf16;
typedef float f32x4 __attribute__((ext_vector_type(4)));
typedef short s16x8 __attribute__((ext_vector_type(8)));

#define B_    8
#define LP    12
#define NC    4096
#define NO    128
#define NAPO  8
#define NN    4224
#define E_    64
#define A_    64
#define H_    256
#define QC    80
#define PROJ0 65
#define NCHUNK 17

#define TOT_IN 688896
#define QTF_C  67584     // 132*512 shorts per (b,c) group
#define QTF_B  337920    // 5*QTF_C per batch

struct Ptr16 { const void* p[16]; };
union U8 { s16x8 v; unsigned u[4]; };

__device__ __forceinline__ float b2f(bf16 x){ return __bfloat162float(x); }
__device__ __forceinline__ float bs2f(unsigned short s){
  union { unsigned u; float f; } x; x.u = ((unsigned)s) << 16; return x.f;
}
__device__ __forceinline__ unsigned short f2bs(float f){
  bf16 h = __float2bfloat16(f);
  union { bf16 h; unsigned short s; } x; x.h = h; return x.s;
}
__device__ __forceinline__ unsigned pack2(float a, float b){
  return (unsigned)f2bs(a) | ((unsigned)f2bs(b) << 16);
}
__device__ __forceinline__ float lo16f(unsigned w){
  union { unsigned u; float f; } x; x.u = w << 16; return x.f;
}
__device__ __forceinline__ float hi16f(unsigned w){
  union { unsigned u; float f; } x; x.u = w & 0xffff0000u; return x.f;
}
__device__ __forceinline__ float rdval(const void* p, int i, int fl){
  return fl ? ((const float*)p)[i] : bs2f(((const unsigned short*)p)[i]);
}

// ---------------- k_detect: fp32 (flag=1) vs bf16 (flag=0) input data ----------------
__global__ void k_detect(const void* probe, int* flag){
  __shared__ int cnt;
  if (threadIdx.x == 0) cnt = 0;
  __syncthreads();
  const unsigned short* u = (const unsigned short*)probe;
  int c = 0;
  for (int i = threadIdx.x; i < 4096; i += 256){
    int e = (u[i] >> 7) & 0xFF;
    if (e >= 137) c++;
  }
  atomicAdd(&cnt, c);
  __syncthreads();
  if (threadIdx.x == 0) *flag = (cnt >= 8) ? 1 : 0;
}

// ---------------- k_prep: convert(2691) + awFrag pack(64) + obj embeddings(256) ----------------
__global__ void k_prep(Ptr16 ps, const int* flag, float* dst,
                       unsigned short* awFrag,
                       const int* gtc, const int* gta,
                       float* objIn, float* objOut){
  int mb = blockIdx.x;
  int fl = *flag;
  if (mb < 2691){
    int idx = mb*256 + threadIdx.x;
    if (idx >= TOT_IN) return;
    constexpr int cum[17] = {0,16384,32768,49152,65536,327680,589824,589888,589952,
                             622720,622976,639360,639424,672192,672448,688832,688896};
    int t = 0;
    #pragma unroll
    for (int i=1;i<16;i++) if (idx >= cum[i]) t = i;
    dst[idx] = rdval(ps.p[t], idx - cum[t], fl);
  } else if (mb < 2755){
    int idx = (mb-2691)*256 + threadIdx.x;      // < 16384
    int j = idx & 7;
    int lane = (idx >> 3) & 63;
    int m = (idx >> 9) & 15;
    int kc = idx >> 13;
    int e = kc*32 + (lane>>4)*8 + j;
    int h = m*16 + (lane&15);
    awFrag[idx] = f2bs(rdval(ps.p[8], e*H_ + h, fl));
  } else {
    int idx = (mb-2755)*256 + threadIdx.x;      // < 65536
    int e = idx & 63; int bo = idx >> 6;
    int cls = gtc[bo];
    float vi = rdval(ps.p[0], cls*E_ + e, fl);
    float vo = rdval(ps.p[1], cls*E_ + e, fl);
    const int* ga = gta + bo*NAPO;
    #pragma unroll
    for (int j=0;j<NAPO;j++){
      int at = ga[j];
      vi += rdval(ps.p[2], at*E_ + e, fl);
      vo += rdval(ps.p[3], at*E_ + e, fl);
    }
    objIn[idx] = vi; objOut[idx] = vo;
  }
}

// ================ k_mid: meta(8) | QTf+qsum(136) | baseT->Aopt(80) ================
__device__ __forceinline__ void mid_meta(char* smem, int b,
                       const float* conceptOut, const float* meta_init,
                       const float* mw1, const float* mb1, const float* mw2, const float* mb2,
                       const float* aw1, const float* ab1,
                       const int* ops, const int* args,
                       float* metaAll, float* metaH){
  unsigned* mw1p = (unsigned*)smem;               // 64*256 = 65536 B
  unsigned* mw2p = (unsigned*)(smem + 65536);     // 128*64 = 32768 B
  unsigned* aw1p = (unsigned*)(smem + 98304);     // 32*256 = 32768 B
  float* meta_s  = (float*)(smem + 131072);
  float* argx    = (float*)(smem + 131328);
  float* hid     = (float*)(smem + 131584);
  float* part    = (float*)(smem + 132608);
  int tid = threadIdx.x;

  for (int i=tid; i<64*256; i+=256){
    int j2 = i >> 8, t = i & 255;
    mw1p[i] = pack2(mw1[(2*j2)*H_ + t], mw1[(2*j2+1)*H_ + t]);
  }
  for (int i=tid; i<128*64; i+=256){
    int h2 = i >> 6, a = i & 63;
    mw2p[i] = pack2(mw2[(2*h2)*A_ + a], mw2[(2*h2+1)*A_ + a]);
  }
  for (int i=tid; i<32*256; i+=256){
    int a2 = i >> 8, t = i & 255;
    aw1p[i] = pack2(aw1[(E_+2*a2)*H_ + t], aw1[(E_+2*a2+1)*H_ + t]);
  }
  float r_mb1 = mb1[tid];
  float r_ab1 = ab1[tid];
  float r_mb2 = (tid < A_) ? mb2[tid] : 0.f;
  if (tid < A_) meta_s[tid] = meta_init[tid];
  __syncthreads();

  for (int t=0;t<LP;t++){
    int op  = ops[b*LP + t];
    int arg = args[b*LP + t];
    if (tid >= 64 && tid < 128) argx[tid-64] = conceptOut[arg*E_ + (tid-64)];
    __syncthreads();
    float acc = r_mb1;
    for (int j2=0;j2<32;j2++){
      unsigned w = mw1p[j2*256 + tid];
      float2 xp = *(const float2*)&meta_s[2*j2];
      acc = fmaf(xp.x, lo16f(w), acc);
      acc = fmaf(xp.y, hi16f(w), acc);
    }
    for (int j2=0;j2<32;j2++){
      unsigned w = mw1p[(32+j2)*256 + tid];
      float2 xp = *(const float2*)&argx[2*j2];
      acc = fmaf(xp.x, lo16f(w), acc);
      acc = fmaf(xp.y, hi16f(w), acc);
    }
    hid[tid] = fmaxf(acc, 0.f);
    __syncthreads();
    int wv_ = tid >> 6, l = tid & 63;
    float acc2 = 0.f;
    for (int h2 = wv_*32; h2 < wv_*32+32; h2++){
      unsigned w = mw2p[h2*64 + l];
      float2 hp = *(const float2*)&hid[2*h2];
      acc2 = fmaf(hp.x, lo16f(w), acc2);
      acc2 = fmaf(hp.y, hi16f(w), acc2);
    }
    part[wv_*64 + l] = acc2;
    __syncthreads();
    if (tid < A_){
      float s = part[tid] + part[64+tid] + part[128+tid] + part[192+tid] + r_mb2;
      float nm = (op==0) ? s : meta_s[tid];
      meta_s[tid] = nm;
      metaAll[(b*LP+t)*A_ + tid] = nm;
    }
    __syncthreads();
    float mh = r_ab1;
    for (int a2=0;a2<32;a2++){
      unsigned w = aw1p[a2*256 + tid];
      float2 mp = *(const float2*)&meta_s[2*a2];
      mh = fmaf(mp.x, lo16f(w), mh);
      mh = fmaf(mp.y, hi16f(w), mh);
    }
    metaH[(b*LP+t)*H_ + tid] = mh;
  }
}

__device__ __forceinline__ void mid_qt(char* smem, int idx,
                       const float* conceptIn, const float* conceptOut, const int* args,
                       const float* objIn, const float* objOut,
                       unsigned short* QTf, float* qsum){
  float* tile = (float*)smem;                  // 256*65*4 = 66560 B
  float* argv = (float*)(smem + 66560);
  float* qs   = (float*)(smem + 69632);
  int b = idx / NCHUNK, chunk = idx % NCHUNK;
  int tid = threadIdx.x;
  int rows = (chunk < 16) ? 256 : 128;
  int n0 = chunk*256;
  int n = n0 + tid;
  bool valid = (tid < rows);
  if (tid < 80) qs[tid] = 0.f;
  unsigned short* Qb = QTf + (size_t)b*QTF_B + ((n>>5)*512 + (n&31));
  {
    const float* src = (chunk < 16) ? (conceptIn + (size_t)n0*E_) : (objIn + (size_t)b*NO*E_);
    int tot = rows*64;
    for (int i=tid; i<tot; i+=256) tile[(i>>6)*65 + (i&63)] = src[i];
  }
  __syncthreads();
  if (valid){
    Qb[0] = 0x3F80;
    Qb[4*QTF_C + 13*32] = 0;
    Qb[4*QTF_C + 14*32] = 0;
    Qb[4*QTF_C + 15*32] = 0;
    for (int e=0;e<64;e++){
      int qc = 1+e;
      Qb[(qc>>4)*QTF_C + (qc&15)*32] = f2bs(tile[tid*65 + e]);
    }
    for (int i=0;i<64;i++){
      int e = (i + tid) & 63;
      atomicAdd(&qs[1+e], tile[tid*65+e]);
    }
  }
  __syncthreads();
  for (int i=tid;i<LP*E_;i+=256) argv[i] = conceptOut[args[b*LP + (i>>6)]*E_ + (i&63)];
  {
    const float* src = (chunk < 16) ? (conceptOut + (size_t)n0*E_) : (objOut + (size_t)b*NO*E_);
    int tot = rows*64;
    for (int i=tid; i<tot; i+=256) tile[(i>>6)*65 + (i&63)] = src[i];
  }
  __syncthreads();
  float dots[LP];
  #pragma unroll
  for (int t=0;t<LP;t++) dots[t] = 0.f;
  for (int e=0;e<64;e++){
    float o = tile[tid*65 + e];
    #pragma unroll
    for (int t=0;t<LP;t++) dots[t] += o*argv[t*64+e];
  }
  #pragma unroll
  for (int t=0;t<LP;t++){
    float v = valid ? dots[t]*(1.f/E_) : 0.f;
    if (valid){
      int qc = PROJ0+t;
      Qb[(qc>>4)*QTF_C + (qc&15)*32] = f2bs(v);
    }
    float r = v;
    #pragma unroll
    for (int off=32; off>0; off>>=1) r += __shfl_down(r, off, 64);
    if ((tid & 63) == 0) atomicAdd(&qs[PROJ0+t], r);
  }
  __syncthreads();
  if (tid < 80) atomicAdd(&qsum[b*QC + tid], qs[tid]);
  if (chunk == 0 && tid == 0) atomicAdd(&qsum[b*QC], (float)NN);
}

__device__ __forceinline__ void mid_base(int blk,
                       const float* conceptOut, const float* objOut,
                       const unsigned short* awFrag,
                       unsigned short* AoptC, unsigned short* AoptO){
  int n0 = blk * 64;
  int tid = threadIdx.x;
  int w = tid >> 6, l = tid & 63, quad = l >> 4, lq = l & 15;
  int n = n0 + w*16 + lq;
  const float* src = (n < NC) ? (conceptOut + (size_t)n*E_) : (objOut + (size_t)(n-NC)*E_);
  f32x4 acc[16];
  #pragma unroll
  for (int m=0;m<16;m++) acc[m] = (f32x4){0.f,0.f,0.f,0.f};
  #pragma unroll
  for (int kc=0;kc<2;kc++){
    s16x8 bfr;
    #pragma unroll
    for (int j=0;j<8;j++) bfr[j] = (short)f2bs(src[kc*32 + quad*8 + j]);
    const unsigned short* ap = awFrag + ((size_t)(kc*16)*64 + l)*8;
    #pragma unroll
    for (int m=0;m<16;m++){
      s16x8 af = *(const s16x8*)(ap + (size_t)m*64*8);
      acc[m] = __builtin_amdgcn_mfma_f32_16x16x32_bf16(af, bfr, acc[m], 0, 0, 0);
    }
  }
  int nl = n & 31;
  if (n < NC){
    int nch = n >> 5;
    #pragma unroll
    for (int m=0;m<16;m++){
      #pragma unroll
      for (int r=0;r<4;r++)
        AoptC[(size_t)(m*128 + nch)*512 + (quad*4+r)*32 + nl] = f2bs(acc[m][r]);
    }
  } else {
    int no = n - NC; int bb = no >> 7; int oc = (no & 127) >> 5;
    #pragma unroll
    for (int m=0;m<16;m++){
      #pragma unroll
      for (int r=0;r<4;r++)
        AoptO[(size_t)((bb*16 + m)*4 + oc)*512 + (quad*4+r)*32 + nl] = f2bs(acc[m][r]);
    }
  }
}

__global__ __launch_bounds__(256) void k_mid(
    const float* conceptIn, const float* conceptOut,
    const float* meta_init, const float* mw1, const float* mb1, const float* mw2, const float* mb2,
    const float* aw1, const float* ab1, const int* ops, const int* args,
    const float* objIn, const float* objOut, const unsigned short* awFrag,
    float* metaAll, float* metaH, unsigned short* QTf, float* qsum,
    unsigned short* AoptC, unsigned short* AoptO){
  __shared__ __align__(16) char smem[133888];
  int mb = blockIdx.x;
  if (mb < 8)
    mid_meta(smem, mb, conceptOut, meta_init, mw1, mb1, mw2, mb2, aw1, ab1, ops, args, metaAll, metaH);
  else if (mb < 144)
    mid_qt(smem, mb-8, conceptIn, conceptOut, args, objIn, objOut, QTf, qsum);
  else
    mid_base(mb-144, conceptOut, objOut, awFrag, AoptC, AoptO);
}

// ---------------- k_T (MFMA v5): as v4, but T output is bf16 packed in Lred order ----------------
// TB layout: [bt][ht][2560 dwords], dword i2 packs Lred flat indices (2*i2, 2*i2+1).
__global__ __launch_bounds__(256) void k_T(const unsigned short* AoptC, const unsigned short* AoptO,
                                           const unsigned short* QTf, const float* metaH,
                                           unsigned* TB0, unsigned* TB1){
  __shared__ float Lred[2*5120];
  int bid = blockIdx.x;
  int kh = bid & 1; int ht = (bid >> 1) & 3; int bt = bid >> 3; int b = bt / LP;
  int tid = threadIdx.x;
  int w = tid >> 6, l = tid & 63, quad = l >> 4, lq = l & 15;
  int off = lq*32 + quad*8;
  int start = kh*66 + ((w<2) ? (w*17) : (34 + (w-2)*16));
  int count = (w<2) ? 17 : 16;
  float mh[4];
  #pragma unroll
  for (int s=0;s<4;s++) mh[s] = metaH[(size_t)bt*H_ + ht*64 + s*16 + lq];
  f32x4 acc[4][5];
  #pragma unroll
  for (int s=0;s<4;s++){
    #pragma unroll
    for (int c=0;c<5;c++) acc[s][c] = (f32x4){0.f,0.f,0.f,0.f};
  }
  const unsigned short* QTb = QTf + (size_t)b*QTF_B + off;
  const unsigned short* AC  = AoptC + (size_t)(ht*4)*65536 + off;       // 65536 = 128*512
  const unsigned short* AO  = AoptO + (size_t)(b*16 + ht*4)*2048 + off; // 2048 = 4*512
  for (int it=0; it<count; it++){
    int nchunk = start + it;
    U8 bfr[5];
    #pragma unroll
    for (int c=0;c<5;c++)
      bfr[c].v = *(const s16x8*)(QTb + (size_t)c*QTF_C + (size_t)nchunk*512);
    bool isC = (nchunk < 128);
    #pragma unroll
    for (int s=0;s<4;s++){
      U8 a;
      a.v = isC ? *(const s16x8*)(AC + (size_t)s*65536 + (size_t)nchunk*512)
                : *(const s16x8*)(AO + (size_t)s*2048 + (size_t)(nchunk-128)*512);
      float mhs = mh[s];
      U8 af;
      #pragma unroll
      for (int d=0;d<4;d++){
        unsigned wv = a.u[d];
        float lo = fmaxf(__uint_as_float(wv << 16) + mhs, 0.f);
        float hi = fmaxf(__uint_as_float(wv & 0xffff0000u) + mhs, 0.f);
        af.u[d] = (__float_as_uint(hi) & 0xffff0000u) | (__float_as_uint(lo) >> 16);
      }
      #pragma unroll
      for (int c=0;c<5;c++)
        acc[s][c] = __builtin_amdgcn_mfma_f32_16x16x32_bf16(af.v, bfr[c].v, acc[s][c], 0, 0, 0);
    }
  }
  // two-stage reduce: waves 2,3 stash; waves 0,1 merge
  if (w >= 2){
    #pragma unroll
    for (int s=0;s<4;s++){
      #pragma unroll
      for (int c=0;c<5;c++)
        *(f32x4*)&Lred[(w-2)*5120 + (s*5+c)*256 + l*4] = acc[s][c];
    }
  }
  __syncthreads();
  if (w < 2){
    #pragma unroll
    for (int s=0;s<4;s++){
      #pragma unroll
      for (int c=0;c<5;c++){
        f32x4 v = *(const f32x4*)&Lred[w*5120 + (s*5+c)*256 + l*4];
        v = v + acc[s][c];
        *(f32x4*)&Lred[w*5120 + (s*5+c)*256 + l*4] = v;
      }
    }
  }
  __syncthreads();
  unsigned* Tp = (kh ? TB1 : TB0) + ((size_t)bt*4 + ht)*2560;
  for (int i2=tid; i2<2560; i2+=256){
    float lo = Lred[2*i2]   + Lred[5120 + 2*i2];
    float hi = Lred[2*i2+1] + Lred[5120 + 2*i2+1];
    Tp[i2] = pack2(lo, hi);
  }
}

// ---------------- k_U v2: K-split x2; reads bf16 T in Lred order; writes Ut partials ----------------
__global__ __launch_bounds__(256) void k_U(const unsigned* TB0, const unsigned* TB1,
                                           const float* w2, const float* b2v,
                                           const float* qsum, float* Ut0, float* Ut1){
  __shared__ float Wt[128*64];
  __shared__ float Tt[128*81];
  int bid = blockIdx.x;
  int kq = bid & 1; int bt = bid >> 1; int b = bt / LP;
  int tid = threadIdx.x;
  for (int i=tid; i<8192; i+=256){
    int hl = i >> 6, e = i & 63;
    Wt[i] = w2[(kq*128 + hl)*E_ + e];
  }
  #pragma unroll
  for (int half=0; half<2; half++){
    const unsigned* s0 = TB0 + ((size_t)bt*4 + kq*2 + half)*2560;
    const unsigned* s1 = TB1 + ((size_t)bt*4 + kq*2 + half)*2560;
    for (int i2=tid; i2<2560; i2+=256){
      unsigned w0 = s0[i2], w1 = s1[i2];
      int idx = 2*i2;
      int sc = idx >> 8; int ll = (idx >> 2) & 63; int r = idx & 3;
      int s = sc/5, c = sc - s*5;
      int hl = half*64 + s*16 + ((ll>>4)<<2) + r;
      int qc = c*16 + (ll&15);
      Tt[hl*81 + qc]     = lo16f(w0) + lo16f(w1);
      Tt[(hl+1)*81 + qc] = hi16f(w0) + hi16f(w1);
    }
  }
  __syncthreads();
  int el = tid & 15, ql = tid >> 4;
  float acc[4][5];
  #pragma unroll
  for (int i=0;i<4;i++){
    #pragma unroll
    for (int j=0;j<5;j++) acc[i][j]=0.f;
  }
  #pragma unroll 4
  for (int kk=0; kk<128; kk++){
    float4 wv = *(const float4*)&Wt[kk*64 + el*4];
    float ww[4] = {wv.x, wv.y, wv.z, wv.w};
    const float* tp = &Tt[kk*81 + ql*5];
    #pragma unroll
    for (int j=0;j<5;j++){
      float tv = tp[j];
      #pragma unroll
      for (int i=0;i<4;i++) acc[i][j] = fmaf(ww[i], tv, acc[i][j]);
    }
  }
  const float invN = 1.f/NN;
  float* Up = (kq ? Ut1 : Ut0) + (size_t)bt*5120;
  if (kq == 0){
    float be[4], qv[5];
    #pragma unroll
    for (int i=0;i<4;i++) be[i] = b2v[el*4+i];
    #pragma unroll
    for (int j=0;j<5;j++) qv[j] = qsum[b*QC + ql*5+j];
    #pragma unroll
    for (int i=0;i<4;i++){
      #pragma unroll
      for (int j=0;j<5;j++)
        Up[(el*4+i)*QC + ql*5+j] = (acc[i][j] + be[i]*qv[j]) * invN;
    }
  } else {
    #pragma unroll
    for (int i=0;i<4;i++){
      #pragma unroll
      for (int j=0;j<5;j++)
        Up[(el*4+i)*QC + ql*5+j] = acc[i][j] * invN;
    }
  }
}

// ---------------- k_rec v3: MFMA per-step M = U_t @ C; padded LDS (no 16-way conflicts) ----------------
// C in LDS [qc][a] pad 65; U staged [e][qc] pad 81 (double-buffered).
// A-frag: U[m0+lq][k0+quad*8+j]; B-frag: C[k0+quad*8+j][n0+lq]; D: M[m0+quad*4+r][n0+lq].
__global__ __launch_bounds__(256) void k_rec(const float* Ut0, const float* Ut1, const float* metaAll,
                                             const int* ops, const float* att_init, float* Cm){
  __shared__ float C[QC*65];
  __shared__ float Ul[2][64*81];
  int b = blockIdx.x, tid = threadIdx.x;
  int w = tid >> 6, l = tid & 63, quad = l >> 4, lq = l & 15;
  for (int i=tid;i<QC*65;i+=256) C[i] = 0.f;
  if (tid < A_) C[tid] = att_init[tid];        // row 0 (same thread wrote the zero)
  {
    const float* U0 = Ut0 + (size_t)(b*LP)*5120;
    const float* U1 = Ut1 + (size_t)(b*LP)*5120;
    #pragma unroll
    for (int k=0;k<5;k++){
      int i = tid*4 + k*1024;
      float4 v0 = *(const float4*)&U0[i];
      float4 v1 = *(const float4*)&U1[i];
      int r = i/80, c = i%80;
      Ul[0][r*81+c]   = v0.x+v1.x; Ul[0][r*81+c+1] = v0.y+v1.y;
      Ul[0][r*81+c+2] = v0.z+v1.z; Ul[0][r*81+c+3] = v0.w+v1.w;
    }
  }
  __syncthreads();
  for (int t=0;t<LP;t++){
    float4 rv0[5], rv1[5];
    if (t < LP-1){
      const float* U0 = Ut0 + (size_t)(b*LP+t+1)*5120;
      const float* U1 = Ut1 + (size_t)(b*LP+t+1)*5120;
      #pragma unroll
      for (int k=0;k<5;k++){
        rv0[k] = *(const float4*)&U0[tid*4 + k*1024];
        rv1[k] = *(const float4*)&U1[tid*4 + k*1024];
      }
    }
    const float* Uc = Ul[t&1];
    // A-frags (12): U[e = s*16+lq][qc = k0t*32 + quad*8 + j], zero-pad qc>=80
    U8 af[3][4];
    #pragma unroll
    for (int k0t=0;k0t<3;k0t++){
      #pragma unroll
      for (int s=0;s<4;s++){
        int e = s*16 + lq;
        int qb = k0t*32 + quad*8;
        float v[8];
        #pragma unroll
        for (int j=0;j<8;j++){
          int qc = qb + j;
          v[j] = (qc < QC) ? Uc[e*81 + qc] : 0.f;
        }
        #pragma unroll
        for (int d=0;d<4;d++) af[k0t][s].u[d] = pack2(v[2*d], v[2*d+1]);
      }
    }
    // B-frags (3): C[k = k0t*32 + quad*8 + j][a = w*16 + lq], zero-pad k>=80
    U8 bf[3];
    #pragma unroll
    for (int k0t=0;k0t<3;k0t++){
      int kb = k0t*32 + quad*8;
      float v[8];
      #pragma unroll
      for (int j=0;j<8;j++){
        int k = kb + j;
        v[j] = (k < QC) ? C[k*65 + w*16 + lq] : 0.f;
      }
      #pragma unroll
      for (int d=0;d<4;d++) bf[k0t].u[d] = pack2(v[2*d], v[2*d+1]);
    }
    f32x4 acc[4];
    #pragma unroll
    for (int s=0;s<4;s++){
      acc[s] = (f32x4){0.f,0.f,0.f,0.f};
      #pragma unroll
      for (int k0t=0;k0t<3;k0t++)
        acc[s] = __builtin_amdgcn_mfma_f32_16x16x32_bf16(af[k0t][s].v, bf[k0t].v, acc[s], 0, 0, 0);
    }
    int op = ops[b*LP + t];
    float tr  = (op==2) ? 1.f : 0.f;
    float ins = (op==1) ? 1.f : 0.f;
    __syncthreads();                          // all B-frag reads of C done
    #pragma unroll
    for (int s=0;s<4;s++){
      #pragma unroll
      for (int r=0;r<4;r++){
        int e = s*16 + quad*4 + r;            // M row; C row = 1+e
        C[(1+e)*65 + w*16 + lq] += tr*acc[s][r];
      }
    }
    if (tid < A_) C[(PROJ0+t)*65 + tid] += ins*metaAll[(b*LP+t)*A_ + tid];
    if (t < LP-1){
      float* Un = Ul[(t+1)&1];
      #pragma unroll
      for (int k=0;k<5;k++){
        int i = tid*4 + k*1024;
        int r = i/80, c = i%80;
        Un[r*81+c]   = rv0[k].x+rv1[k].x; Un[r*81+c+1] = rv0[k].y+rv1[k].y;
        Un[r*81+c+2] = rv0[k].z+rv1[k].z; Un[r*81+c+3] = rv0[k].w+rv1[k].w;
      }
    }
    __syncthreads();
  }
  for (int i=tid;i<QC*A_;i+=256) Cm[b*QC*A_ + i] = C[(i>>6)*65 + (i&63)];
}

// ---------------- k_out: 128-thread blocks, 264 blocks; ol[b,n] = ||C^T q_n||^2 / 64 ----------------
__global__ __launch_bounds__(128) void k_out(const unsigned short* QTf, const float* Cm,
                                             float* ol, float* esum){
  __shared__ float C[QC*A_];
  __shared__ float wsum[2];
  int b = blockIdx.x / 33, rem = blockIdx.x % 33;
  int tid = threadIdx.x;
  for (int i=tid;i<QC*A_;i+=128) C[i] = Cm[b*QC*A_ + i];
  __syncthreads();
  int n = rem*128 + tid;                      // 33*128 = 4224 = NN, always valid
  float y[A_];
  #pragma unroll
  for (int a=0;a<A_;a++) y[a]=0.f;
  const unsigned short* Qb = QTf + (size_t)b*QTF_B + ((n>>5)*512 + (n&31));
  for (int j=0;j<QC;j++){
    float qvv = bs2f(Qb[(j>>4)*QTF_C + (j&15)*32]);
    const float* Cj = &C[j*A_];
    #pragma unroll
    for (int a=0;a<A_;a++) y[a] = fmaf(qvv, Cj[a], y[a]);
  }
  float s = 0.f;
  #pragma unroll
  for (int a=0;a<A_;a++) s = fmaf(y[a], y[a], s);
  float o = s * (1.f/A_);
  ol[(size_t)b*NN + n] = o;
  float contrib = expf(o);
  #pragma unroll
  for (int off=32; off>0; off>>=1) contrib += __shfl_down(contrib, off, 64);
  if ((tid & 63) == 0) wsum[tid>>6] = contrib;
  __syncthreads();
  if (tid == 0) atomicAdd(&esum[b], wsum[0]+wsum[1]);
}

// ---------------- k_fin ----------------
__global__ void k_fin(const float* ol, const float* esum, const int* flag, void* out){
  int idx = blockIdx.x*256 + threadIdx.x;
  if (idx < B_*NN){
    int b = idx / NN;
    float v = ol[idx] - logf(esum[b]);
    if (*flag) ((float*)out)[idx] = v;
    else       ((bf16*)out)[idx]  = __float2bfloat16(v);
  }
}

extern "C" void kernel_launch(void* const* d_in, const int* in_sizes, int n_in,
                              void* d_out, int out_size, void* d_ws, size_t ws_size,
                              hipStream_t stream) {
  (void)in_sizes; (void)n_in; (void)out_size; (void)ws_size;
  const int* ops  = (const int*)d_in[17];
  const int* args = (const int*)d_in[18];
  const int* gtc  = (const int*)d_in[19];
  const int* gta  = (const int*)d_in[20];

  float* ws = (float*)d_ws;
  int* flag = (int*)ws;
  float* W  = ws + 16;

  const float* conceptIn  = W + 65536;
  const float* conceptOut = W + 327680;
  const float* meta_init  = W + 589824;
  const float* att_init   = W + 589888;
  const float* aw1        = W + 589952;
  const float* ab1        = W + 622720;
  const float* aw2        = W + 622976;
  const float* ab2        = W + 639360;
  const float* mw1        = W + 639424;
  const float* mb1        = W + 672192;
  const float* mw2        = W + 672448;
  const float* mb2        = W + 688832;

  constexpr size_t OFF_OBJIN   = 16 + TOT_IN;            // 688912
  constexpr size_t OFF_OBJOUT  = OFF_OBJIN  + 65536;     // 754448
  constexpr size_t OFF_METAALL = OFF_OBJOUT + 65536;     // 819984
  constexpr size_t OFF_METAH   = OFF_METAALL + 6144;     // 826128
  constexpr size_t OFF_QSUM    = OFF_METAH  + 24576;     // 850704
  constexpr size_t OFF_ESUM    = OFF_QSUM   + 640;       // 851344
  constexpr size_t OFF_UT0     = OFF_ESUM   + 16;        // 851360, 491520
  constexpr size_t OFF_UT1     = OFF_UT0    + 491520;    // 1342880, 491520
  constexpr size_t OFF_CM      = OFF_UT1    + 491520;    // 1834400, 40960
  constexpr size_t OFF_OL      = OFF_CM     + 40960;     // 1875360, 33792
  constexpr size_t OFF_QTF     = OFF_OL     + 33792;     // 1909152, 1351680
  constexpr size_t OFF_AOPTC   = OFF_QTF    + 1351680;   // 3260832, 524288
  constexpr size_t OFF_AOPTO   = OFF_AOPTC  + 524288;    // 3785120, 131072
  constexpr size_t OFF_AWF     = OFF_AOPTO  + 131072;    // 3916192, 8192
  constexpr size_t OFF_TB0     = OFF_AWF    + 8192;      // 3924384, 983040 dwords
  constexpr size_t OFF_TB1     = OFF_TB0    + 983040;    // 4907424, 983040 dwords
  // end = 5,890,464 floats ~= 23.6 MB

  float* objIn   = ws + OFF_OBJIN;
  float* objOut  = ws + OFF_OBJOUT;
  float* metaAll = ws + OFF_METAALL;
  float* metaH   = ws + OFF_METAH;
  float* qsum    = ws + OFF_QSUM;
  float* esum    = ws + OFF_ESUM;
  float* Ut0     = ws + OFF_UT0;
  float* Ut1     = ws + OFF_UT1;
  float* Cm      = ws + OFF_CM;
  float* ol      = ws + OFF_OL;
  unsigned short* QTf    = (unsigned short*)(ws + OFF_QTF);
  unsigned short* AoptC  = (unsigned short*)(ws + OFF_AOPTC);
  unsigned short* AoptO  = (unsigned short*)(ws + OFF_AOPTO);
  unsigned short* awFrag = (unsigned short*)(ws + OFF_AWF);
  unsigned* TB0          = (unsigned*)(ws + OFF_TB0);
  unsigned* TB1          = (unsigned*)(ws + OFF_TB1);

  hipMemsetAsync(qsum, 0, (640 + 16)*sizeof(float), stream);   // qsum + esum

  Ptr16 ps;
  const int src_idx[16] = {0,1,2,3,4,5,6,8,9,10,11,12,13,14,15,16};
  for (int i=0;i<16;i++) ps.p[i] = d_in[src_idx[i]];

  k_detect<<<1, 256, 0, stream>>>(d_in[4], flag);
  k_prep  <<<3011, 256, 0, stream>>>(ps, flag, W, awFrag, gtc, gta, objIn, objOut);
  k_mid   <<<224, 256, 0, stream>>>(conceptIn, conceptOut, meta_init, mw1, mb1, mw2, mb2,
                                    aw1, ab1, ops, args, objIn, objOut, awFrag,
                                    metaAll, metaH, QTf, qsum, AoptC, AoptO);
  k_T     <<<B_*LP*4*2, 256, 0, stream>>>(AoptC, AoptO, QTf, metaH, TB0, TB1);
  k_U     <<<B_*LP*2, 256, 0, stream>>>(TB0, TB1, aw2, ab2, qsum, Ut0, Ut1);
  k_rec   <<<B_, 256, 0, stream>>>(Ut0, Ut1, metaAll, ops, att_init, Cm);
  k_out   <<<B_*33, 128, 0, stream>>>(QTf, Cm, ol, esum);
  k_fin   <<<(B_*NN + 255)/256, 256, 0, stream>>>(ol, esum, flag, d_out);
}

// Round 10
// 265.363 us; speedup vs baseline: 6.9936x; 1.0272x over previous
//
#include <hip/hip_runtime.h>
#include <hip/hip_bf16.h>

typedef __hip_bfloat16 bf16;
typedef float f32x4 __attribute__((ext_vector_type(4)));
typedef short s16x8 __attribute__((ext_vector_type(8)));

#define B_    8
#define LP    12
#define NC    4096
#define NO    128
#define NAPO  8
#define NN    4224
#define E_    64
#define A_    64
#define H_    256
#define QC    80
#define PROJ0 65
#define NCHUNK 17

#define TOT_IN 688896
#define QTF_C  67584     // 132*512 shorts per (b,c) group
#define QTF_B  337920    // 5*QTF_C per batch
#define TB_P   983040    // dwords per kh-partial: 96*4*2560

struct Ptr16 { const void* p[16]; };
union U8 { s16x8 v; unsigned u[4]; };

__device__ __forceinline__ float b2f(bf16 x){ return __bfloat162float(x); }
__device__ __forceinline__ float bs2f(unsigned short s){
  union { unsigned u; float f; } x; x.u = ((unsigned)s) << 16; return x.f;
}
__device__ __forceinline__ unsigned short f2bs(float f){
  bf16 h = __float2bfloat16(f);
  union { bf16 h; unsigned short s; } x; x.h = h; return x.s;
}
__device__ __forceinline__ unsigned pack2(float a, float b){
  return (unsigned)f2bs(a) | ((unsigned)f2bs(b) << 16);
}
__device__ __forceinline__ float lo16f(unsigned w){
  union { unsigned u; float f; } x; x.u = w << 16; return x.f;
}
__device__ __forceinline__ float hi16f(unsigned w){
  union { unsigned u; float f; } x; x.u = w & 0xffff0000u; return x.f;
}
__device__ __forceinline__ float rdval(const void* p, int i, int fl){
  return fl ? ((const float*)p)[i] : bs2f(((const unsigned short*)p)[i]);
}

// ---------------- k_prep: dtype-detect (per-wave ballot) + convert + awFrag + obj + zero ----------------
__global__ void k_prep(Ptr16 ps, int* flag, float* dst,
                       unsigned short* awFrag,
                       const int* gtc, const int* gta,
                       float* objIn, float* objOut, float* qsum_esum){
  int tid = threadIdx.x;
  // wave-local dtype detect: probe concept_embIn even half-words; fp32 garbage -> ~46% exp>=137
  const unsigned short* u = (const unsigned short*)ps.p[4];
  int hit = (((u[tid*16] >> 7) & 0xFF) >= 137) ? 1 : 0;
  unsigned long long m = __ballot(hit);
  int fl = (m != 0ULL) ? 1 : 0;
  int mb = blockIdx.x;
  if (mb < 2691){
    int idx = mb*256 + tid;
    if (idx >= TOT_IN) return;
    constexpr int cum[17] = {0,16384,32768,49152,65536,327680,589824,589888,589952,
                             622720,622976,639360,639424,672192,672448,688832,688896};
    int t = 0;
    #pragma unroll
    for (int i=1;i<16;i++) if (idx >= cum[i]) t = i;
    dst[idx] = rdval(ps.p[t], idx - cum[t], fl);
  } else if (mb < 2755){
    int idx = (mb-2691)*256 + tid;              // < 16384
    int j = idx & 7;
    int lane = (idx >> 3) & 63;
    int mm = (idx >> 9) & 15;
    int kc = idx >> 13;
    int e = kc*32 + (lane>>4)*8 + j;
    int h = mm*16 + (lane&15);
    awFrag[idx] = f2bs(rdval(ps.p[8], e*H_ + h, fl));
  } else if (mb < 3011){
    int idx = (mb-2755)*256 + tid;              // < 65536
    int e = idx & 63; int bo = idx >> 6;
    int cls = gtc[bo];
    float vi = rdval(ps.p[0], cls*E_ + e, fl);
    float vo = rdval(ps.p[1], cls*E_ + e, fl);
    const int* ga = gta + bo*NAPO;
    #pragma unroll
    for (int j=0;j<NAPO;j++){
      int at = ga[j];
      vi += rdval(ps.p[2], at*E_ + e, fl);
      vo += rdval(ps.p[3], at*E_ + e, fl);
    }
    objIn[idx] = vi; objOut[idx] = vo;
  } else {
    if (tid < 656) qsum_esum[tid] = 0.f;        // qsum(640) + esum(16)
    if (tid == 0) *flag = fl;
  }
}

// ================ k_mid: meta(8) | QTf+qsum(136) | baseT->Aopt(80) ================
__device__ __forceinline__ void mid_meta(char* smem, int b,
                       const float* conceptOut, const float* meta_init,
                       const float* mw1, const float* mb1, const float* mw2, const float* mb2,
                       const float* aw1, const float* ab1,
                       const int* ops, const int* args,
                       float* metaAll, float* metaH){
  unsigned* mw1p = (unsigned*)smem;               // 64*256 = 65536 B
  unsigned* mw2p = (unsigned*)(smem + 65536);     // 128*64 = 32768 B
  unsigned* aw1p = (unsigned*)(smem + 98304);     // 32*256 = 32768 B
  float* meta_s  = (float*)(smem + 131072);
  float* argx    = (float*)(smem + 131328);
  float* hid     = (float*)(smem + 131584);
  float* part    = (float*)(smem + 132608);
  int tid = threadIdx.x;

  for (int i=tid; i<64*256; i+=256){
    int j2 = i >> 8, t = i & 255;
    mw1p[i] = pack2(mw1[(2*j2)*H_ + t], mw1[(2*j2+1)*H_ + t]);
  }
  for (int i=tid; i<128*64; i+=256){
    int h2 = i >> 6, a = i & 63;
    mw2p[i] = pack2(mw2[(2*h2)*A_ + a], mw2[(2*h2+1)*A_ + a]);
  }
  for (int i=tid; i<32*256; i+=256){
    int a2 = i >> 8, t = i & 255;
    aw1p[i] = pack2(aw1[(E_+2*a2)*H_ + t], aw1[(E_+2*a2+1)*H_ + t]);
  }
  float r_mb1 = mb1[tid];
  float r_ab1 = ab1[tid];
  float r_mb2 = (tid < A_) ? mb2[tid] : 0.f;
  if (tid < A_) meta_s[tid] = meta_init[tid];
  __syncthreads();

  for (int t=0;t<LP;t++){
    int op  = ops[b*LP + t];
    int arg = args[b*LP + t];
    if (tid >= 64 && tid < 128) argx[tid-64] = conceptOut[arg*E_ + (tid-64)];
    __syncthreads();
    float acc = r_mb1;
    for (int j2=0;j2<32;j2++){
      unsigned w = mw1p[j2*256 + tid];
      float2 xp = *(const float2*)&meta_s[2*j2];
      acc = fmaf(xp.x, lo16f(w), acc);
      acc = fmaf(xp.y, hi16f(w), acc);
    }
    for (int j2=0;j2<32;j2++){
      unsigned w = mw1p[(32+j2)*256 + tid];
      float2 xp = *(const float2*)&argx[2*j2];
      acc = fmaf(xp.x, lo16f(w), acc);
      acc = fmaf(xp.y, hi16f(w), acc);
    }
    hid[tid] = fmaxf(acc, 0.f);
    __syncthreads();
    int wv_ = tid >> 6, l = tid & 63;
    float acc2 = 0.f;
    for (int h2 = wv_*32; h2 < wv_*32+32; h2++){
      unsigned w = mw2p[h2*64 + l];
      float2 hp = *(const float2*)&hid[2*h2];
      acc2 = fmaf(hp.x, lo16f(w), acc2);
      acc2 = fmaf(hp.y, hi16f(w), acc2);
    }
    part[wv_*64 + l] = acc2;
    __syncthreads();
    if (tid < A_){
      float s = part[tid] + part[64+tid] + part[128+tid] + part[192+tid] + r_mb2;
      float nm = (op==0) ? s : meta_s[tid];
      meta_s[tid] = nm;
      metaAll[(b*LP+t)*A_ + tid] = nm;
    }
    __syncthreads();
    float mh = r_ab1;
    for (int a2=0;a2<32;a2++){
      unsigned w = aw1p[a2*256 + tid];
      float2 mp = *(const float2*)&meta_s[2*a2];
      mh = fmaf(mp.x, lo16f(w), mh);
      mh = fmaf(mp.y, hi16f(w), mh);
    }
    metaH[(b*LP+t)*H_ + tid] = mh;
  }
}

__device__ __forceinline__ void mid_qt(char* smem, int idx,
                       const float* conceptIn, const float* conceptOut, const int* args,
                       const float* objIn, const float* objOut,
                       unsigned short* QTf, float* qsum){
  float* tile = (float*)smem;                  // 256*65*4 = 66560 B
  float* argv = (float*)(smem + 66560);
  float* qs   = (float*)(smem + 69632);
  int b = idx / NCHUNK, chunk = idx % NCHUNK;
  int tid = threadIdx.x;
  int rows = (chunk < 16) ? 256 : 128;
  int n0 = chunk*256;
  int n = n0 + tid;
  bool valid = (tid < rows);
  if (tid < 80) qs[tid] = 0.f;
  unsigned short* Qb = QTf + (size_t)b*QTF_B + ((n>>5)*512 + (n&31));
  {
    const float* src = (chunk < 16) ? (conceptIn + (size_t)n0*E_) : (objIn + (size_t)b*NO*E_);
    int tot = rows*64;
    for (int i=tid; i<tot; i+=256) tile[(i>>6)*65 + (i&63)] = src[i];
  }
  __syncthreads();
  if (valid){
    Qb[0] = 0x3F80;
    Qb[4*QTF_C + 13*32] = 0;
    Qb[4*QTF_C + 14*32] = 0;
    Qb[4*QTF_C + 15*32] = 0;
    for (int e=0;e<64;e++){
      int qc = 1+e;
      Qb[(qc>>4)*QTF_C + (qc&15)*32] = f2bs(tile[tid*65 + e]);
    }
    for (int i=0;i<64;i++){
      int e = (i + tid) & 63;
      atomicAdd(&qs[1+e], tile[tid*65+e]);
    }
  }
  __syncthreads();
  for (int i=tid;i<LP*E_;i+=256) argv[i] = conceptOut[args[b*LP + (i>>6)]*E_ + (i&63)];
  {
    const float* src = (chunk < 16) ? (conceptOut + (size_t)n0*E_) : (objOut + (size_t)b*NO*E_);
    int tot = rows*64;
    for (int i=tid; i<tot; i+=256) tile[(i>>6)*65 + (i&63)] = src[i];
  }
  __syncthreads();
  float dots[LP];
  #pragma unroll
  for (int t=0;t<LP;t++) dots[t] = 0.f;
  for (int e=0;e<64;e++){
    float o = tile[tid*65 + e];
    #pragma unroll
    for (int t=0;t<LP;t++) dots[t] += o*argv[t*64+e];
  }
  #pragma unroll
  for (int t=0;t<LP;t++){
    float v = valid ? dots[t]*(1.f/E_) : 0.f;
    if (valid){
      int qc = PROJ0+t;
      Qb[(qc>>4)*QTF_C + (qc&15)*32] = f2bs(v);
    }
    float r = v;
    #pragma unroll
    for (int off=32; off>0; off>>=1) r += __shfl_down(r, off, 64);
    if ((tid & 63) == 0) atomicAdd(&qs[PROJ0+t], r);
  }
  __syncthreads();
  if (tid < 80) atomicAdd(&qsum[b*QC + tid], qs[tid]);
  if (chunk == 0 && tid == 0) atomicAdd(&qsum[b*QC], (float)NN);
}

__device__ __forceinline__ void mid_base(int blk,
                       const float* conceptOut, const float* objOut,
                       const unsigned short* awFrag,
                       unsigned short* AoptC, unsigned short* AoptO){
  int n0 = blk * 64;
  int tid = threadIdx.x;
  int w = tid >> 6, l = tid & 63, quad = l >> 4, lq = l & 15;
  int n = n0 + w*16 + lq;
  const float* src = (n < NC) ? (conceptOut + (size_t)n*E_) : (objOut + (size_t)(n-NC)*E_);
  f32x4 acc[16];
  #pragma unroll
  for (int m=0;m<16;m++) acc[m] = (f32x4){0.f,0.f,0.f,0.f};
  #pragma unroll
  for (int kc=0;kc<2;kc++){
    s16x8 bfr;
    #pragma unroll
    for (int j=0;j<8;j++) bfr[j] = (short)f2bs(src[kc*32 + quad*8 + j]);
    const unsigned short* ap = awFrag + ((size_t)(kc*16)*64 + l)*8;
    #pragma unroll
    for (int m=0;m<16;m++){
      s16x8 af = *(const s16x8*)(ap + (size_t)m*64*8);
      acc[m] = __builtin_amdgcn_mfma_f32_16x16x32_bf16(af, bfr, acc[m], 0, 0, 0);
    }
  }
  int nl = n & 31;
  if (n < NC){
    int nch = n >> 5;
    #pragma unroll
    for (int m=0;m<16;m++){
      #pragma unroll
      for (int r=0;r<4;r++)
        AoptC[(size_t)(m*128 + nch)*512 + (quad*4+r)*32 + nl] = f2bs(acc[m][r]);
    }
  } else {
    int no = n - NC; int bb = no >> 7; int oc = (no & 127) >> 5;
    #pragma unroll
    for (int m=0;m<16;m++){
      #pragma unroll
      for (int r=0;r<4;r++)
        AoptO[(size_t)((bb*16 + m)*4 + oc)*512 + (quad*4+r)*32 + nl] = f2bs(acc[m][r]);
    }
  }
}

__global__ __launch_bounds__(256) void k_mid(
    const float* conceptIn, const float* conceptOut,
    const float* meta_init, const float* mw1, const float* mb1, const float* mw2, const float* mb2,
    const float* aw1, const float* ab1, const int* ops, const int* args,
    const float* objIn, const float* objOut, const unsigned short* awFrag,
    float* metaAll, float* metaH, unsigned short* QTf, float* qsum,
    unsigned short* AoptC, unsigned short* AoptO){
  __shared__ __align__(16) char smem[133888];
  int mb = blockIdx.x;
  if (mb < 8)
    mid_meta(smem, mb, conceptOut, meta_init, mw1, mb1, mw2, mb2, aw1, ab1, ops, args, metaAll, metaH);
  else if (mb < 144)
    mid_qt(smem, mb-8, conceptIn, conceptOut, args, objIn, objOut, QTf, qsum);
  else
    mid_base(mb-144, conceptOut, objOut, awFrag, AoptC, AoptO);
}

// ---------------- k_T (MFMA v6): single-wave blocks, kh 8-way K-split, no LDS/barriers ----------------
// TB partial p=kh: [p][bt][ht][2560 dwords]; dword i2 packs acc pair (r0,r1)/(r2,r3).
__global__ __launch_bounds__(64) void k_T(const unsigned short* AoptC, const unsigned short* AoptO,
                                          const unsigned short* QTf, const float* metaH,
                                          unsigned* TB){
  int bid = blockIdx.x;
  int kh = bid & 7; int ht = (bid >> 3) & 3; int bt = bid >> 5; int b = bt / LP;
  int l = threadIdx.x, quad = l >> 4, lq = l & 15;
  int off = lq*32 + quad*8;
  int start = (kh < 4) ? (kh*17) : (68 + (kh-4)*16);
  int count = (kh < 4) ? 17 : 16;
  float mh[4];
  #pragma unroll
  for (int s=0;s<4;s++) mh[s] = metaH[(size_t)bt*H_ + ht*64 + s*16 + lq];
  f32x4 acc[4][5];
  #pragma unroll
  for (int s=0;s<4;s++){
    #pragma unroll
    for (int c=0;c<5;c++) acc[s][c] = (f32x4){0.f,0.f,0.f,0.f};
  }
  const unsigned short* QTb = QTf + (size_t)b*QTF_B + off;
  const unsigned short* AC  = AoptC + (size_t)(ht*4)*65536 + off;       // 65536 = 128*512
  const unsigned short* AO  = AoptO + (size_t)(b*16 + ht*4)*2048 + off; // 2048 = 4*512
  for (int it=0; it<count; it++){
    int nchunk = start + it;
    U8 bfr[5];
    #pragma unroll
    for (int c=0;c<5;c++)
      bfr[c].v = *(const s16x8*)(QTb + (size_t)c*QTF_C + (size_t)nchunk*512);
    bool isC = (nchunk < 128);
    #pragma unroll
    for (int s=0;s<4;s++){
      U8 a;
      a.v = isC ? *(const s16x8*)(AC + (size_t)s*65536 + (size_t)nchunk*512)
                : *(const s16x8*)(AO + (size_t)s*2048 + (size_t)(nchunk-128)*512);
      float mhs = mh[s];
      U8 af;
      #pragma unroll
      for (int d=0;d<4;d++){
        unsigned wv = a.u[d];
        float lo = fmaxf(__uint_as_float(wv << 16) + mhs, 0.f);
        float hi = fmaxf(__uint_as_float(wv & 0xffff0000u) + mhs, 0.f);
        af.u[d] = __builtin_amdgcn_perm(__float_as_uint(hi), __float_as_uint(lo), 0x07060302u);
      }
      #pragma unroll
      for (int c=0;c<5;c++)
        acc[s][c] = __builtin_amdgcn_mfma_f32_16x16x32_bf16(af.v, bfr[c].v, acc[s][c], 0, 0, 0);
    }
  }
  unsigned* Tp = TB + (size_t)kh*TB_P + ((size_t)bt*4 + ht)*2560;
  #pragma unroll
  for (int s=0;s<4;s++){
    #pragma unroll
    for (int c=0;c<5;c++){
      uint2 v;
      v.x = pack2(acc[s][c][0], acc[s][c][1]);
      v.y = pack2(acc[s][c][2], acc[s][c][3]);
      *(uint2*)(Tp + (s*5+c)*128 + l*2) = v;
    }
  }
}

// ---------------- k_U v3: K-split x2; sums 8 bf16 TB partials during staging ----------------
__global__ __launch_bounds__(256) void k_U(const unsigned* TB,
                                           const float* w2, const float* b2v,
                                           const float* qsum, float* Ut0, float* Ut1){
  __shared__ float Wt[128*64];
  __shared__ float Tt[128*81];
  int bid = blockIdx.x;
  int kq = bid & 1; int bt = bid >> 1; int b = bt / LP;
  int tid = threadIdx.x;
  for (int i=tid; i<8192; i+=256){
    int hl = i >> 6, e = i & 63;
    Wt[i] = w2[(kq*128 + hl)*E_ + e];
  }
  #pragma unroll
  for (int half=0; half<2; half++){
    const unsigned* base = TB + ((size_t)bt*4 + kq*2 + half)*2560;
    for (int i2=tid; i2<2560; i2+=256){
      float lo = 0.f, hi = 0.f;
      #pragma unroll
      for (int p=0;p<8;p++){
        unsigned w = base[(size_t)p*TB_P + i2];
        lo += lo16f(w); hi += hi16f(w);
      }
      int idx = 2*i2;
      int sc = idx >> 8; int ll = (idx >> 2) & 63; int r = idx & 3;
      int s = sc/5, c = sc - s*5;
      int hl = half*64 + s*16 + ((ll>>4)<<2) + r;
      int qc = c*16 + (ll&15);
      Tt[hl*81 + qc]     = lo;
      Tt[(hl+1)*81 + qc] = hi;
    }
  }
  __syncthreads();
  int el = tid & 15, ql = tid >> 4;
  float acc[4][5];
  #pragma unroll
  for (int i=0;i<4;i++){
    #pragma unroll
    for (int j=0;j<5;j++) acc[i][j]=0.f;
  }
  #pragma unroll 4
  for (int kk=0; kk<128; kk++){
    float4 wv = *(const float4*)&Wt[kk*64 + el*4];
    float ww[4] = {wv.x, wv.y, wv.z, wv.w};
    const float* tp = &Tt[kk*81 + ql*5];
    #pragma unroll
    for (int j=0;j<5;j++){
      float tv = tp[j];
      #pragma unroll
      for (int i=0;i<4;i++) acc[i][j] = fmaf(ww[i], tv, acc[i][j]);
    }
  }
  const float invN = 1.f/NN;
  float* Up = (kq ? Ut1 : Ut0) + (size_t)bt*5120;
  if (kq == 0){
    float be[4], qv[5];
    #pragma unroll
    for (int i=0;i<4;i++) be[i] = b2v[el*4+i];
    #pragma unroll
    for (int j=0;j<5;j++) qv[j] = qsum[b*QC + ql*5+j];
    #pragma unroll
    for (int i=0;i<4;i++){
      #pragma unroll
      for (int j=0;j<5;j++)
        Up[(el*4+i)*QC + ql*5+j] = (acc[i][j] + be[i]*qv[j]) * invN;
    }
  } else {
    #pragma unroll
    for (int i=0;i<4;i++){
      #pragma unroll
      for (int j=0;j<5;j++)
        Up[(el*4+i)*QC + ql*5+j] = acc[i][j] * invN;
    }
  }
}

// ---------------- k_rec v3: MFMA per-step M = U_t @ C; padded LDS ----------------
__global__ __launch_bounds__(256) void k_rec(const float* Ut0, const float* Ut1, const float* metaAll,
                                             const int* ops, const float* att_init, float* Cm){
  __shared__ float C[QC*65];
  __shared__ float Ul[2][64*81];
  int b = blockIdx.x, tid = threadIdx.x;
  int w = tid >> 6, l = tid & 63, quad = l >> 4, lq = l & 15;
  for (int i=tid;i<QC*65;i+=256) C[i] = 0.f;
  if (tid < A_) C[tid] = att_init[tid];
  {
    const float* U0 = Ut0 + (size_t)(b*LP)*5120;
    const float* U1 = Ut1 + (size_t)(b*LP)*5120;
    #pragma unroll
    for (int k=0;k<5;k++){
      int i = tid*4 + k*1024;
      float4 v0 = *(const float4*)&U0[i];
      float4 v1 = *(const float4*)&U1[i];
      int r = i/80, c = i%80;
      Ul[0][r*81+c]   = v0.x+v1.x; Ul[0][r*81+c+1] = v0.y+v1.y;
      Ul[0][r*81+c+2] = v0.z+v1.z; Ul[0][r*81+c+3] = v0.w+v1.w;
    }
  }
  __syncthreads();
  for (int t=0;t<LP;t++){
    float4 rv0[5], rv1[5];
    if (t < LP-1){
      const float* U0 = Ut0 + (size_t)(b*LP+t+1)*5120;
      const float* U1 = Ut1 + (size_t)(b*LP+t+1)*5120;
      #pragma unroll
      for (int k=0;k<5;k++){
        rv0[k] = *(const float4*)&U0[tid*4 + k*1024];
        rv1[k] = *(const float4*)&U1[tid*4 + k*1024];
      }
    }
    const float* Uc = Ul[t&1];
    U8 af[3][4];
    #pragma unroll
    for (int k0t=0;k0t<3;k0t++){
      #pragma unroll
      for (int s=0;s<4;s++){
        int e = s*16 + lq;
        int qb = k0t*32 + quad*8;
        float v[8];
        #pragma unroll
        for (int j=0;j<8;j++){
          int qc = qb + j;
          v[j] = (qc < QC) ? Uc[e*81 + qc] : 0.f;
        }
        #pragma unroll
        for (int d=0;d<4;d++) af[k0t][s].u[d] = pack2(v[2*d], v[2*d+1]);
      }
    }
    U8 bf[3];
    #pragma unroll
    for (int k0t=0;k0t<3;k0t++){
      int kb = k0t*32 + quad*8;
      float v[8];
      #pragma unroll
      for (int j=0;j<8;j++){
        int k = kb + j;
        v[j] = (k < QC) ? C[k*65 + w*16 + lq] : 0.f;
      }
      #pragma unroll
      for (int d=0;d<4;d++) bf[k0t].u[d] = pack2(v[2*d], v[2*d+1]);
    }
    f32x4 acc[4];
    #pragma unroll
    for (int s=0;s<4;s++){
      acc[s] = (f32x4){0.f,0.f,0.f,0.f};
      #pragma unroll
      for (int k0t=0;k0t<3;k0t++)
        acc[s] = __builtin_amdgcn_mfma_f32_16x16x32_bf16(af[k0t][s].v, bf[k0t].v, acc[s], 0, 0, 0);
    }
    int op = ops[b*LP + t];
    float tr  = (op==2) ? 1.f : 0.f;
    float ins = (op==1) ? 1.f : 0.f;
    __syncthreads();
    #pragma unroll
    for (int s=0;s<4;s++){
      #pragma unroll
      for (int r=0;r<4;r++){
        int e = s*16 + quad*4 + r;
        C[(1+e)*65 + w*16 + lq] += tr*acc[s][r];
      }
    }
    if (tid < A_) C[(PROJ0+t)*65 + tid] += ins*metaAll[(b*LP+t)*A_ + tid];
    if (t < LP-1){
      float* Un = Ul[(t+1)&1];
      #pragma unroll
      for (int k=0;k<5;k++){
        int i = tid*4 + k*1024;
        int r = i/80, c = i%80;
        Un[r*81+c]   = rv0[k].x+rv1[k].x; Un[r*81+c+1] = rv0[k].y+rv1[k].y;
        Un[r*81+c+2] = rv0[k].z+rv1[k].z; Un[r*81+c+3] = rv0[k].w+rv1[k].w;
      }
    }
    __syncthreads();
  }
  for (int i=tid;i<QC*A_;i+=256) Cm[b*QC*A_ + i] = C[(i>>6)*65 + (i&63)];
}

// ---------------- k_out: 128-thread blocks; ol[b,n] = ||C^T q_n||^2 / 64 ----------------
__global__ __launch_bounds__(128) void k_out(const unsigned short* QTf, const float* Cm,
                                             float* ol, float* esum){
  __shared__ float C[QC*A_];
  __shared__ float wsum[2];
  int b = blockIdx.x / 33, rem = blockIdx.x % 33;
  int tid = threadIdx.x;
  for (int i=tid;i<QC*A_;i+=128) C[i] = Cm[b*QC*A_ + i];
  __syncthreads();
  int n = rem*128 + tid;
  float y[A_];
  #pragma unroll
  for (int a=0;a<A_;a++) y[a]=0.f;
  const unsigned short* Qb = QTf + (size_t)b*QTF_B + ((n>>5)*512 + (n&31));
  for (int j=0;j<QC;j++){
    float qvv = bs2f(Qb[(j>>4)*QTF_C + (j&15)*32]);
    const float* Cj = &C[j*A_];
    #pragma unroll
    for (int a=0;a<A_;a++) y[a] = fmaf(qvv, Cj[a], y[a]);
  }
  float s = 0.f;
  #pragma unroll
  for (int a=0;a<A_;a++) s = fmaf(y[a], y[a], s);
  float o = s * (1.f/A_);
  ol[(size_t)b*NN + n] = o;
  float contrib = expf(o);
  #pragma unroll
  for (int off=32; off>0; off>>=1) contrib += __shfl_down(contrib, off, 64);
  if ((tid & 63) == 0) wsum[tid>>6] = contrib;
  __syncthreads();
  if (tid == 0) atomicAdd(&esum[b], wsum[0]+wsum[1]);
}

// ---------------- k_fin ----------------
__global__ void k_fin(const float* ol, const float* esum, const int* flag, void* out){
  int idx = blockIdx.x*256 + threadIdx.x;
  if (idx < B_*NN){
    int b = idx / NN;
    float v = ol[idx] - logf(esum[b]);
    if (*flag) ((float*)out)[idx] = v;
    else       ((bf16*)out)[idx]  = __float2bfloat16(v);
  }
}

extern "C" void kernel_launch(void* const* d_in, const int* in_sizes, int n_in,
                              void* d_out, int out_size, void* d_ws, size_t ws_size,
                              hipStream_t stream) {
  (void)in_sizes; (void)n_in; (void)out_size; (void)ws_size;
  const int* ops  = (const int*)d_in[17];
  const int* args = (const int*)d_in[18];
  const int* gtc  = (const int*)d_in[19];
  const int* gta  = (const int*)d_in[20];

  float* ws = (float*)d_ws;
  int* flag = (int*)ws;
  float* W  = ws + 16;

  const float* conceptIn  = W + 65536;
  const float* conceptOut = W + 327680;
  const float* meta_init  = W + 589824;
  const float* att_init   = W + 589888;
  const float* aw1        = W + 589952;
  const float* ab1        = W + 622720;
  const float* aw2        = W + 622976;
  const float* ab2        = W + 639360;
  const float* mw1        = W + 639424;
  const float* mb1        = W + 672192;
  const float* mw2        = W + 672448;
  const float* mb2        = W + 688832;

  constexpr size_t OFF_OBJIN   = 16 + TOT_IN;            // 688912
  constexpr size_t OFF_OBJOUT  = OFF_OBJIN  + 65536;
  constexpr size_t OFF_METAALL = OFF_OBJOUT + 65536;
  constexpr size_t OFF_METAH   = OFF_METAALL + 6144;
  constexpr size_t OFF_QSUM    = OFF_METAH  + 24576;
  constexpr size_t OFF_ESUM    = OFF_QSUM   + 640;
  constexpr size_t OFF_UT0     = OFF_ESUM   + 16;
  constexpr size_t OFF_UT1     = OFF_UT0    + 491520;
  constexpr size_t OFF_CM      = OFF_UT1    + 491520;
  constexpr size_t OFF_OL      = OFF_CM     + 40960;
  constexpr size_t OFF_QTF     = OFF_OL     + 33792;
  constexpr size_t OFF_AOPTC   = OFF_QTF    + 1351680;
  constexpr size_t OFF_AOPTO   = OFF_AOPTC  + 524288;
  constexpr size_t OFF_AWF     = OFF_AOPTO  + 131072;
  constexpr size_t OFF_TB      = OFF_AWF    + 8192;      // 8 partials x 983040 dwords
  // end = OFF_TB + 7864320 = 11,788,704 floats ~= 47.2 MB (ws is 256 MiB)

  float* objIn   = ws + OFF_OBJIN;
  float* objOut  = ws + OFF_OBJOUT;
  float* metaAll = ws + OFF_METAALL;
  float* metaH   = ws + OFF_METAH;
  float* qsum    = ws + OFF_QSUM;
  float* esum    = ws + OFF_ESUM;
  float* Ut0     = ws + OFF_UT0;
  float* Ut1     = ws + OFF_UT1;
  float* Cm      = ws + OFF_CM;
  float* ol      = ws + OFF_OL;
  unsigned short* QTf    = (unsigned short*)(ws + OFF_QTF);
  unsigned short* AoptC  = (unsigned short*)(ws + OFF_AOPTC);
  unsigned short* AoptO  = (unsigned short*)(ws + OFF_AOPTO);
  unsigned short* awFrag = (unsigned short*)(ws + OFF_AWF);
  unsigned* TB           = (unsigned*)(ws + OFF_TB);

  Ptr16 ps;
  const int src_idx[16] = {0,1,2,3,4,5,6,8,9,10,11,12,13,14,15,16};
  for (int i=0;i<16;i++) ps.p[i] = d_in[src_idx[i]];

  k_prep<<<3012, 256, 0, stream>>>(ps, flag, W, awFrag, gtc, gta, objIn, objOut, qsum);
  k_mid <<<224, 256, 0, stream>>>(conceptIn, conceptOut, meta_init, mw1, mb1, mw2, mb2,
                                  aw1, ab1, ops, args, objIn, objOut, awFrag,
                                  metaAll, metaH, QTf, qsum, AoptC, AoptO);
  k_T   <<<B_*LP*4*8, 64, 0, stream>>>(AoptC, AoptO, QTf, metaH, TB);
  k_U   <<<B_*LP*2, 256, 0, stream>>>(TB, aw2, ab2, qsum, Ut0, Ut1);
  k_rec <<<B_, 256, 0, stream>>>(Ut0, Ut1, metaAll, ops, att_init, Cm);
  k_out <<<B_*33, 128, 0, stream>>>(QTf, Cm, ol, esum);
  k_fin <<<(B_*NN + 255)/256, 256, 0, stream>>>(ol, esum, flag, d_out);
}